// Round 1
// baseline (2082.367 us; speedup 1.0000x reference)
//
#include <hip/hip_runtime.h>
#include <math.h>

#define LL 256      // L
#define NS 128      // N sequences
#define DM 256      // d_msa
#define DH 32       // d_h
#define DP 128      // d_pair
#define HW 65536    // L*L

__device__ __forceinline__ float elu1(float v) { return v > 0.f ? v : expm1f(v); }

// ---------------------------------------------------------------------------
// K1: LayerNorm over d_msa + left/right projections.
// grid = N*L blocks (one (s,l) row), 256 threads.
// left[l][s][i], right[m][s][j] (right pre-divided by N).
// ---------------------------------------------------------------------------
__global__ __launch_bounds__(256) void k_ln_proj(
    const float* __restrict__ msa, const float* __restrict__ ln_g, const float* __restrict__ ln_b,
    const float* __restrict__ Wl, const float* __restrict__ bl,
    const float* __restrict__ Wr, const float* __restrict__ br,
    float* __restrict__ left, float* __restrict__ right)
{
  int row = blockIdx.x;             // s*LL + l
  int s = row >> 8, l = row & 255;
  const float* x = msa + (size_t)row * DM;
  int t = threadIdx.x;
  float v = x[t];
  float sum = v, sq = v * v;
  #pragma unroll
  for (int off = 32; off; off >>= 1) {
    sum += __shfl_down(sum, off);
    sq  += __shfl_down(sq, off);
  }
  __shared__ float red[8];
  __shared__ float sx[DM];
  int lane = t & 63, w = t >> 6;
  if (lane == 0) { red[w] = sum; red[4 + w] = sq; }
  __syncthreads();
  sum = red[0] + red[1] + red[2] + red[3];
  sq  = red[4] + red[5] + red[6] + red[7];
  float mean = sum * (1.f / DM);
  float var  = sq * (1.f / DM) - mean * mean;
  float rstd = rsqrtf(var + 1e-5f);
  sx[t] = (v - mean) * rstd * ln_g[t] + ln_b[t];
  __syncthreads();
  if (t < 64) {
    int col = t & 31;
    const float* W = (t < 32) ? Wl : Wr;
    float acc = (t < 32) ? bl[col] : br[col];
    #pragma unroll 4
    for (int d = 0; d < DM; ++d) acc += sx[d] * W[d * DH + col];
    size_t o = ((size_t)l * NS + s) * DH + col;
    if (t < 32) left[o] = acc;
    else        right[o] = acc * (1.f / NS);
  }
}

// ---------------------------------------------------------------------------
// K2 (per l-strip): op[l,m,i,j] = sum_s left[l,s,i]*right[m,s,j]
// Block handles one l and 4 m's. grid = (64, 16).
// OP layout: [lLocal*256+m][i*32+j]
// ---------------------------------------------------------------------------
__global__ __launch_bounds__(256) void k_outer(
    const float* __restrict__ left, const float* __restrict__ right,
    float* __restrict__ OP, int lBase)
{
  __shared__ alignas(16) float Ls[NS * DH];
  __shared__ alignas(16) float Rs[4][NS * DH];
  int t = threadIdx.x;
  int l = lBase + blockIdx.y;
  int m0 = blockIdx.x * 4;
  {
    const float4* lsrc = (const float4*)(left + (size_t)l * NS * DH);
    float4* Ld = (float4*)Ls;
    #pragma unroll
    for (int k = 0; k < 4; ++k) Ld[t + 256 * k] = lsrc[t + 256 * k];
    #pragma unroll
    for (int mm = 0; mm < 4; ++mm) {
      const float4* rsrc = (const float4*)(right + (size_t)(m0 + mm) * NS * DH);
      float4* Rd = (float4*)Rs[mm];
      #pragma unroll
      for (int k = 0; k < 4; ++k) Rd[t + 256 * k] = rsrc[t + 256 * k];
    }
  }
  __syncthreads();
  int j = t & 31, ib = (t >> 5) * 4;
  float acc[4][4] = {};
  #pragma unroll 2
  for (int s = 0; s < NS; ++s) {
    const float4 lv = *(const float4*)&Ls[s * DH + ib];
    float rv[4];
    #pragma unroll
    for (int mm = 0; mm < 4; ++mm) rv[mm] = Rs[mm][s * DH + j];
    #pragma unroll
    for (int mm = 0; mm < 4; ++mm) {
      acc[mm][0] += lv.x * rv[mm];
      acc[mm][1] += lv.y * rv[mm];
      acc[mm][2] += lv.z * rv[mm];
      acc[mm][3] += lv.w * rv[mm];
    }
  }
  #pragma unroll
  for (int mm = 0; mm < 4; ++mm) {
    float* dst = OP + ((size_t)blockIdx.y * LL + m0 + mm) * 1024;
    #pragma unroll
    for (int k = 0; k < 4; ++k) dst[(ib + k) * DH + j] = acc[mm][k];
  }
}

// ---------------------------------------------------------------------------
// K3 (per l-strip): out_raw[pix][c] = OP[pix] @ Wo + bo
// Tile: 32 pixels x 64 c. grid = 256 (128 pixel-tiles x 2 c-halves).
// ---------------------------------------------------------------------------
__global__ __launch_bounds__(256) void k_proj_out(
    const float* __restrict__ OP, const float* __restrict__ Wo, const float* __restrict__ bo,
    float* __restrict__ outraw, int lBase)
{
  __shared__ alignas(16) float At[32 * 64];
  __shared__ alignas(16) float Bt[64 * 64];
  int t = threadIdx.x;
  int pixTile = blockIdx.x >> 1;
  int cBase = (blockIdx.x & 1) * 64;
  int pix0 = pixTile * 32;
  int cl4 = (t & 15) * 4;
  int p0  = (t >> 4) * 2;
  float acc[2][4] = {};
  for (int kc = 0; kc < 1024; kc += 64) {
    #pragma unroll
    for (int k = 0; k < 2; ++k) {
      int off = (t + 256 * k) * 4;
      int p = off >> 6, kk = off & 63;
      *(float4*)&At[off] = *(const float4*)&OP[(size_t)(pix0 + p) * 1024 + kc + kk];
    }
    #pragma unroll
    for (int k = 0; k < 4; ++k) {
      int off = (t + 256 * k) * 4;
      int kk = off >> 6, c = off & 63;
      *(float4*)&Bt[off] = *(const float4*)&Wo[(size_t)(kc + kk) * DP + cBase + c];
    }
    __syncthreads();
    #pragma unroll 4
    for (int kk = 0; kk < 64; ++kk) {
      const float4 b = *(const float4*)&Bt[kk * 64 + cl4];
      #pragma unroll
      for (int pp = 0; pp < 2; ++pp) {
        float a = At[(p0 + pp) * 64 + kk];
        acc[pp][0] += a * b.x; acc[pp][1] += a * b.y;
        acc[pp][2] += a * b.z; acc[pp][3] += a * b.w;
      }
    }
    __syncthreads();
  }
  const float4 bv = *(const float4*)&bo[cBase + cl4];
  #pragma unroll
  for (int pp = 0; pp < 2; ++pp) {
    float4 r;
    r.x = acc[pp][0] + bv.x; r.y = acc[pp][1] + bv.y;
    r.z = acc[pp][2] + bv.z; r.w = acc[pp][3] + bv.w;
    *(float4*)&outraw[((size_t)lBase * LL + pix0 + p0 + pp) * DP + cBase + cl4] = r;
  }
}

// ---------------------------------------------------------------------------
// K4: p = concat(pair, out) @ Wd + bd, fused with NHWC -> planar transpose.
// Block: 32 pixels (one row chunk). grid = 2048.
// ---------------------------------------------------------------------------
__global__ __launch_bounds__(256) void k_projdown_trans(
    const float* __restrict__ outraw, const float* __restrict__ pairin,
    const float* __restrict__ Wd, const float* __restrict__ bd,
    float* __restrict__ pplanar)
{
  __shared__ alignas(16) float pairT[32 * 128];
  __shared__ alignas(16) float outT[32 * 128];
  __shared__ alignas(16) float res[32 * 132];
  int t = threadIdx.x;
  int pix0 = blockIdx.x * 32;
  #pragma unroll
  for (int k = 0; k < 4; ++k) {
    int off = (t + 256 * k) * 4;
    *(float4*)&pairT[off] = *(const float4*)&pairin[(size_t)pix0 * DP + off];
    *(float4*)&outT[off]  = *(const float4*)&outraw[(size_t)pix0 * DP + off];
  }
  __syncthreads();
  int c4 = (t & 31) * 4;
  int pg = (t >> 5) * 4;
  float acc[4][4];
  const float4 bv = *(const float4*)&bd[c4];
  #pragma unroll
  for (int q = 0; q < 4; ++q) { acc[q][0] = bv.x; acc[q][1] = bv.y; acc[q][2] = bv.z; acc[q][3] = bv.w; }
  for (int k = 0; k < 128; ++k) {
    const float4 w = *(const float4*)&Wd[(size_t)k * DP + c4];
    #pragma unroll
    for (int q = 0; q < 4; ++q) {
      float a = pairT[(pg + q) * 128 + k];
      acc[q][0] += a * w.x; acc[q][1] += a * w.y; acc[q][2] += a * w.z; acc[q][3] += a * w.w;
    }
  }
  for (int k = 0; k < 128; ++k) {
    const float4 w = *(const float4*)&Wd[(size_t)(128 + k) * DP + c4];
    #pragma unroll
    for (int q = 0; q < 4; ++q) {
      float a = outT[(pg + q) * 128 + k];
      acc[q][0] += a * w.x; acc[q][1] += a * w.y; acc[q][2] += a * w.z; acc[q][3] += a * w.w;
    }
  }
  #pragma unroll
  for (int q = 0; q < 4; ++q) {
    float4 r; r.x = acc[q][0]; r.y = acc[q][1]; r.z = acc[q][2]; r.w = acc[q][3];
    *(float4*)&res[(pg + q) * 132 + c4] = r;
  }
  __syncthreads();
  int y = pix0 >> 8, x0 = pix0 & 255;
  #pragma unroll
  for (int k = 0; k < 16; ++k) {
    int idx = k * 256 + t;
    int c = idx >> 5, xl = idx & 31;
    pplanar[(size_t)c * HW + y * LL + x0 + xl] = res[xl * 132 + c];
  }
}

// ---------------------------------------------------------------------------
// K5: 3x3 SAME conv, planar in/out. grid = (16,16,4): 16x16 spatial tile,
// 32 output channels per block. Weights via uniform scalar loads.
// ---------------------------------------------------------------------------
__global__ __launch_bounds__(256) void k_conv3x3(
    const float* __restrict__ in, const float* __restrict__ w,
    float* __restrict__ out)
{
  __shared__ float patch[18 * 20];
  int t = threadIdx.x;
  int tx = t & 15, ty = t >> 4;
  int x0 = blockIdx.x * 16, y0 = blockIdx.y * 16;
  int coB = blockIdx.z * 32;
  float acc[32] = {};
  for (int ci = 0; ci < 128; ++ci) {
    __syncthreads();
    for (int p = t; p < 324; p += 256) {
      int py = p / 18, px = p % 18;
      int gy = y0 + py - 1, gx = x0 + px - 1;
      float v = 0.f;
      if ((unsigned)gy < 256u && (unsigned)gx < 256u)
        v = in[(size_t)ci * HW + gy * LL + gx];
      patch[py * 20 + px] = v;
    }
    __syncthreads();
    float p00 = patch[(ty + 0) * 20 + tx + 0], p01 = patch[(ty + 0) * 20 + tx + 1], p02 = patch[(ty + 0) * 20 + tx + 2];
    float p10 = patch[(ty + 1) * 20 + tx + 0], p11 = patch[(ty + 1) * 20 + tx + 1], p12 = patch[(ty + 1) * 20 + tx + 2];
    float p20 = patch[(ty + 2) * 20 + tx + 0], p21 = patch[(ty + 2) * 20 + tx + 1], p22 = patch[(ty + 2) * 20 + tx + 2];
    const float* wp = w + ((size_t)coB * 128 + ci) * 9;
    #pragma unroll
    for (int co = 0; co < 32; ++co) {
      const float* wc = wp + (size_t)co * 128 * 9;
      acc[co] += p00 * wc[0] + p01 * wc[1] + p02 * wc[2]
               + p10 * wc[3] + p11 * wc[4] + p12 * wc[5]
               + p20 * wc[6] + p21 * wc[7] + p22 * wc[8];
    }
  }
  int ox = x0 + tx, oy = y0 + ty;
  #pragma unroll
  for (int co = 0; co < 32; ++co)
    out[(size_t)(coB + co) * HW + oy * LL + ox] = acc[co];
}

// ---------------------------------------------------------------------------
// K6: per-channel instance-norm stats (mean, rstd). grid = 128.
// ---------------------------------------------------------------------------
__global__ __launch_bounds__(256) void k_instat(const float* __restrict__ x, float* __restrict__ st)
{
  int c = blockIdx.x, t = threadIdx.x;
  const float4* p4 = (const float4*)(x + (size_t)c * HW);
  float s = 0, s2 = 0;
  for (int i = t; i < HW / 4; i += 256) {
    float4 v = p4[i];
    s  += v.x + v.y + v.z + v.w;
    s2 += v.x * v.x + v.y * v.y + v.z * v.z + v.w * v.w;
  }
  #pragma unroll
  for (int off = 32; off; off >>= 1) { s += __shfl_down(s, off); s2 += __shfl_down(s2, off); }
  __shared__ float red[8];
  int lane = t & 63, w = t >> 6;
  if (lane == 0) { red[w] = s; red[4 + w] = s2; }
  __syncthreads();
  if (t == 0) {
    s  = red[0] + red[1] + red[2] + red[3];
    s2 = red[4] + red[5] + red[6] + red[7];
    float m = s * (1.f / HW);
    float var = s2 * (1.f / HW) - m * m;
    st[c] = m;
    st[128 + c] = rsqrtf(var + 1e-6f);
  }
}

// ---------------------------------------------------------------------------
// K7: h = elu(IN(h)) in place (planar). grid = 8192.
// ---------------------------------------------------------------------------
__global__ __launch_bounds__(256) void k_in_elu(float* __restrict__ h, const float* __restrict__ st,
                                                const float* __restrict__ g, const float* __restrict__ b)
{
  int i = blockIdx.x * 256 + threadIdx.x;   // float4 index
  int c = i >> 14;                          // 16384 float4 per channel
  float m = st[c], r = st[128 + c];
  float sc = r * g[c], bb = b[c] - m * sc;
  float4* p = (float4*)h;
  float4 v = p[i];
  v.x = elu1(v.x * sc + bb);
  v.y = elu1(v.y * sc + bb);
  v.z = elu1(v.z * sc + bb);
  v.w = elu1(v.w * sc + bb);
  p[i] = v;
}

// ---------------------------------------------------------------------------
// K8: out_nhwc = elu(p + IN2(h2)), planar reads, LDS transpose, NHWC write.
// grid = (8, 256).
// ---------------------------------------------------------------------------
__global__ __launch_bounds__(256) void k_final(
    const float* __restrict__ pbuf, const float* __restrict__ h2, const float* __restrict__ st,
    const float* __restrict__ g, const float* __restrict__ b, float* __restrict__ out)
{
  __shared__ float lds[128 * 33];
  int t = threadIdx.x;
  int x0 = blockIdx.x * 32, y = blockIdx.y;
  #pragma unroll
  for (int k = 0; k < 16; ++k) {
    int idx = k * 256 + t;
    int c = idx >> 5, xl = idx & 31;
    size_t gi = (size_t)c * HW + y * LL + x0 + xl;
    float hv = (h2[gi] - st[c]) * st[128 + c] * g[c] + b[c];
    float v = pbuf[gi] + hv;
    lds[c * 33 + xl] = v > 0.f ? v : expm1f(v);
  }
  __syncthreads();
  #pragma unroll
  for (int k = 0; k < 16; ++k) {
    int idx = k * 256 + t;
    int px = idx >> 7, c = idx & 127;
    out[((size_t)(y * LL) + x0 + px) * DP + c] = lds[c * 33 + px];
  }
}

// ---------------------------------------------------------------------------
extern "C" void kernel_launch(void* const* d_in, const int* in_sizes, int n_in,
                              void* d_out, int out_size, void* d_ws, size_t ws_size,
                              hipStream_t stream)
{
  const float* msa   = (const float*)d_in[0];
  const float* pair  = (const float*)d_in[1];
  const float* ln_g  = (const float*)d_in[2];
  const float* ln_b  = (const float*)d_in[3];
  const float* Wl    = (const float*)d_in[4];
  const float* bl    = (const float*)d_in[5];
  const float* Wr    = (const float*)d_in[6];
  const float* br    = (const float*)d_in[7];
  const float* Wo    = (const float*)d_in[8];
  const float* bo    = (const float*)d_in[9];
  const float* Wd    = (const float*)d_in[10];
  const float* bd    = (const float*)d_in[11];
  const float* conv1 = (const float*)d_in[12];
  const float* in1_g = (const float*)d_in[13];
  const float* in1_b = (const float*)d_in[14];
  const float* conv2 = (const float*)d_in[15];
  const float* in2_g = (const float*)d_in[16];
  const float* in2_b = (const float*)d_in[17];
  float* out = (float*)d_out;

  // Workspace layout (floats). h2 reuses [0,8M): left/right/OP/outraw-head are
  // dead before conv2 writes it. Peak use ~125.8 MB.
  float* ws = (float*)d_ws;
  const size_t M = 1048576;
  float* left   = ws;            // 1M floats
  float* right  = ws + M;        // 1M
  float* OP     = ws + 2 * M;    // 4M  (strip: 16*256 pixels x 1024)
  float* outraw = ws + 6 * M;    // 8M
  float* pbuf   = ws + 14 * M;   // 8M  (planar p, residual input)
  float* h1     = ws + 22 * M;   // 8M
  float* h2     = ws;            // 8M  (reuse)
  float* stats  = ws + 30 * M;   // 512

  k_ln_proj<<<dim3(NS * LL), dim3(256), 0, stream>>>(msa, ln_g, ln_b, Wl, bl, Wr, br, left, right);

  for (int sb = 0; sb < 16; ++sb) {
    k_outer<<<dim3(64, 16), dim3(256), 0, stream>>>(left, right, OP, sb * 16);
    k_proj_out<<<dim3(256), dim3(256), 0, stream>>>(OP, Wo, bo, outraw, sb * 16);
  }

  k_projdown_trans<<<dim3(2048), dim3(256), 0, stream>>>(outraw, pair, Wd, bd, pbuf);

  k_conv3x3<<<dim3(16, 16, 4), dim3(256), 0, stream>>>(pbuf, conv1, h1);
  k_instat<<<dim3(128), dim3(256), 0, stream>>>(h1, stats);
  k_in_elu<<<dim3(8192), dim3(256), 0, stream>>>(h1, stats, in1_g, in1_b);

  k_conv3x3<<<dim3(16, 16, 4), dim3(256), 0, stream>>>(h1, conv2, h2);
  k_instat<<<dim3(128), dim3(256), 0, stream>>>(h2, stats + 256);

  k_final<<<dim3(8, 256), dim3(256), 0, stream>>>(pbuf, h2, stats + 256, in2_g, in2_b, out);
}

// Round 2
// 581.643 us; speedup vs baseline: 3.5801x; 3.5801x over previous
//
#include <hip/hip_runtime.h>
#include <math.h>

#define LL 256      // L
#define NS 128      // N sequences
#define DM 256      // d_msa
#define DH 32       // d_h
#define DP 128      // d_pair
#define HW 65536    // L*L

using u16 = unsigned short;
typedef __attribute__((ext_vector_type(8))) short s8v;   // 8 bf16 (A/B frag)
typedef __attribute__((ext_vector_type(4))) short s4v;   // 4 bf16 (packed store)
typedef __attribute__((ext_vector_type(4))) float f4v;   // C/D frag

#define MFMA(a, b, c) __builtin_amdgcn_mfma_f32_16x16x32_bf16((a), (b), (c), 0, 0, 0)

__device__ __forceinline__ u16 f2bf(float f) {
  unsigned u = __float_as_uint(f);
  u = (u + 0x7FFFu + ((u >> 16) & 1u)) >> 16;   // RNE
  return (u16)u;
}
__device__ __forceinline__ float bf2f(u16 h) { return __uint_as_float(((unsigned)h) << 16); }
__device__ __forceinline__ float elu1(float v) { return v > 0.f ? v : expm1f(v); }

// ---------------------------------------------------------------------------
// P1: WlrT[n][k] bf16, n<32 -> Wl col n ; n>=32 -> Wr col n-32.  grid 64.
// ---------------------------------------------------------------------------
__global__ __launch_bounds__(256) void k_prep_wlr(const float* __restrict__ Wl,
                                                  const float* __restrict__ Wr,
                                                  u16* __restrict__ WlrT)
{
  int idx = blockIdx.x * 256 + threadIdx.x;     // 16384
  int n = idx >> 8, k = idx & 255;
  float v = (n < 32) ? Wl[k * DH + n] : Wr[k * DH + (n - 32)];
  WlrT[n * 256 + k] = f2bf(v);
}

// ---------------------------------------------------------------------------
// P2: WoT[c][j*32+i] = Wo[(i*32+j)*128 + c]  (bf16, B^T layout, K-permuted).
// grid 512.
// ---------------------------------------------------------------------------
__global__ __launch_bounds__(256) void k_prep_wo(const float* __restrict__ Wo,
                                                 u16* __restrict__ WoT)
{
  int idx = blockIdx.x * 256 + threadIdx.x;     // 131072
  int c = idx >> 10, kp = idx & 1023;
  int i = kp & 31, j = kp >> 5;
  WoT[idx] = f2bf(Wo[(size_t)(i * 32 + j) * DP + c]);
}

// ---------------------------------------------------------------------------
// P3: pack conv weights into MFMA B-fragment order:
// 16B unit idx = ((tap*4+kk)*128 + co)*4 + h ; elem j: w[co][kk*32+h*8+j][tap]
// grid 72 (one conv).
// ---------------------------------------------------------------------------
__global__ __launch_bounds__(256) void k_prep_convw(const float* __restrict__ w,
                                                    u16* __restrict__ wP)
{
  int idx = blockIdx.x * 256 + threadIdx.x;     // 18432 = 9*4*128*4
  int h = idx & 3, co = (idx >> 2) & 127, kk = (idx >> 9) & 3, tap = idx >> 11;
  s8v o;
  #pragma unroll
  for (int j = 0; j < 8; ++j) {
    int ci = kk * 32 + h * 8 + j;
    o[j] = (short)f2bf(w[((size_t)co * DP + ci) * 9 + tap]);
  }
  *(s8v*)(wP + (size_t)idx * 8) = o;
}

// ---------------------------------------------------------------------------
// K1: LayerNorm over d_msa -> msaN bf16 [32768][256]. grid 8192 (4 rows/blk).
// ---------------------------------------------------------------------------
__global__ __launch_bounds__(256) void k_ln(const float* __restrict__ msa,
                                            const float* __restrict__ g,
                                            const float* __restrict__ b,
                                            u16* __restrict__ msaN)
{
  int lane = threadIdx.x & 63, wid = threadIdx.x >> 6;
  int row = blockIdx.x * 4 + wid;
  const float4 v = ((const float4*)(msa + (size_t)row * DM))[lane];
  float s = v.x + v.y + v.z + v.w;
  float q = v.x * v.x + v.y * v.y + v.z * v.z + v.w * v.w;
  #pragma unroll
  for (int off = 32; off; off >>= 1) { s += __shfl_down(s, off); q += __shfl_down(q, off); }
  s = __shfl(s, 0); q = __shfl(q, 0);
  float mean = s * (1.f / DM);
  float var  = q * (1.f / DM) - mean * mean;
  float rstd = rsqrtf(var + 1e-5f);
  const float4 gv = ((const float4*)g)[lane];
  const float4 bv = ((const float4*)b)[lane];
  s4v o;
  o[0] = (short)f2bf((v.x - mean) * rstd * gv.x + bv.x);
  o[1] = (short)f2bf((v.y - mean) * rstd * gv.y + bv.y);
  o[2] = (short)f2bf((v.z - mean) * rstd * gv.z + bv.z);
  o[3] = (short)f2bf((v.w - mean) * rstd * gv.w + bv.w);
  *(s4v*)(msaN + (size_t)row * DM + lane * 4) = o;
}

// ---------------------------------------------------------------------------
// K2: [32768 x 256] @ [256 x 64] -> leftT/rightT bf16 (M-major, K=s contig).
// Block = one s (256 rows). 4 waves x (64 rows x 64 cols). grid 128.
// leftT[(l*32+i)*128 + s], rightT[(m*32+j)*128 + s] (x 1/N).
// ---------------------------------------------------------------------------
__global__ __launch_bounds__(256) void k_gemm_lr(const u16* __restrict__ msaN,
                                                 const u16* __restrict__ WlrT,
                                                 const float* __restrict__ bl,
                                                 const float* __restrict__ br,
                                                 u16* __restrict__ leftT,
                                                 u16* __restrict__ rightT)
{
  int lane = threadIdx.x & 63, wid = threadIdx.x >> 6;
  int sIdx = blockIdx.x;
  size_t rowBase = (size_t)sIdx * 256 + wid * 64;
  f4v acc[4][4] = {};
  #pragma unroll
  for (int ks = 0; ks < 8; ++ks) {
    int k = ks * 32 + (lane >> 4) * 8;
    s8v a[4], bb[4];
    #pragma unroll
    for (int mi = 0; mi < 4; ++mi)
      a[mi] = *(const s8v*)(msaN + (rowBase + mi * 16 + (lane & 15)) * 256 + k);
    #pragma unroll
    for (int ni = 0; ni < 4; ++ni)
      bb[ni] = *(const s8v*)(WlrT + (size_t)(ni * 16 + (lane & 15)) * 256 + k);
    #pragma unroll
    for (int mi = 0; mi < 4; ++mi)
      #pragma unroll
      for (int ni = 0; ni < 4; ++ni)
        acc[mi][ni] = MFMA(a[mi], bb[ni], acc[mi][ni]);
  }
  #pragma unroll
  for (int mi = 0; mi < 4; ++mi) {
    #pragma unroll
    for (int ni = 0; ni < 4; ++ni) {
      int n = ni * 16 + (lane & 15);
      #pragma unroll
      for (int r = 0; r < 4; ++r) {
        int l = wid * 64 + mi * 16 + (lane >> 4) * 4 + r;
        float v = acc[mi][ni][r];
        if (n < 32) {
          leftT[((size_t)l * 32 + n) * 128 + sIdx] = f2bf(v + bl[n]);
        } else {
          rightT[((size_t)l * 32 + (n - 32)) * 128 + sIdx] =
              f2bf((v + br[n - 32]) * (1.f / NS));
        }
      }
    }
  }
}

// ---------------------------------------------------------------------------
// K3 (GEMM1, per 64-l strip): op = leftT^strip (2048 x 128K) x rightT^T (8192).
// Frags straight from L2 (no LDS). Block 128x128, waves 2x2 (64x64 each).
// Output: OPb[(lLoc*256+m)][j*32+i] bf16 (packed 4-i stores).
// grid (64, 16).
// ---------------------------------------------------------------------------
__global__ __launch_bounds__(256) void k_gemm1(const u16* __restrict__ leftT,
                                               const u16* __restrict__ rightT,
                                               u16* __restrict__ OPb, int lBase)
{
  int lane = threadIdx.x & 63, wid = threadIdx.x >> 6;
  int wr = wid >> 1, wc = wid & 1;
  int m0 = blockIdx.y * 128 + wr * 64;       // strip M (= lLoc*32+i), 0..2047
  int n0 = blockIdx.x * 128 + wc * 64;       // N (= m*32+j), 0..8191
  const u16* Abase = leftT + (size_t)lBase * 32 * 128;
  f4v acc[4][4] = {};
  #pragma unroll
  for (int ks = 0; ks < 4; ++ks) {
    int k = ks * 32 + (lane >> 4) * 8;
    s8v a[4], bb[4];
    #pragma unroll
    for (int mi = 0; mi < 4; ++mi)
      a[mi] = *(const s8v*)(Abase + (size_t)(m0 + mi * 16 + (lane & 15)) * 128 + k);
    #pragma unroll
    for (int ni = 0; ni < 4; ++ni)
      bb[ni] = *(const s8v*)(rightT + (size_t)(n0 + ni * 16 + (lane & 15)) * 128 + k);
    #pragma unroll
    for (int mi = 0; mi < 4; ++mi)
      #pragma unroll
      for (int ni = 0; ni < 4; ++ni)
        acc[mi][ni] = MFMA(a[mi], bb[ni], acc[mi][ni]);
  }
  #pragma unroll
  for (int mi = 0; mi < 4; ++mi) {
    int mrow = m0 + mi * 16 + (lane >> 4) * 4;
    int lLoc = mrow >> 5, i0 = mrow & 31;
    #pragma unroll
    for (int ni = 0; ni < 4; ++ni) {
      int n = n0 + ni * 16 + (lane & 15);
      int mpix = n >> 5, j = n & 31;
      s4v o;
      #pragma unroll
      for (int r = 0; r < 4; ++r) o[r] = (short)f2bf(acc[mi][ni][r]);
      *(s4v*)(OPb + ((size_t)lLoc * 256 + mpix) * 1024 + j * 32 + i0) = o;
    }
  }
}

// ---------------------------------------------------------------------------
// K4 (GEMM2, per strip): outbf[pix][c] = OPb[pix][1024k] @ WoT + bo.
// Block BM=64 x BN=128, waves 2x2 (32 x 64). Frags from L2/L3. grid 256.
// ---------------------------------------------------------------------------
__global__ __launch_bounds__(256) void k_gemm2(const u16* __restrict__ OPb,
                                               const u16* __restrict__ WoT,
                                               const float* __restrict__ bo,
                                               u16* __restrict__ outbf, int pixBase)
{
  int lane = threadIdx.x & 63, wid = threadIdx.x >> 6;
  int wr = wid >> 1, wc = wid & 1;
  int m0 = blockIdx.x * 64 + wr * 32;        // strip pixel, 0..16383
  int n0 = wc * 64;
  f4v acc[2][4] = {};
  #pragma unroll 4
  for (int ks = 0; ks < 32; ++ks) {
    int k = ks * 32 + (lane >> 4) * 8;
    s8v a[2], bb[4];
    #pragma unroll
    for (int mi = 0; mi < 2; ++mi)
      a[mi] = *(const s8v*)(OPb + (size_t)(m0 + mi * 16 + (lane & 15)) * 1024 + k);
    #pragma unroll
    for (int ni = 0; ni < 4; ++ni)
      bb[ni] = *(const s8v*)(WoT + (size_t)(n0 + ni * 16 + (lane & 15)) * 1024 + k);
    #pragma unroll
    for (int mi = 0; mi < 2; ++mi)
      #pragma unroll
      for (int ni = 0; ni < 4; ++ni)
        acc[mi][ni] = MFMA(a[mi], bb[ni], acc[mi][ni]);
  }
  #pragma unroll
  for (int mi = 0; mi < 2; ++mi) {
    #pragma unroll
    for (int ni = 0; ni < 4; ++ni) {
      int c = n0 + ni * 16 + (lane & 15);
      float bias = bo[c];
      #pragma unroll
      for (int r = 0; r < 4; ++r) {
        int pix = pixBase + m0 + mi * 16 + (lane >> 4) * 4 + r;
        outbf[(size_t)pix * DP + c] = f2bf(acc[mi][ni][r] + bias);
      }
    }
  }
}

// ---------------------------------------------------------------------------
// K5: p = concat(pair, out) @ Wd + bd, fused NHWC -> planar. grid 2048.
// ---------------------------------------------------------------------------
__global__ __launch_bounds__(256) void k_projdown_trans(
    const u16* __restrict__ outbf, const float* __restrict__ pairin,
    const float* __restrict__ Wd, const float* __restrict__ bd,
    float* __restrict__ pplanar)
{
  __shared__ alignas(16) float pairT[32 * 128];
  __shared__ alignas(16) float outT[32 * 128];
  __shared__ alignas(16) float res[32 * 132];
  int t = threadIdx.x;
  int pix0 = blockIdx.x * 32;
  #pragma unroll
  for (int k = 0; k < 4; ++k) {
    int off = (t + 256 * k) * 4;
    *(float4*)&pairT[off] = *(const float4*)&pairin[(size_t)pix0 * DP + off];
  }
  #pragma unroll
  for (int k = 0; k < 2; ++k) {
    int off = (t + 256 * k) * 8;
    uint4 u = *(const uint4*)(outbf + (size_t)pix0 * DP + off);
    outT[off + 0] = bf2f((u16)(u.x & 0xffff)); outT[off + 1] = bf2f((u16)(u.x >> 16));
    outT[off + 2] = bf2f((u16)(u.y & 0xffff)); outT[off + 3] = bf2f((u16)(u.y >> 16));
    outT[off + 4] = bf2f((u16)(u.z & 0xffff)); outT[off + 5] = bf2f((u16)(u.z >> 16));
    outT[off + 6] = bf2f((u16)(u.w & 0xffff)); outT[off + 7] = bf2f((u16)(u.w >> 16));
  }
  __syncthreads();
  int c4 = (t & 31) * 4;
  int pg = (t >> 5) * 4;
  float acc[4][4];
  const float4 bv = *(const float4*)&bd[c4];
  #pragma unroll
  for (int q = 0; q < 4; ++q) { acc[q][0] = bv.x; acc[q][1] = bv.y; acc[q][2] = bv.z; acc[q][3] = bv.w; }
  for (int k = 0; k < 128; ++k) {
    const float4 w = *(const float4*)&Wd[(size_t)k * DP + c4];
    #pragma unroll
    for (int q = 0; q < 4; ++q) {
      float a = pairT[(pg + q) * 128 + k];
      acc[q][0] += a * w.x; acc[q][1] += a * w.y; acc[q][2] += a * w.z; acc[q][3] += a * w.w;
    }
  }
  for (int k = 0; k < 128; ++k) {
    const float4 w = *(const float4*)&Wd[(size_t)(128 + k) * DP + c4];
    #pragma unroll
    for (int q = 0; q < 4; ++q) {
      float a = outT[(pg + q) * 128 + k];
      acc[q][0] += a * w.x; acc[q][1] += a * w.y; acc[q][2] += a * w.z; acc[q][3] += a * w.w;
    }
  }
  #pragma unroll
  for (int q = 0; q < 4; ++q) {
    float4 r; r.x = acc[q][0]; r.y = acc[q][1]; r.z = acc[q][2]; r.w = acc[q][3];
    *(float4*)&res[(pg + q) * 132 + c4] = r;
  }
  __syncthreads();
  int y = pix0 >> 8, x0 = pix0 & 255;
  #pragma unroll
  for (int k = 0; k < 16; ++k) {
    int idx = k * 256 + t;
    int c = idx >> 5, xl = idx & 31;
    pplanar[(size_t)c * HW + y * LL + x0 + xl] = res[xl * 132 + c];
  }
}

// ---------------------------------------------------------------------------
// K6: conv3x3 via implicit-GEMM MFMA. Block: one y-row, 64 px, all 128 co.
// LDS: [3 rows][66 px][136-pad ci] bf16. 4 waves = 4 co-strips of 32.
// grid (4, 256).
// ---------------------------------------------------------------------------
__global__ __launch_bounds__(256) void k_conv_mfma(const float* __restrict__ in,
                                                   const u16* __restrict__ wP,
                                                   float* __restrict__ out)
{
  __shared__ alignas(16) u16 Ast[3 * 66 * 136];
  int t = threadIdx.x;
  int lane = t & 63, wid = t >> 6;
  int x0 = blockIdx.x * 64, y = blockIdx.y;
  for (int e = t; e < 3 * 128 * 66; e += 256) {
    int r = e / 8448; int rem = e - r * 8448;
    int ci = rem / 66; int p = rem - ci * 66;
    int gy = y + r - 1, gx = x0 - 1 + p;
    float v = 0.f;
    if ((unsigned)gy < 256u && (unsigned)gx < 256u)
      v = in[(size_t)ci * HW + gy * LL + gx];
    Ast[(r * 66 + p) * 136 + ci] = f2bf(v);
  }
  __syncthreads();
  int co0 = wid * 32;
  f4v acc[4][2] = {};
  #pragma unroll
  for (int tap = 0; tap < 9; ++tap) {
    int dy = tap / 3, dx = tap - dy * 3;
    #pragma unroll
    for (int kk = 0; kk < 4; ++kk) {
      int k = kk * 32 + (lane >> 4) * 8;
      s8v a[4], bb[2];
      #pragma unroll
      for (int mi = 0; mi < 4; ++mi) {
        int p = mi * 16 + (lane & 15) + dx;
        a[mi] = *(const s8v*)&Ast[(dy * 66 + p) * 136 + k];
      }
      #pragma unroll
      for (int ni = 0; ni < 2; ++ni) {
        int co = co0 + ni * 16 + (lane & 15);
        bb[ni] = *(const s8v*)(wP + ((size_t)((tap * 4 + kk) * 128 + co) * 4 + (lane >> 4)) * 8);
      }
      #pragma unroll
      for (int mi = 0; mi < 4; ++mi)
        #pragma unroll
        for (int ni = 0; ni < 2; ++ni)
          acc[mi][ni] = MFMA(a[mi], bb[ni], acc[mi][ni]);
    }
  }
  #pragma unroll
  for (int mi = 0; mi < 4; ++mi) {
    #pragma unroll
    for (int ni = 0; ni < 2; ++ni) {
      int co = co0 + ni * 16 + (lane & 15);
      int x = x0 + mi * 16 + (lane >> 4) * 4;
      float4 v; v.x = acc[mi][ni][0]; v.y = acc[mi][ni][1];
      v.z = acc[mi][ni][2]; v.w = acc[mi][ni][3];
      *(float4*)(out + (size_t)co * HW + (size_t)y * LL + x) = v;
    }
  }
}

// ---------------------------------------------------------------------------
// K7: per-channel instance-norm stats (mean, rstd). grid 128.
// ---------------------------------------------------------------------------
__global__ __launch_bounds__(256) void k_instat(const float* __restrict__ x, float* __restrict__ st)
{
  int c = blockIdx.x, t = threadIdx.x;
  const float4* p4 = (const float4*)(x + (size_t)c * HW);
  float s = 0, s2 = 0;
  for (int i = t; i < HW / 4; i += 256) {
    float4 v = p4[i];
    s  += v.x + v.y + v.z + v.w;
    s2 += v.x * v.x + v.y * v.y + v.z * v.z + v.w * v.w;
  }
  #pragma unroll
  for (int off = 32; off; off >>= 1) { s += __shfl_down(s, off); s2 += __shfl_down(s2, off); }
  __shared__ float red[8];
  int lane = t & 63, w = t >> 6;
  if (lane == 0) { red[w] = s; red[4 + w] = s2; }
  __syncthreads();
  if (t == 0) {
    s  = red[0] + red[1] + red[2] + red[3];
    s2 = red[4] + red[5] + red[6] + red[7];
    float m = s * (1.f / HW);
    float var = s2 * (1.f / HW) - m * m;
    st[c] = m;
    st[128 + c] = rsqrtf(var + 1e-6f);
  }
}

// ---------------------------------------------------------------------------
// K8: h = elu(IN(h)) in place (planar). grid 8192.
// ---------------------------------------------------------------------------
__global__ __launch_bounds__(256) void k_in_elu(float* __restrict__ h, const float* __restrict__ st,
                                                const float* __restrict__ g, const float* __restrict__ b)
{
  int i = blockIdx.x * 256 + threadIdx.x;
  int c = i >> 14;
  float m = st[c], r = st[128 + c];
  float sc = r * g[c], bb = b[c] - m * sc;
  float4* p = (float4*)h;
  float4 v = p[i];
  v.x = elu1(v.x * sc + bb);
  v.y = elu1(v.y * sc + bb);
  v.z = elu1(v.z * sc + bb);
  v.w = elu1(v.w * sc + bb);
  p[i] = v;
}

// ---------------------------------------------------------------------------
// K9: out_nhwc = elu(p + IN2(h2)). grid (8, 256).
// ---------------------------------------------------------------------------
__global__ __launch_bounds__(256) void k_final(
    const float* __restrict__ pbuf, const float* __restrict__ h2, const float* __restrict__ st,
    const float* __restrict__ g, const float* __restrict__ b, float* __restrict__ out)
{
  __shared__ float lds[128 * 33];
  int t = threadIdx.x;
  int x0 = blockIdx.x * 32, y = blockIdx.y;
  #pragma unroll
  for (int k = 0; k < 16; ++k) {
    int idx = k * 256 + t;
    int c = idx >> 5, xl = idx & 31;
    size_t gi = (size_t)c * HW + y * LL + x0 + xl;
    float hv = (h2[gi] - st[c]) * st[128 + c] * g[c] + b[c];
    float v = pbuf[gi] + hv;
    lds[c * 33 + xl] = v > 0.f ? v : expm1f(v);
  }
  __syncthreads();
  #pragma unroll
  for (int k = 0; k < 16; ++k) {
    int idx = k * 256 + t;
    int px = idx >> 7, c = idx & 127;
    out[((size_t)(y * LL) + x0 + px) * DP + c] = lds[c * 33 + px];
  }
}

// ---------------------------------------------------------------------------
extern "C" void kernel_launch(void* const* d_in, const int* in_sizes, int n_in,
                              void* d_out, int out_size, void* d_ws, size_t ws_size,
                              hipStream_t stream)
{
  const float* msa   = (const float*)d_in[0];
  const float* pair  = (const float*)d_in[1];
  const float* ln_g  = (const float*)d_in[2];
  const float* ln_b  = (const float*)d_in[3];
  const float* Wl    = (const float*)d_in[4];
  const float* bl    = (const float*)d_in[5];
  const float* Wr    = (const float*)d_in[6];
  const float* br    = (const float*)d_in[7];
  const float* Wo    = (const float*)d_in[8];
  const float* bo    = (const float*)d_in[9];
  const float* Wd    = (const float*)d_in[10];
  const float* bd    = (const float*)d_in[11];
  const float* conv1 = (const float*)d_in[12];
  const float* in1_g = (const float*)d_in[13];
  const float* in1_b = (const float*)d_in[14];
  const float* conv2 = (const float*)d_in[15];
  const float* in2_g = (const float*)d_in[16];
  const float* in2_b = (const float*)d_in[17];
  float* out = (float*)d_out;

  // Workspace layout (float units, F = 1Mi floats). Temporal reuse:
  //  [0,4M)   msaN (bf16)        -> later h1 [0,8M)
  //  [4M,5M)  leftT/rightT(bf16) -> (dead before conv1)
  //  [5M,13M) OPb strip (bf16)   -> later h2 [8M,16M)
  //  [13M,17M) outbf (bf16)      -> (dead before conv2)
  //  [17M,25M) pbuf (f32, live to end)
  //  [25M,26M) packed weights;  [26M,+512) stats.   Peak ~104 MB.
  float* ws = (float*)d_ws;
  const size_t F = 1048576;
  u16* msaN   = (u16*)ws;
  u16* leftT  = (u16*)(ws + 4 * F);
  u16* rightT = (u16*)(ws + 4 * F + F / 2);
  u16* OPb    = (u16*)(ws + 5 * F);
  u16* outbf  = (u16*)(ws + 13 * F);
  float* pbuf = ws + 17 * F;
  float* h1   = ws;
  float* h2   = ws + 8 * F;
  u16* aux    = (u16*)(ws + 25 * F);
  u16* wP1    = aux;                 // 147456 u16
  u16* wP2    = aux + 147456;        // 147456
  u16* WoT    = aux + 294912;        // 131072
  u16* WlrT   = aux + 425984;        // 16384
  float* stats = ws + 26 * F;        // 512

  k_prep_wlr<<<dim3(64), dim3(256), 0, stream>>>(Wl, Wr, WlrT);
  k_prep_wo<<<dim3(512), dim3(256), 0, stream>>>(Wo, WoT);
  k_prep_convw<<<dim3(72), dim3(256), 0, stream>>>(conv1, wP1);
  k_prep_convw<<<dim3(72), dim3(256), 0, stream>>>(conv2, wP2);

  k_ln<<<dim3(8192), dim3(256), 0, stream>>>(msa, ln_g, ln_b, msaN);
  k_gemm_lr<<<dim3(128), dim3(256), 0, stream>>>(msaN, WlrT, bl, br, leftT, rightT);

  for (int s = 0; s < 4; ++s) {
    k_gemm1<<<dim3(64, 16), dim3(256), 0, stream>>>(leftT, rightT, OPb, s * 64);
    k_gemm2<<<dim3(256), dim3(256), 0, stream>>>(OPb, WoT, bo, outbf, s * 16384);
  }

  k_projdown_trans<<<dim3(2048), dim3(256), 0, stream>>>(outbf, pair, Wd, bd, pbuf);

  k_conv_mfma<<<dim3(4, 256), dim3(256), 0, stream>>>(pbuf, wP1, h1);
  k_instat<<<dim3(128), dim3(256), 0, stream>>>(h1, stats);
  k_in_elu<<<dim3(8192), dim3(256), 0, stream>>>(h1, stats, in1_g, in1_b);

  k_conv_mfma<<<dim3(4, 256), dim3(256), 0, stream>>>(h1, wP2, h2);
  k_instat<<<dim3(128), dim3(256), 0, stream>>>(h2, stats + 256);

  k_final<<<dim3(8, 256), dim3(256), 0, stream>>>(pbuf, h2, stats + 256, in2_g, in2_b, out);
}

// Round 3
// 375.582 us; speedup vs baseline: 5.5444x; 1.5486x over previous
//
#include <hip/hip_runtime.h>
#include <math.h>

#define LL 256      // L
#define NS 128      // N sequences
#define DM 256      // d_msa
#define DH 32       // d_h
#define DP 128      // d_pair
#define HW 65536    // L*L

using u16 = unsigned short;
typedef __attribute__((ext_vector_type(8))) short s8v;   // 8 bf16 (A/B frag)
typedef __attribute__((ext_vector_type(4))) short s4v;   // 4 bf16 (packed store)
typedef __attribute__((ext_vector_type(4))) float f4v;   // C/D frag

#define MFMA(a, b, c) __builtin_amdgcn_mfma_f32_16x16x32_bf16((a), (b), (c), 0, 0, 0)

__device__ __forceinline__ u16 f2bf(float f) {
  unsigned u = __float_as_uint(f);
  u = (u + 0x7FFFu + ((u >> 16) & 1u)) >> 16;   // RNE
  return (u16)u;
}
__device__ __forceinline__ float bf2f(u16 h) { return __uint_as_float(((unsigned)h) << 16); }
__device__ __forceinline__ float elu1(float v) { return v > 0.f ? v : expm1f(v); }
__device__ __forceinline__ s8v zero8() {
  s8v v;
  #pragma unroll
  for (int j = 0; j < 8; ++j) v[j] = 0;
  return v;
}
__device__ __forceinline__ unsigned pack2(float a, float b) {
  return (unsigned)f2bf(a) | ((unsigned)f2bf(b) << 16);
}

// ---------------------------------------------------------------------------
// P1: WlrT[n][k] bf16, n<32 -> Wl col n ; n>=32 -> Wr col n-32.  grid 64.
// ---------------------------------------------------------------------------
__global__ __launch_bounds__(256) void k_prep_wlr(const float* __restrict__ Wl,
                                                  const float* __restrict__ Wr,
                                                  u16* __restrict__ WlrT)
{
  int idx = blockIdx.x * 256 + threadIdx.x;     // 16384
  int n = idx >> 8, k = idx & 255;
  float v = (n < 32) ? Wl[k * DH + n] : Wr[k * DH + (n - 32)];
  WlrT[n * 256 + k] = f2bf(v);
}

// ---------------------------------------------------------------------------
// P2: WoT[c][j*32+i] = Wo[(i*32+j)*128 + c]  (bf16, B^T layout, K-permuted).
// grid 512.
// ---------------------------------------------------------------------------
__global__ __launch_bounds__(256) void k_prep_wo(const float* __restrict__ Wo,
                                                 u16* __restrict__ WoT)
{
  int idx = blockIdx.x * 256 + threadIdx.x;     // 131072
  int c = idx >> 10, kp = idx & 1023;
  int i = kp & 31, j = kp >> 5;
  WoT[idx] = f2bf(Wo[(size_t)(i * 32 + j) * DP + c]);
}

// ---------------------------------------------------------------------------
// P3: pack conv weights into MFMA B-fragment order.
// ---------------------------------------------------------------------------
__global__ __launch_bounds__(256) void k_prep_convw(const float* __restrict__ w,
                                                    u16* __restrict__ wP)
{
  int idx = blockIdx.x * 256 + threadIdx.x;     // 18432 = 9*4*128*4
  int h = idx & 3, co = (idx >> 2) & 127, kk = (idx >> 9) & 3, tap = idx >> 11;
  s8v o;
  #pragma unroll
  for (int j = 0; j < 8; ++j) {
    int ci = kk * 32 + h * 8 + j;
    o[j] = (short)f2bf(w[((size_t)co * DP + ci) * 9 + tap]);
  }
  *(s8v*)(wP + (size_t)idx * 8) = o;
}

// ---------------------------------------------------------------------------
// P4: WdT[n][k] = Wd[k][n] bf16. grid 128.
// ---------------------------------------------------------------------------
__global__ __launch_bounds__(256) void k_prep_wdt(const float* __restrict__ Wd,
                                                  u16* __restrict__ WdT)
{
  int idx = blockIdx.x * 256 + threadIdx.x;     // 32768
  int n = idx >> 8, k = idx & 255;
  WdT[idx] = f2bf(Wd[(size_t)k * DP + n]);
}

// ---------------------------------------------------------------------------
// P5: pair f32 -> bf16 (NHWC already). grid 8192.
// ---------------------------------------------------------------------------
__global__ __launch_bounds__(256) void k_pair2bf(const float* __restrict__ pair,
                                                 u16* __restrict__ pairb)
{
  int i = blockIdx.x * 256 + threadIdx.x;       // float4 idx, 2097152
  float4 v = ((const float4*)pair)[i];
  uint2 o; o.x = pack2(v.x, v.y); o.y = pack2(v.z, v.w);
  ((uint2*)pairb)[i] = o;
}

// ---------------------------------------------------------------------------
// K1: LayerNorm over d_msa -> msaN bf16 [32768][256]. grid 8192.
// ---------------------------------------------------------------------------
__global__ __launch_bounds__(256) void k_ln(const float* __restrict__ msa,
                                            const float* __restrict__ g,
                                            const float* __restrict__ b,
                                            u16* __restrict__ msaN)
{
  int lane = threadIdx.x & 63, wid = threadIdx.x >> 6;
  int row = blockIdx.x * 4 + wid;
  const float4 v = ((const float4*)(msa + (size_t)row * DM))[lane];
  float s = v.x + v.y + v.z + v.w;
  float q = v.x * v.x + v.y * v.y + v.z * v.z + v.w * v.w;
  #pragma unroll
  for (int off = 32; off; off >>= 1) { s += __shfl_down(s, off); q += __shfl_down(q, off); }
  s = __shfl(s, 0); q = __shfl(q, 0);
  float mean = s * (1.f / DM);
  float var  = q * (1.f / DM) - mean * mean;
  float rstd = rsqrtf(var + 1e-5f);
  const float4 gv = ((const float4*)g)[lane];
  const float4 bv = ((const float4*)b)[lane];
  s4v o;
  o[0] = (short)f2bf((v.x - mean) * rstd * gv.x + bv.x);
  o[1] = (short)f2bf((v.y - mean) * rstd * gv.y + bv.y);
  o[2] = (short)f2bf((v.z - mean) * rstd * gv.z + bv.z);
  o[3] = (short)f2bf((v.w - mean) * rstd * gv.w + bv.w);
  *(s4v*)(msaN + (size_t)row * DM + lane * 4) = o;
}

// ---------------------------------------------------------------------------
// K2: [32768 x 256] @ [256 x 64] -> leftT/rightT bf16 (K=s contiguous).
// ---------------------------------------------------------------------------
__global__ __launch_bounds__(256) void k_gemm_lr(const u16* __restrict__ msaN,
                                                 const u16* __restrict__ WlrT,
                                                 const float* __restrict__ bl,
                                                 const float* __restrict__ br,
                                                 u16* __restrict__ leftT,
                                                 u16* __restrict__ rightT)
{
  int lane = threadIdx.x & 63, wid = threadIdx.x >> 6;
  int sIdx = blockIdx.x;
  size_t rowBase = (size_t)sIdx * 256 + wid * 64;
  f4v acc[4][4] = {};
  #pragma unroll
  for (int ks = 0; ks < 8; ++ks) {
    int k = ks * 32 + (lane >> 4) * 8;
    s8v a[4], bb[4];
    #pragma unroll
    for (int mi = 0; mi < 4; ++mi)
      a[mi] = *(const s8v*)(msaN + (rowBase + mi * 16 + (lane & 15)) * 256 + k);
    #pragma unroll
    for (int ni = 0; ni < 4; ++ni)
      bb[ni] = *(const s8v*)(WlrT + (size_t)(ni * 16 + (lane & 15)) * 256 + k);
    #pragma unroll
    for (int mi = 0; mi < 4; ++mi)
      #pragma unroll
      for (int ni = 0; ni < 4; ++ni)
        acc[mi][ni] = MFMA(a[mi], bb[ni], acc[mi][ni]);
  }
  #pragma unroll
  for (int mi = 0; mi < 4; ++mi) {
    #pragma unroll
    for (int ni = 0; ni < 4; ++ni) {
      int n = ni * 16 + (lane & 15);
      #pragma unroll
      for (int r = 0; r < 4; ++r) {
        int l = wid * 64 + mi * 16 + (lane >> 4) * 4 + r;
        float v = acc[mi][ni][r];
        if (n < 32) {
          leftT[((size_t)l * 32 + n) * 128 + sIdx] = f2bf(v + bl[n]);
        } else {
          rightT[((size_t)l * 32 + (n - 32)) * 128 + sIdx] =
              f2bf((v + br[n - 32]) * (1.f / NS));
        }
      }
    }
  }
}

// ---------------------------------------------------------------------------
// K3 (GEMM1, per 64-l strip): LDS-staged 128x128 tile, K=128 single shot.
// grid (64, 16). Output OPb[(lLoc*256+m)][j*32+i] bf16.
// ---------------------------------------------------------------------------
__global__ __launch_bounds__(256) void k_gemm1(const u16* __restrict__ leftT,
                                               const u16* __restrict__ rightT,
                                               u16* __restrict__ OPb, int lBase)
{
  __shared__ alignas(16) u16 At[128 * 128];
  __shared__ alignas(16) u16 Bt[128 * 128];
  int t = threadIdx.x;
  int lane = t & 63, wid = t >> 6;
  int wr = wid >> 1, wc = wid & 1;
  int m0 = blockIdx.y * 128;
  int n0 = blockIdx.x * 128;
  const u16* Asrc = leftT + ((size_t)lBase * 32 + m0) * 128;
  const u16* Bsrc = rightT + (size_t)n0 * 128;
  #pragma unroll
  for (int i = 0; i < 8; ++i) {
    int u = t + 256 * i;
    int row = u >> 4;
    int lb = (u * 16) ^ ((row & 7) << 4);
    *(s8v*)((char*)At + lb) = *(const s8v*)(Asrc + u * 8);
    *(s8v*)((char*)Bt + lb) = *(const s8v*)(Bsrc + u * 8);
  }
  __syncthreads();
  f4v acc[4][4] = {};
  #pragma unroll
  for (int ks = 0; ks < 4; ++ks) {
    int kb = ks * 64 + (lane >> 4) * 16;      // byte offset in row
    s8v a[4], bb[4];
    #pragma unroll
    for (int mi = 0; mi < 4; ++mi) {
      int row = wr * 64 + mi * 16 + (lane & 15);
      a[mi] = *(const s8v*)((char*)At + ((row * 256 + kb) ^ ((row & 7) << 4)));
    }
    #pragma unroll
    for (int ni = 0; ni < 4; ++ni) {
      int row = wc * 64 + ni * 16 + (lane & 15);
      bb[ni] = *(const s8v*)((char*)Bt + ((row * 256 + kb) ^ ((row & 7) << 4)));
    }
    #pragma unroll
    for (int mi = 0; mi < 4; ++mi)
      #pragma unroll
      for (int ni = 0; ni < 4; ++ni)
        acc[mi][ni] = MFMA(a[mi], bb[ni], acc[mi][ni]);
  }
  #pragma unroll
  for (int mi = 0; mi < 4; ++mi) {
    int mrow = m0 + wr * 64 + mi * 16 + (lane >> 4) * 4;
    int lLoc = mrow >> 5, i0 = mrow & 31;
    #pragma unroll
    for (int ni = 0; ni < 4; ++ni) {
      int n = n0 + wc * 64 + ni * 16 + (lane & 15);
      int mpix = n >> 5, j = n & 31;
      s4v o;
      #pragma unroll
      for (int r = 0; r < 4; ++r) o[r] = (short)f2bf(acc[mi][ni][r]);
      *(s4v*)(OPb + ((size_t)lLoc * 256 + mpix) * 1024 + j * 32 + i0) = o;
    }
  }
}

// ---------------------------------------------------------------------------
// K4 (GEMM2, per strip): outbf = OPb @ WoT + bo. BM=64, K=1024 in 8 chunks,
// A LDS-staged (swizzled), B from L2. grid 256.
// ---------------------------------------------------------------------------
__global__ __launch_bounds__(256) void k_gemm2(const u16* __restrict__ OPb,
                                               const u16* __restrict__ WoT,
                                               const float* __restrict__ bo,
                                               u16* __restrict__ outbf, int pixBase)
{
  __shared__ alignas(16) u16 At[64 * 128];   // 16 KB
  int t = threadIdx.x;
  int lane = t & 63, wid = t >> 6;
  int wr = wid >> 1, wc = wid & 1;
  int m0 = blockIdx.x * 64;
  f4v acc[2][4] = {};
  for (int kc = 0; kc < 8; ++kc) {
    __syncthreads();
    #pragma unroll
    for (int i = 0; i < 4; ++i) {
      int u = t + 256 * i;
      int row = u >> 4;
      int lb = (u * 16) ^ ((row & 7) << 4);
      *(s8v*)((char*)At + lb) =
          *(const s8v*)(OPb + (size_t)(m0 + row) * 1024 + kc * 128 + (u & 15) * 8);
    }
    __syncthreads();
    #pragma unroll
    for (int ks = 0; ks < 4; ++ks) {
      int kb = ks * 64 + (lane >> 4) * 16;
      s8v a[2], bb[4];
      #pragma unroll
      for (int mi = 0; mi < 2; ++mi) {
        int row = wr * 32 + mi * 16 + (lane & 15);
        a[mi] = *(const s8v*)((char*)At + ((row * 256 + kb) ^ ((row & 7) << 4)));
      }
      #pragma unroll
      for (int ni = 0; ni < 4; ++ni) {
        int n = wc * 64 + ni * 16 + (lane & 15);
        bb[ni] = *(const s8v*)(WoT + (size_t)n * 1024 + kc * 128 + ks * 32 + (lane >> 4) * 8);
      }
      #pragma unroll
      for (int mi = 0; mi < 2; ++mi)
        #pragma unroll
        for (int ni = 0; ni < 4; ++ni)
          acc[mi][ni] = MFMA(a[mi], bb[ni], acc[mi][ni]);
    }
  }
  #pragma unroll
  for (int mi = 0; mi < 2; ++mi) {
    #pragma unroll
    for (int ni = 0; ni < 4; ++ni) {
      int c = wc * 64 + ni * 16 + (lane & 15);
      float bias = bo[c];
      #pragma unroll
      for (int r = 0; r < 4; ++r) {
        int pix = pixBase + m0 + wr * 32 + mi * 16 + (lane >> 4) * 4 + r;
        outbf[(size_t)pix * DP + c] = f2bf(acc[mi][ni][r] + bias);
      }
    }
  }
}

// ---------------------------------------------------------------------------
// K5: proj_down as MFMA GEMM: p = [pairb|outbf] @ WdT^T + bd.
// M=65536, N=128, K=256. A,B from L2. Epilogue: pbuf planar bf16 + pN NHWC
// bf16. grid 512 (BM=128).
// ---------------------------------------------------------------------------
__global__ __launch_bounds__(256) void k_projdown2(const u16* __restrict__ pairb,
                                                   const u16* __restrict__ outbf,
                                                   const u16* __restrict__ WdT,
                                                   const float* __restrict__ bd,
                                                   u16* __restrict__ pbufB,
                                                   u16* __restrict__ pN)
{
  int t = threadIdx.x;
  int lane = t & 63, wid = t >> 6;
  int wr = wid >> 1, wc = wid & 1;
  int m0 = blockIdx.x * 128 + wr * 64;
  int n0 = wc * 64;
  f4v acc[4][4] = {};
  #pragma unroll
  for (int ks = 0; ks < 8; ++ks) {
    int k = ks * 32 + (lane >> 4) * 8;
    const u16* Abase = (k < 128) ? pairb : (outbf - 128);
    s8v a[4], bb[4];
    #pragma unroll
    for (int mi = 0; mi < 4; ++mi)
      a[mi] = *(const s8v*)(Abase + (size_t)(m0 + mi * 16 + (lane & 15)) * 128 + k);
    #pragma unroll
    for (int ni = 0; ni < 4; ++ni)
      bb[ni] = *(const s8v*)(WdT + (size_t)(n0 + ni * 16 + (lane & 15)) * 256 + k);
    #pragma unroll
    for (int mi = 0; mi < 4; ++mi)
      #pragma unroll
      for (int ni = 0; ni < 4; ++ni)
        acc[mi][ni] = MFMA(a[mi], bb[ni], acc[mi][ni]);
  }
  #pragma unroll
  for (int mi = 0; mi < 4; ++mi) {
    int pix0 = m0 + mi * 16 + (lane >> 4) * 4;
    #pragma unroll
    for (int ni = 0; ni < 4; ++ni) {
      int c = n0 + ni * 16 + (lane & 15);
      float bias = bd[c];
      s4v pk;
      #pragma unroll
      for (int r = 0; r < 4; ++r) {
        float v = acc[mi][ni][r] + bias;
        pk[r] = (short)f2bf(v);
        pN[(size_t)(pix0 + r) * DP + c] = (u16)pk[r];
      }
      *(s4v*)(pbufB + (size_t)c * HW + pix0) = pk;   // planar, 4 consecutive pix
    }
  }
}

// ---------------------------------------------------------------------------
// K6: conv3x3 implicit-GEMM MFMA. Input NHWC bf16; LDS 3x66x128 swizzled;
// output planar f32. grid (4, 256).
// ---------------------------------------------------------------------------
__global__ __launch_bounds__(256) void k_conv_mfma(const u16* __restrict__ inN,
                                                   const u16* __restrict__ wP,
                                                   float* __restrict__ out)
{
  __shared__ alignas(16) u16 Ast[3 * 66 * 128];   // 50688 B, swizzled
  int t = threadIdx.x;
  int lane = t & 63, wid = t >> 6;
  int x0 = blockIdx.x * 64, y = blockIdx.y;
  for (int u = t; u < 3168; u += 256) {           // 16B units: 3 rows x 66 px x 16
    int r = u / 1056;
    int rem = u - r * 1056;
    int p = rem >> 4, ku = rem & 15;
    int gy = y + r - 1, gx = x0 - 1 + p;
    s8v v = zero8();
    if ((unsigned)gy < 256u && (unsigned)gx < 256u)
      v = *(const s8v*)(inN + ((size_t)gy * LL + gx) * 128 + ku * 8);
    int lb = (u * 16) ^ ((p & 7) << 4);
    *(s8v*)((char*)Ast + lb) = v;
  }
  __syncthreads();
  int co0 = wid * 32;
  f4v acc[4][2] = {};
  #pragma unroll
  for (int tap = 0; tap < 9; ++tap) {
    const int dy = tap / 3, dx = tap % 3;
    #pragma unroll
    for (int kk = 0; kk < 4; ++kk) {
      s8v a[4], bb[2];
      #pragma unroll
      for (int mi = 0; mi < 4; ++mi) {
        int p = mi * 16 + (lane & 15) + dx;
        int lb = (((dy * 66 + p) * 256) + kk * 64 + (lane >> 4) * 16) ^ ((p & 7) << 4);
        a[mi] = *(const s8v*)((const char*)Ast + lb);
      }
      #pragma unroll
      for (int ni = 0; ni < 2; ++ni) {
        int co = co0 + ni * 16 + (lane & 15);
        bb[ni] = *(const s8v*)(wP + ((size_t)((tap * 4 + kk) * 128 + co) * 4 + (lane >> 4)) * 8);
      }
      #pragma unroll
      for (int mi = 0; mi < 4; ++mi)
        #pragma unroll
        for (int ni = 0; ni < 2; ++ni)
          acc[mi][ni] = MFMA(a[mi], bb[ni], acc[mi][ni]);
    }
  }
  #pragma unroll
  for (int mi = 0; mi < 4; ++mi) {
    #pragma unroll
    for (int ni = 0; ni < 2; ++ni) {
      int co = co0 + ni * 16 + (lane & 15);
      int x = x0 + mi * 16 + (lane >> 4) * 4;
      float4 v; v.x = acc[mi][ni][0]; v.y = acc[mi][ni][1];
      v.z = acc[mi][ni][2]; v.w = acc[mi][ni][3];
      *(float4*)(out + (size_t)co * HW + (size_t)y * LL + x) = v;
    }
  }
}

// ---------------------------------------------------------------------------
// K7: per-channel instance-norm stats. grid 128.
// ---------------------------------------------------------------------------
__global__ __launch_bounds__(256) void k_instat(const float* __restrict__ x, float* __restrict__ st)
{
  int c = blockIdx.x, t = threadIdx.x;
  const float4* p4 = (const float4*)(x + (size_t)c * HW);
  float s = 0, s2 = 0;
  for (int i = t; i < HW / 4; i += 256) {
    float4 v = p4[i];
    s  += v.x + v.y + v.z + v.w;
    s2 += v.x * v.x + v.y * v.y + v.z * v.z + v.w * v.w;
  }
  #pragma unroll
  for (int off = 32; off; off >>= 1) { s += __shfl_down(s, off); s2 += __shfl_down(s2, off); }
  __shared__ float red[8];
  int lane = t & 63, w = t >> 6;
  if (lane == 0) { red[w] = s; red[4 + w] = s2; }
  __syncthreads();
  if (t == 0) {
    s  = red[0] + red[1] + red[2] + red[3];
    s2 = red[4] + red[5] + red[6] + red[7];
    float m = s * (1.f / HW);
    float var = s2 * (1.f / HW) - m * m;
    st[c] = m;
    st[128 + c] = rsqrtf(var + 1e-6f);
  }
}

// ---------------------------------------------------------------------------
// K8: h1N = NHWC bf16 of elu(IN(h1)). Planar f32 read, LDS transpose.
// grid (8, 256).
// ---------------------------------------------------------------------------
__global__ __launch_bounds__(256) void k_in_elu_t(const float* __restrict__ h1,
                                                  const float* __restrict__ st,
                                                  const float* __restrict__ g,
                                                  const float* __restrict__ b,
                                                  u16* __restrict__ h1N)
{
  __shared__ float lds[128 * 33];
  int t = threadIdx.x;
  int x0 = blockIdx.x * 32, y = blockIdx.y;
  #pragma unroll
  for (int k = 0; k < 16; ++k) {
    int idx = k * 256 + t;
    int c = idx >> 5, xl = idx & 31;
    float m = st[c], r = st[128 + c];
    float sc = r * g[c], bb = b[c] - m * sc;
    float v = h1[(size_t)c * HW + y * LL + x0 + xl];
    lds[c * 33 + xl] = elu1(v * sc + bb);
  }
  __syncthreads();
  #pragma unroll
  for (int k = 0; k < 8; ++k) {
    int idx = k * 256 + t;
    int px = idx >> 6, cu = idx & 63;          // cu = c/2
    unsigned o = pack2(lds[(2 * cu) * 33 + px], lds[(2 * cu + 1) * 33 + px]);
    *(unsigned*)(h1N + ((size_t)(y * LL + x0 + px) * DP + 2 * cu)) = o;
  }
}

// ---------------------------------------------------------------------------
// K9: out_nhwc = elu(p + IN2(h2)); pbuf is planar bf16. grid (8, 256).
// ---------------------------------------------------------------------------
__global__ __launch_bounds__(256) void k_final(
    const u16* __restrict__ pbufB, const float* __restrict__ h2, const float* __restrict__ st,
    const float* __restrict__ g, const float* __restrict__ b, float* __restrict__ out)
{
  __shared__ float lds[128 * 33];
  int t = threadIdx.x;
  int x0 = blockIdx.x * 32, y = blockIdx.y;
  #pragma unroll
  for (int k = 0; k < 16; ++k) {
    int idx = k * 256 + t;
    int c = idx >> 5, xl = idx & 31;
    size_t gi = (size_t)c * HW + y * LL + x0 + xl;
    float hv = (h2[gi] - st[c]) * st[128 + c] * g[c] + b[c];
    float v = bf2f(pbufB[gi]) + hv;
    lds[c * 33 + xl] = v > 0.f ? v : expm1f(v);
  }
  __syncthreads();
  #pragma unroll
  for (int k = 0; k < 16; ++k) {
    int idx = k * 256 + t;
    int px = idx >> 7, c = idx & 127;
    out[((size_t)(y * LL) + x0 + px) * DP + c] = lds[c * 33 + px];
  }
}

// ---------------------------------------------------------------------------
extern "C" void kernel_launch(void* const* d_in, const int* in_sizes, int n_in,
                              void* d_out, int out_size, void* d_ws, size_t ws_size,
                              hipStream_t stream)
{
  const float* msa   = (const float*)d_in[0];
  const float* pair  = (const float*)d_in[1];
  const float* ln_g  = (const float*)d_in[2];
  const float* ln_b  = (const float*)d_in[3];
  const float* Wl    = (const float*)d_in[4];
  const float* bl    = (const float*)d_in[5];
  const float* Wr    = (const float*)d_in[6];
  const float* br    = (const float*)d_in[7];
  const float* Wo    = (const float*)d_in[8];
  const float* bo    = (const float*)d_in[9];
  const float* Wd    = (const float*)d_in[10];
  const float* bd    = (const float*)d_in[11];
  const float* conv1 = (const float*)d_in[12];
  const float* in1_g = (const float*)d_in[13];
  const float* in1_b = (const float*)d_in[14];
  const float* conv2 = (const float*)d_in[15];
  const float* in2_g = (const float*)d_in[16];
  const float* in2_b = (const float*)d_in[17];
  float* out = (float*)d_out;

  // Workspace layout (MB):
  //  [0,16)   msaN -> pairb -> h1N          (bf16)
  //  [16,20)  leftT + rightT                (bf16)
  //  [20,52)  OPb strip -> h1 f32
  //  [52,68)  outbf -> (h2 low half)
  //  [68,84)  pN -> (h2 high half)          ; h2 f32 = [52,84)
  //  [84,100) pbuf planar bf16 (live to end)
  //  [100,..) stats + packed weights        (~1 MB)
  float* ws = (float*)d_ws;
  const size_t F = 1048576;                  // floats per 4 MB
  u16* msaN   = (u16*)ws;
  u16* pairb  = (u16*)ws;
  u16* h1N    = (u16*)ws;
  u16* leftT  = (u16*)(ws + 4 * F);
  u16* rightT = (u16*)(ws + 4 * F + F / 2);
  u16* OPb    = (u16*)(ws + 5 * F);
  float* h1   = ws + 5 * F;
  u16* outbf  = (u16*)(ws + 13 * F);
  float* h2   = ws + 13 * F;
  u16* pN     = (u16*)(ws + 17 * F);
  u16* pbufB  = (u16*)(ws + 21 * F);
  float* stats = ws + 25 * F;                // 512 floats
  u16* aux    = (u16*)(ws + 25 * F + 512);
  u16* wP1    = aux;                         // 147456
  u16* wP2    = aux + 147456;                // 147456
  u16* WoT    = aux + 294912;                // 131072
  u16* WlrT   = aux + 425984;                // 16384
  u16* WdT    = aux + 442368;                // 32768

  k_prep_wlr<<<dim3(64), dim3(256), 0, stream>>>(Wl, Wr, WlrT);
  k_prep_wo<<<dim3(512), dim3(256), 0, stream>>>(Wo, WoT);
  k_prep_convw<<<dim3(72), dim3(256), 0, stream>>>(conv1, wP1);
  k_prep_convw<<<dim3(72), dim3(256), 0, stream>>>(conv2, wP2);
  k_prep_wdt<<<dim3(128), dim3(256), 0, stream>>>(Wd, WdT);

  k_ln<<<dim3(8192), dim3(256), 0, stream>>>(msa, ln_g, ln_b, msaN);
  k_gemm_lr<<<dim3(128), dim3(256), 0, stream>>>(msaN, WlrT, bl, br, leftT, rightT);
  k_pair2bf<<<dim3(8192), dim3(256), 0, stream>>>(pair, pairb);   // msaN dead now

  for (int s = 0; s < 4; ++s) {
    k_gemm1<<<dim3(64, 16), dim3(256), 0, stream>>>(leftT, rightT, OPb, s * 64);
    k_gemm2<<<dim3(256), dim3(256), 0, stream>>>(OPb, WoT, bo, outbf, s * 16384);
  }

  k_projdown2<<<dim3(512), dim3(256), 0, stream>>>(pairb, outbf, WdT, bd, pbufB, pN);

  k_conv_mfma<<<dim3(4, 256), dim3(256), 0, stream>>>(pN, wP1, h1);
  k_instat<<<dim3(128), dim3(256), 0, stream>>>(h1, stats);
  k_in_elu_t<<<dim3(8, 256), dim3(256), 0, stream>>>(h1, stats, in1_g, in1_b, h1N);

  k_conv_mfma<<<dim3(4, 256), dim3(256), 0, stream>>>(h1N, wP2, h2);
  k_instat<<<dim3(128), dim3(256), 0, stream>>>(h2, stats + 256);

  k_final<<<dim3(8, 256), dim3(256), 0, stream>>>(pbufB, h2, stats + 256, in2_g, in2_b, out);
}

// Round 4
// 303.807 us; speedup vs baseline: 6.8542x; 1.2363x over previous
//
#include <hip/hip_runtime.h>
#include <math.h>

#define LL 256      // L
#define NS 128      // N sequences
#define DM 256      // d_msa
#define DH 32       // d_h
#define DP 128      // d_pair
#define HW 65536    // L*L

using u16 = unsigned short;
typedef __attribute__((ext_vector_type(8))) short s8v;   // 8 bf16 (A/B frag)
typedef __attribute__((ext_vector_type(4))) short s4v;   // 4 bf16 (packed store)
typedef __attribute__((ext_vector_type(4))) float f4v;   // C/D frag

#define MFMA(a, b, c) __builtin_amdgcn_mfma_f32_16x16x32_bf16((a), (b), (c), 0, 0, 0)

__device__ __forceinline__ u16 f2bf(float f) {
  unsigned u = __float_as_uint(f);
  u = (u + 0x7FFFu + ((u >> 16) & 1u)) >> 16;   // RNE
  return (u16)u;
}
__device__ __forceinline__ float bf2f(u16 h) { return __uint_as_float(((unsigned)h) << 16); }
__device__ __forceinline__ float elu1(float v) { return v > 0.f ? v : expm1f(v); }
__device__ __forceinline__ s8v zero8() {
  s8v v;
  #pragma unroll
  for (int j = 0; j < 8; ++j) v[j] = 0;
  return v;
}
__device__ __forceinline__ unsigned pack2(float a, float b) {
  return (unsigned)f2bf(a) | ((unsigned)f2bf(b) << 16);
}

// ---------------------------------------------------------------------------
// P1: WlrT[n][k] bf16, n<32 -> Wl col n ; n>=32 -> Wr col n-32.  grid 64.
// ---------------------------------------------------------------------------
__global__ __launch_bounds__(256) void k_prep_wlr(const float* __restrict__ Wl,
                                                  const float* __restrict__ Wr,
                                                  u16* __restrict__ WlrT)
{
  int idx = blockIdx.x * 256 + threadIdx.x;     // 16384
  int n = idx >> 8, k = idx & 255;
  float v = (n < 32) ? Wl[k * DH + n] : Wr[k * DH + (n - 32)];
  WlrT[n * 256 + k] = f2bf(v);
}

// ---------------------------------------------------------------------------
// P2: WoT[c][j*32+i] = Wo[(i*32+j)*128 + c]  (bf16, B^T layout, K-permuted).
// grid 512.
// ---------------------------------------------------------------------------
__global__ __launch_bounds__(256) void k_prep_wo(const float* __restrict__ Wo,
                                                 u16* __restrict__ WoT)
{
  int idx = blockIdx.x * 256 + threadIdx.x;     // 131072
  int c = idx >> 10, kp = idx & 1023;
  int i = kp & 31, j = kp >> 5;
  WoT[idx] = f2bf(Wo[(size_t)(i * 32 + j) * DP + c]);
}

// ---------------------------------------------------------------------------
// P3: pack conv weights into MFMA B-fragment order.
// ---------------------------------------------------------------------------
__global__ __launch_bounds__(256) void k_prep_convw(const float* __restrict__ w,
                                                    u16* __restrict__ wP)
{
  int idx = blockIdx.x * 256 + threadIdx.x;     // 18432 = 9*4*128*4
  int h = idx & 3, co = (idx >> 2) & 127, kk = (idx >> 9) & 3, tap = idx >> 11;
  s8v o;
  #pragma unroll
  for (int j = 0; j < 8; ++j) {
    int ci = kk * 32 + h * 8 + j;
    o[j] = (short)f2bf(w[((size_t)co * DP + ci) * 9 + tap]);
  }
  *(s8v*)(wP + (size_t)idx * 8) = o;
}

// ---------------------------------------------------------------------------
// P4: WdT[n][k] = Wd[k][n] bf16. grid 128.
// ---------------------------------------------------------------------------
__global__ __launch_bounds__(256) void k_prep_wdt(const float* __restrict__ Wd,
                                                  u16* __restrict__ WdT)
{
  int idx = blockIdx.x * 256 + threadIdx.x;     // 32768
  int n = idx >> 8, k = idx & 255;
  WdT[idx] = f2bf(Wd[(size_t)k * DP + n]);
}

// ---------------------------------------------------------------------------
// P5: pair f32 -> bf16 (NHWC already). grid 8192.
// ---------------------------------------------------------------------------
__global__ __launch_bounds__(256) void k_pair2bf(const float* __restrict__ pair,
                                                 u16* __restrict__ pairb)
{
  int i = blockIdx.x * 256 + threadIdx.x;       // float4 idx, 2097152
  float4 v = ((const float4*)pair)[i];
  uint2 o; o.x = pack2(v.x, v.y); o.y = pack2(v.z, v.w);
  ((uint2*)pairb)[i] = o;
}

// ---------------------------------------------------------------------------
// K1: LayerNorm over d_msa -> msaN bf16 [32768][256]. grid 8192.
// ---------------------------------------------------------------------------
__global__ __launch_bounds__(256) void k_ln(const float* __restrict__ msa,
                                            const float* __restrict__ g,
                                            const float* __restrict__ b,
                                            u16* __restrict__ msaN)
{
  int lane = threadIdx.x & 63, wid = threadIdx.x >> 6;
  int row = blockIdx.x * 4 + wid;
  const float4 v = ((const float4*)(msa + (size_t)row * DM))[lane];
  float s = v.x + v.y + v.z + v.w;
  float q = v.x * v.x + v.y * v.y + v.z * v.z + v.w * v.w;
  #pragma unroll
  for (int off = 32; off; off >>= 1) { s += __shfl_down(s, off); q += __shfl_down(q, off); }
  s = __shfl(s, 0); q = __shfl(q, 0);
  float mean = s * (1.f / DM);
  float var  = q * (1.f / DM) - mean * mean;
  float rstd = rsqrtf(var + 1e-5f);
  const float4 gv = ((const float4*)g)[lane];
  const float4 bv = ((const float4*)b)[lane];
  s4v o;
  o[0] = (short)f2bf((v.x - mean) * rstd * gv.x + bv.x);
  o[1] = (short)f2bf((v.y - mean) * rstd * gv.y + bv.y);
  o[2] = (short)f2bf((v.z - mean) * rstd * gv.z + bv.z);
  o[3] = (short)f2bf((v.w - mean) * rstd * gv.w + bv.w);
  *(s4v*)(msaN + (size_t)row * DM + lane * 4) = o;
}

// ---------------------------------------------------------------------------
// K2: [32768 x 256] @ [256 x 64] -> leftT/rightT bf16 (K=s contiguous).
// ---------------------------------------------------------------------------
__global__ __launch_bounds__(256) void k_gemm_lr(const u16* __restrict__ msaN,
                                                 const u16* __restrict__ WlrT,
                                                 const float* __restrict__ bl,
                                                 const float* __restrict__ br,
                                                 u16* __restrict__ leftT,
                                                 u16* __restrict__ rightT)
{
  int lane = threadIdx.x & 63, wid = threadIdx.x >> 6;
  int sIdx = blockIdx.x;
  size_t rowBase = (size_t)sIdx * 256 + wid * 64;
  f4v acc[4][4] = {};
  #pragma unroll
  for (int ks = 0; ks < 8; ++ks) {
    int k = ks * 32 + (lane >> 4) * 8;
    s8v a[4], bb[4];
    #pragma unroll
    for (int mi = 0; mi < 4; ++mi)
      a[mi] = *(const s8v*)(msaN + (rowBase + mi * 16 + (lane & 15)) * 256 + k);
    #pragma unroll
    for (int ni = 0; ni < 4; ++ni)
      bb[ni] = *(const s8v*)(WlrT + (size_t)(ni * 16 + (lane & 15)) * 256 + k);
    #pragma unroll
    for (int mi = 0; mi < 4; ++mi)
      #pragma unroll
      for (int ni = 0; ni < 4; ++ni)
        acc[mi][ni] = MFMA(a[mi], bb[ni], acc[mi][ni]);
  }
  #pragma unroll
  for (int mi = 0; mi < 4; ++mi) {
    #pragma unroll
    for (int ni = 0; ni < 4; ++ni) {
      int n = ni * 16 + (lane & 15);
      #pragma unroll
      for (int r = 0; r < 4; ++r) {
        int l = wid * 64 + mi * 16 + (lane >> 4) * 4 + r;
        float v = acc[mi][ni][r];
        if (n < 32) {
          leftT[((size_t)l * 32 + n) * 128 + sIdx] = f2bf(v + bl[n]);
        } else {
          rightT[((size_t)l * 32 + (n - 32)) * 128 + sIdx] =
              f2bf((v + br[n - 32]) * (1.f / NS));
        }
      }
    }
  }
}

// ---------------------------------------------------------------------------
// K3: fused outer-product + Wo-projection + proj_down.
// Block = 64 pixels (2 l x 32 m), 512 threads (8 waves). grid 1024:
// bx = mg*128 + lp  (mg: m-group 0..7, lp: l-pair 0..127).
// Phase 1: op[64][1024] (K=s 128) -> LDS (bf16, swizzled, kp = j*32+i)
// Phase 2: ob[64][128] = op @ WoT + bo -> LDS bf16
// Phase 3: p[64][128] = [pairb|ob] @ WdT + bd -> pN (NHWC bf16, coalesced)
// ---------------------------------------------------------------------------
__global__ __launch_bounds__(512) void k_fused(
    const u16* __restrict__ leftT, const u16* __restrict__ rightT,
    const u16* __restrict__ WoT, const u16* __restrict__ pairb,
    const u16* __restrict__ WdT, const float* __restrict__ bo,
    const float* __restrict__ bd, u16* __restrict__ pN)
{
  __shared__ alignas(16) u16 opL[64 * 1024];   // 128 KB
  __shared__ alignas(16) u16 obL[64 * 128];    // 16 KB
  int t = threadIdx.x, lane = t & 63, w = t >> 6;
  int rlo = lane & 15, slot = lane >> 4;
  int bx = blockIdx.x;
  int mg = bx >> 7, lp = bx & 127;
  int l0 = lp * 2, m0 = mg * 32;

  // ---- phase 1: outer product, wave w covers cols [w*128, w*128+128) ----
  {
    const u16* Ab = leftT + (size_t)l0 * 32 * 128;
    const u16* Bb = rightT + ((size_t)m0 * 32 + (size_t)w * 128) * 128;
    f4v acc[4][8] = {};
    #pragma unroll
    for (int ks = 0; ks < 4; ++ks) {
      int k = ks * 32 + slot * 8;
      s8v a[4], b[8];
      #pragma unroll
      for (int mi = 0; mi < 4; ++mi)
        a[mi] = *(const s8v*)(Ab + (size_t)(mi * 16 + rlo) * 128 + k);
      #pragma unroll
      for (int ni = 0; ni < 8; ++ni)
        b[ni] = *(const s8v*)(Bb + (size_t)(ni * 16 + rlo) * 128 + k);
      #pragma unroll
      for (int mi = 0; mi < 4; ++mi)
        #pragma unroll
        for (int ni = 0; ni < 8; ++ni)
          acc[mi][ni] = MFMA(a[mi], b[ni], acc[mi][ni]);
    }
    #pragma unroll
    for (int mi = 0; mi < 4; ++mi) {
      int i0 = (mi & 1) * 16 + slot * 4;
      int lLoc = mi >> 1;
      #pragma unroll
      for (int ni = 0; ni < 8; ++ni) {
        int nn = w * 128 + ni * 16 + rlo;
        int pix = lLoc * 32 + (nn >> 5);
        int kp = (nn & 31) * 32 + i0;
        s4v o;
        #pragma unroll
        for (int r = 0; r < 4; ++r) o[r] = (short)f2bf(acc[mi][ni][r]);
        int byte = (pix * 2048 + kp * 2) ^ ((pix & 7) << 4);
        *(s4v*)((char*)opL + byte) = o;
      }
    }
  }
  __syncthreads();

  int wr = w >> 2, wcq = w & 3;
  int pix0 = wr * 32, c0 = wcq * 32;
  // ---- phase 2: ob = op @ WoT + bo ----
  {
    f4v acc[2][2] = {};
    #pragma unroll 4
    for (int ks = 0; ks < 32; ++ks) {
      int k = ks * 32 + slot * 8;
      s8v a[2], b[2];
      #pragma unroll
      for (int mi = 0; mi < 2; ++mi) {
        int pix = pix0 + mi * 16 + rlo;
        int byte = (pix * 2048 + k * 2) ^ ((pix & 7) << 4);
        a[mi] = *(const s8v*)((const char*)opL + byte);
      }
      #pragma unroll
      for (int ni = 0; ni < 2; ++ni)
        b[ni] = *(const s8v*)(WoT + (size_t)(c0 + ni * 16 + rlo) * 1024 + k);
      #pragma unroll
      for (int mi = 0; mi < 2; ++mi)
        #pragma unroll
        for (int ni = 0; ni < 2; ++ni)
          acc[mi][ni] = MFMA(a[mi], b[ni], acc[mi][ni]);
    }
    #pragma unroll
    for (int mi = 0; mi < 2; ++mi) {
      #pragma unroll
      for (int ni = 0; ni < 2; ++ni) {
        int c = c0 + ni * 16 + rlo;
        float bias = bo[c];
        #pragma unroll
        for (int r = 0; r < 4; ++r) {
          int pix = pix0 + mi * 16 + slot * 4 + r;
          int byte = (pix * 256 + c * 2) ^ ((pix & 7) << 4);
          *(u16*)((char*)obL + byte) = f2bf(acc[mi][ni][r] + bias);
        }
      }
    }
  }
  __syncthreads();

  // ---- phase 3: p = [pairb | ob] @ WdT + bd ----
  {
    f4v acc[2][2] = {};
    #pragma unroll
    for (int ks = 0; ks < 4; ++ks) {           // K 0..127 from pairb
      int k = ks * 32 + slot * 8;
      s8v a[2], b[2];
      #pragma unroll
      for (int mi = 0; mi < 2; ++mi) {
        int pix = pix0 + mi * 16 + rlo;
        int pixG = (l0 + (pix >> 5)) * 256 + m0 + (pix & 31);
        a[mi] = *(const s8v*)(pairb + (size_t)pixG * 128 + k);
      }
      #pragma unroll
      for (int ni = 0; ni < 2; ++ni)
        b[ni] = *(const s8v*)(WdT + (size_t)(c0 + ni * 16 + rlo) * 256 + k);
      #pragma unroll
      for (int mi = 0; mi < 2; ++mi)
        #pragma unroll
        for (int ni = 0; ni < 2; ++ni)
          acc[mi][ni] = MFMA(a[mi], b[ni], acc[mi][ni]);
    }
    #pragma unroll
    for (int ks = 0; ks < 4; ++ks) {           // K 128..255 from ob (LDS)
      int k = ks * 32 + slot * 8;
      s8v a[2], b[2];
      #pragma unroll
      for (int mi = 0; mi < 2; ++mi) {
        int pix = pix0 + mi * 16 + rlo;
        int byte = (pix * 256 + k * 2) ^ ((pix & 7) << 4);
        a[mi] = *(const s8v*)((const char*)obL + byte);
      }
      #pragma unroll
      for (int ni = 0; ni < 2; ++ni)
        b[ni] = *(const s8v*)(WdT + (size_t)(c0 + ni * 16 + rlo) * 256 + 128 + k);
      #pragma unroll
      for (int mi = 0; mi < 2; ++mi)
        #pragma unroll
        for (int ni = 0; ni < 2; ++ni)
          acc[mi][ni] = MFMA(a[mi], b[ni], acc[mi][ni]);
    }
    #pragma unroll
    for (int mi = 0; mi < 2; ++mi) {
      #pragma unroll
      for (int ni = 0; ni < 2; ++ni) {
        int c = c0 + ni * 16 + rlo;
        float bias = bd[c];
        #pragma unroll
        for (int r = 0; r < 4; ++r) {
          int pix = pix0 + mi * 16 + slot * 4 + r;
          int byte = (pix * 256 + c * 2) ^ ((pix & 7) << 4);
          *(u16*)((char*)opL + byte) = f2bf(acc[mi][ni][r] + bias);
        }
      }
    }
  }
  __syncthreads();

  // ---- write pN coalesced: 1024 x 16B units ----
  #pragma unroll
  for (int q = 0; q < 2; ++q) {
    int u = q * 512 + t;
    int pix = u >> 4, off = u & 15;
    int byte = (pix * 256 + off * 16) ^ ((pix & 7) << 4);
    uint4 v = *(const uint4*)((const char*)opL + byte);
    int pixG = (l0 + (pix >> 5)) * 256 + m0 + (pix & 31);
    *(uint4*)(pN + (size_t)pixG * 128 + off * 8) = v;
  }
}

// ---------------------------------------------------------------------------
// K4: conv3x3 implicit-GEMM MFMA. 2 output rows/block (halo reuse).
// Input NHWC bf16; LDS 4x66x128 swizzled (67.6 KB -> 2 blocks/CU);
// wave tile 64px x 64co; output planar f32. grid (4, 128).
// ---------------------------------------------------------------------------
__global__ __launch_bounds__(256, 2) void k_conv(const u16* __restrict__ inN,
                                                 const u16* __restrict__ wP,
                                                 float* __restrict__ out)
{
  __shared__ alignas(16) u16 Ast[4 * 66 * 128];   // 67584 B
  int t = threadIdx.x, lane = t & 63, w = t >> 6;
  int rlo = lane & 15, slot = lane >> 4;
  int x0 = blockIdx.x * 64, y0 = blockIdx.y * 2;
  for (int u = t; u < 4224; u += 256) {           // 4 rows x 66 px x 16 units
    int r = u / 1056;
    int rem = u - r * 1056;
    int p = rem >> 4, ku = rem & 15;
    int gy = y0 + r - 1, gx = x0 - 1 + p;
    s8v v = zero8();
    if ((unsigned)gy < 256u && (unsigned)gx < 256u)
      v = *(const s8v*)(inN + ((size_t)gy * LL + gx) * 128 + ku * 8);
    int lb = (u * 16) ^ ((p & 7) << 4);
    *(s8v*)((char*)Ast + lb) = v;
  }
  __syncthreads();
  int wpy = w >> 1, co0 = (w & 1) * 64;
  f4v acc[4][4] = {};
  #pragma unroll
  for (int tap = 0; tap < 9; ++tap) {
    const int dy = tap / 3, dx = tap % 3;
    #pragma unroll
    for (int kk = 0; kk < 4; ++kk) {
      s8v a[4], b[4];
      #pragma unroll
      for (int mi = 0; mi < 4; ++mi) {
        int p = mi * 16 + rlo + dx;
        int lb = (((wpy + dy) * 66 + p) * 256 + kk * 64 + slot * 16) ^ ((p & 7) << 4);
        a[mi] = *(const s8v*)((const char*)Ast + lb);
      }
      #pragma unroll
      for (int ni = 0; ni < 4; ++ni) {
        int co = co0 + ni * 16 + rlo;
        b[ni] = *(const s8v*)(wP + ((size_t)((tap * 4 + kk) * 128 + co) * 4 + slot) * 8);
      }
      #pragma unroll
      for (int mi = 0; mi < 4; ++mi)
        #pragma unroll
        for (int ni = 0; ni < 4; ++ni)
          acc[mi][ni] = MFMA(a[mi], b[ni], acc[mi][ni]);
    }
  }
  int y = y0 + wpy;
  #pragma unroll
  for (int mi = 0; mi < 4; ++mi) {
    #pragma unroll
    for (int ni = 0; ni < 4; ++ni) {
      int co = co0 + ni * 16 + rlo;
      int x = x0 + mi * 16 + slot * 4;
      float4 v; v.x = acc[mi][ni][0]; v.y = acc[mi][ni][1];
      v.z = acc[mi][ni][2]; v.w = acc[mi][ni][3];
      *(float4*)(out + (size_t)co * HW + (size_t)y * LL + x) = v;
    }
  }
}

// ---------------------------------------------------------------------------
// K5a: instance-norm partial sums. grid 1024 (128 ch x 8 segs).
// ---------------------------------------------------------------------------
__global__ __launch_bounds__(256) void k_instat1(const float* __restrict__ x,
                                                 float* __restrict__ gpart)
{
  int b = blockIdx.x, t = threadIdx.x;
  int c = b >> 3, seg = b & 7;
  const float4* p4 = (const float4*)(x + (size_t)c * HW + seg * 8192);
  float s = 0, s2 = 0;
  #pragma unroll
  for (int i = 0; i < 8; ++i) {
    float4 v = p4[t + 256 * i];
    s  += v.x + v.y + v.z + v.w;
    s2 += v.x * v.x + v.y * v.y + v.z * v.z + v.w * v.w;
  }
  #pragma unroll
  for (int off = 32; off; off >>= 1) { s += __shfl_down(s, off); s2 += __shfl_down(s2, off); }
  __shared__ float red[8];
  int lane = t & 63, wd = t >> 6;
  if (lane == 0) { red[wd] = s; red[4 + wd] = s2; }
  __syncthreads();
  if (t == 0) {
    gpart[b]        = red[0] + red[1] + red[2] + red[3];
    gpart[1024 + b] = red[4] + red[5] + red[6] + red[7];
  }
}

// ---------------------------------------------------------------------------
// K5b: finalize stats. grid 1, block 128.
// ---------------------------------------------------------------------------
__global__ __launch_bounds__(128) void k_instat2(const float* __restrict__ gpart,
                                                 float* __restrict__ st)
{
  int c = threadIdx.x;
  float s = 0, s2 = 0;
  #pragma unroll
  for (int seg = 0; seg < 8; ++seg) {
    s  += gpart[c * 8 + seg];
    s2 += gpart[1024 + c * 8 + seg];
  }
  float m = s * (1.f / HW);
  float var = s2 * (1.f / HW) - m * m;
  st[c] = m;
  st[128 + c] = rsqrtf(var + 1e-6f);
}

// ---------------------------------------------------------------------------
// K6: h1N = NHWC bf16 of elu(IN(h1)). Planar f32 read, LDS transpose.
// grid (8, 256).
// ---------------------------------------------------------------------------
__global__ __launch_bounds__(256) void k_in_elu_t(const float* __restrict__ h1,
                                                  const float* __restrict__ st,
                                                  const float* __restrict__ g,
                                                  const float* __restrict__ b,
                                                  u16* __restrict__ h1N)
{
  __shared__ float lds[128 * 33];
  int t = threadIdx.x;
  int x0 = blockIdx.x * 32, y = blockIdx.y;
  #pragma unroll
  for (int k = 0; k < 16; ++k) {
    int idx = k * 256 + t;
    int c = idx >> 5, xl = idx & 31;
    float m = st[c], r = st[128 + c];
    float sc = r * g[c], bb = b[c] - m * sc;
    float v = h1[(size_t)c * HW + y * LL + x0 + xl];
    lds[c * 33 + xl] = elu1(v * sc + bb);
  }
  __syncthreads();
  #pragma unroll
  for (int k = 0; k < 8; ++k) {
    int idx = k * 256 + t;
    int px = idx >> 6, cu = idx & 63;          // cu = c/2
    unsigned o = pack2(lds[(2 * cu) * 33 + px], lds[(2 * cu + 1) * 33 + px]);
    *(unsigned*)(h1N + ((size_t)(y * LL + x0 + px) * DP + 2 * cu)) = o;
  }
}

// ---------------------------------------------------------------------------
// K7: out_nhwc = elu(pN + IN2(h2)); h2 planar f32, pN NHWC bf16. grid (8,256).
// ---------------------------------------------------------------------------
__global__ __launch_bounds__(256) void k_final(
    const u16* __restrict__ pN, const float* __restrict__ h2, const float* __restrict__ st,
    const float* __restrict__ g, const float* __restrict__ b, float* __restrict__ out)
{
  __shared__ float lds[128 * 33];
  int t = threadIdx.x;
  int x0 = blockIdx.x * 32, y = blockIdx.y;
  #pragma unroll
  for (int k = 0; k < 16; ++k) {
    int idx = k * 256 + t;
    int c = idx >> 5, xl = idx & 31;
    size_t gi = (size_t)c * HW + y * LL + x0 + xl;
    lds[c * 33 + xl] = (h2[gi] - st[c]) * st[128 + c] * g[c] + b[c];
  }
  __syncthreads();
  #pragma unroll
  for (int k = 0; k < 16; ++k) {
    int idx = k * 256 + t;
    int px = idx >> 7, c = idx & 127;
    size_t pixG = (size_t)(y * LL) + x0 + px;
    float v = lds[c * 33 + px] + bf2f(pN[pixG * DP + c]);
    out[pixG * DP + c] = v > 0.f ? v : expm1f(v);
  }
}

// ---------------------------------------------------------------------------
extern "C" void kernel_launch(void* const* d_in, const int* in_sizes, int n_in,
                              void* d_out, int out_size, void* d_ws, size_t ws_size,
                              hipStream_t stream)
{
  const float* msa   = (const float*)d_in[0];
  const float* pair  = (const float*)d_in[1];
  const float* ln_g  = (const float*)d_in[2];
  const float* ln_b  = (const float*)d_in[3];
  const float* Wl    = (const float*)d_in[4];
  const float* bl    = (const float*)d_in[5];
  const float* Wr    = (const float*)d_in[6];
  const float* br    = (const float*)d_in[7];
  const float* Wo    = (const float*)d_in[8];
  const float* bo    = (const float*)d_in[9];
  const float* Wd    = (const float*)d_in[10];
  const float* bd    = (const float*)d_in[11];
  const float* conv1 = (const float*)d_in[12];
  const float* in1_g = (const float*)d_in[13];
  const float* in1_b = (const float*)d_in[14];
  const float* conv2 = (const float*)d_in[15];
  const float* in2_g = (const float*)d_in[16];
  const float* in2_b = (const float*)d_in[17];
  float* out = (float*)d_out;

  // Workspace (float units, F = 1Mi floats = 4 MB). Peak ~117 MB (ws >= 120MB
  // proven by round-1 layout).
  //  [0,4F)    msaN (bf16) -> pairb (bf16)
  //  [4F,4.5F) leftT ; [4.5F,5F) rightT
  //  [5F,9F)   pN (NHWC bf16, live to end)
  //  [9F,17F)  h1 (planar f32)
  //  [17F,21F) h1N (NHWC bf16)
  //  [21F,29F) h2 (planar f32)
  //  [29F,..)  gpart(2048) + stats(512) + packed weights
  float* ws = (float*)d_ws;
  const size_t F = 1048576;
  u16* msaN   = (u16*)ws;
  u16* pairb  = (u16*)ws;
  u16* leftT  = (u16*)(ws + 4 * F);
  u16* rightT = (u16*)(ws + 4 * F + F / 2);
  u16* pN     = (u16*)(ws + 5 * F);
  float* h1   = ws + 9 * F;
  u16* h1N    = (u16*)(ws + 17 * F);
  float* h2   = ws + 21 * F;
  float* gpart = ws + 29 * F;                // 2048
  float* stats = ws + 29 * F + 2048;         // 512
  u16* aux    = (u16*)(ws + 29 * F + 2560);
  u16* wP1    = aux;                         // 147456
  u16* wP2    = aux + 147456;                // 147456
  u16* WoT    = aux + 294912;                // 131072
  u16* WlrT   = aux + 425984;                // 16384
  u16* WdT    = aux + 442368;                // 32768

  k_prep_wlr<<<dim3(64), dim3(256), 0, stream>>>(Wl, Wr, WlrT);
  k_prep_wo<<<dim3(512), dim3(256), 0, stream>>>(Wo, WoT);
  k_prep_convw<<<dim3(72), dim3(256), 0, stream>>>(conv1, wP1);
  k_prep_convw<<<dim3(72), dim3(256), 0, stream>>>(conv2, wP2);
  k_prep_wdt<<<dim3(128), dim3(256), 0, stream>>>(Wd, WdT);

  k_ln<<<dim3(8192), dim3(256), 0, stream>>>(msa, ln_g, ln_b, msaN);
  k_gemm_lr<<<dim3(128), dim3(256), 0, stream>>>(msaN, WlrT, bl, br, leftT, rightT);
  k_pair2bf<<<dim3(8192), dim3(256), 0, stream>>>(pair, pairb);   // msaN dead now

  k_fused<<<dim3(1024), dim3(512), 0, stream>>>(leftT, rightT, WoT, pairb, WdT,
                                                bo, bd, pN);

  k_conv<<<dim3(4, 128), dim3(256), 0, stream>>>(pN, wP1, h1);
  k_instat1<<<dim3(1024), dim3(256), 0, stream>>>(h1, gpart);
  k_instat2<<<dim3(1), dim3(128), 0, stream>>>(gpart, stats);
  k_in_elu_t<<<dim3(8, 256), dim3(256), 0, stream>>>(h1, stats, in1_g, in1_b, h1N);

  k_conv<<<dim3(4, 128), dim3(256), 0, stream>>>(h1N, wP2, h2);
  k_instat1<<<dim3(1024), dim3(256), 0, stream>>>(h2, gpart);
  k_instat2<<<dim3(1), dim3(128), 0, stream>>>(gpart, stats + 256);

  k_final<<<dim3(8, 256), dim3(256), 0, stream>>>(pN, h2, stats + 256, in2_g, in2_b, out);
}

// Round 5
// 294.032 us; speedup vs baseline: 7.0821x; 1.0332x over previous
//
#include <hip/hip_runtime.h>
#include <math.h>

#define LL 256      // L
#define NS 128      // N sequences
#define DM 256      // d_msa
#define DH 32       // d_h
#define DP 128      // d_pair
#define HW 65536    // L*L

using u16 = unsigned short;
typedef __attribute__((ext_vector_type(8))) short s8v;   // 8 bf16 (A/B frag)
typedef __attribute__((ext_vector_type(4))) short s4v;   // 4 bf16 (packed store)
typedef __attribute__((ext_vector_type(4))) float f4v;   // C/D frag

#define MFMA(a, b, c) __builtin_amdgcn_mfma_f32_16x16x32_bf16((a), (b), (c), 0, 0, 0)

__device__ __forceinline__ u16 f2bf(float f) {
  unsigned u = __float_as_uint(f);
  u = (u + 0x7FFFu + ((u >> 16) & 1u)) >> 16;   // RNE
  return (u16)u;
}
__device__ __forceinline__ float bf2f(u16 h) { return __uint_as_float(((unsigned)h) << 16); }
__device__ __forceinline__ float elu1(float v) { return v > 0.f ? v : expm1f(v); }
__device__ __forceinline__ s8v zero8() {
  s8v v;
  #pragma unroll
  for (int j = 0; j < 8; ++j) v[j] = 0;
  return v;
}
__device__ __forceinline__ unsigned pack2(float a, float b) {
  return (unsigned)f2bf(a) | ((unsigned)f2bf(b) << 16);
}

// ---------------------------------------------------------------------------
// P: all weight preps + pair->bf16, one launch. grid 9040.
//  [0,64)    WlrT ; [64,576) WoT ; [576,648) wP1 ; [648,720) wP2 ;
//  [720,848) WdT ; [848,9040) pairb
// ---------------------------------------------------------------------------
__device__ __forceinline__ void prep_convw(const float* __restrict__ w,
                                           u16* __restrict__ wP, int idx)
{
  int h = idx & 3, co = (idx >> 2) & 127, kk = (idx >> 9) & 3, tap = idx >> 11;
  s8v o;
  #pragma unroll
  for (int j = 0; j < 8; ++j) {
    int ci = kk * 32 + h * 8 + j;
    o[j] = (short)f2bf(w[((size_t)co * DP + ci) * 9 + tap]);
  }
  *(s8v*)(wP + (size_t)idx * 8) = o;
}

__global__ __launch_bounds__(256) void k_prep_all(
    const float* __restrict__ Wl, const float* __restrict__ Wr,
    const float* __restrict__ Wo, const float* __restrict__ Wd,
    const float* __restrict__ conv1, const float* __restrict__ conv2,
    const float* __restrict__ pair,
    u16* __restrict__ WlrT, u16* __restrict__ WoT, u16* __restrict__ WdT,
    u16* __restrict__ wP1, u16* __restrict__ wP2, u16* __restrict__ pairb)
{
  int bx = blockIdx.x, t = threadIdx.x;
  if (bx < 64) {
    int idx = bx * 256 + t;
    int n = idx >> 8, k = idx & 255;
    float v = (n < 32) ? Wl[k * DH + n] : Wr[k * DH + (n - 32)];
    WlrT[n * 256 + k] = f2bf(v);
  } else if (bx < 576) {
    int idx = (bx - 64) * 256 + t;              // 131072
    int c = idx >> 10, kp = idx & 1023;
    int i = kp & 31, j = kp >> 5;
    WoT[idx] = f2bf(Wo[(size_t)(i * 32 + j) * DP + c]);
  } else if (bx < 648) {
    prep_convw(conv1, wP1, (bx - 576) * 256 + t);
  } else if (bx < 720) {
    prep_convw(conv2, wP2, (bx - 648) * 256 + t);
  } else if (bx < 848) {
    int idx = (bx - 720) * 256 + t;             // 32768
    int n = idx >> 8, k = idx & 255;
    WdT[idx] = f2bf(Wd[(size_t)k * DP + n]);
  } else {
    int i = (bx - 848) * 256 + t;               // float4 idx, 2097152
    float4 v = ((const float4*)pair)[i];
    uint2 o; o.x = pack2(v.x, v.y); o.y = pack2(v.z, v.w);
    ((uint2*)pairb)[i] = o;
  }
}

// ---------------------------------------------------------------------------
// K1: LayerNorm over d_msa -> msaN bf16 [32768][256]. grid 8192.
// ---------------------------------------------------------------------------
__global__ __launch_bounds__(256) void k_ln(const float* __restrict__ msa,
                                            const float* __restrict__ g,
                                            const float* __restrict__ b,
                                            u16* __restrict__ msaN)
{
  int lane = threadIdx.x & 63, wid = threadIdx.x >> 6;
  int row = blockIdx.x * 4 + wid;
  const float4 v = ((const float4*)(msa + (size_t)row * DM))[lane];
  float s = v.x + v.y + v.z + v.w;
  float q = v.x * v.x + v.y * v.y + v.z * v.z + v.w * v.w;
  #pragma unroll
  for (int off = 32; off; off >>= 1) { s += __shfl_down(s, off); q += __shfl_down(q, off); }
  s = __shfl(s, 0); q = __shfl(q, 0);
  float mean = s * (1.f / DM);
  float var  = q * (1.f / DM) - mean * mean;
  float rstd = rsqrtf(var + 1e-5f);
  const float4 gv = ((const float4*)g)[lane];
  const float4 bv = ((const float4*)b)[lane];
  s4v o;
  o[0] = (short)f2bf((v.x - mean) * rstd * gv.x + bv.x);
  o[1] = (short)f2bf((v.y - mean) * rstd * gv.y + bv.y);
  o[2] = (short)f2bf((v.z - mean) * rstd * gv.z + bv.z);
  o[3] = (short)f2bf((v.w - mean) * rstd * gv.w + bv.w);
  *(s4v*)(msaN + (size_t)row * DM + lane * 4) = o;
}

// ---------------------------------------------------------------------------
// K2: [32768 x 256] @ [256 x 64] -> leftT/rightT bf16 (K=s contiguous).
// ---------------------------------------------------------------------------
__global__ __launch_bounds__(256) void k_gemm_lr(const u16* __restrict__ msaN,
                                                 const u16* __restrict__ WlrT,
                                                 const float* __restrict__ bl,
                                                 const float* __restrict__ br,
                                                 u16* __restrict__ leftT,
                                                 u16* __restrict__ rightT)
{
  int lane = threadIdx.x & 63, wid = threadIdx.x >> 6;
  int sIdx = blockIdx.x;
  size_t rowBase = (size_t)sIdx * 256 + wid * 64;
  f4v acc[4][4] = {};
  #pragma unroll
  for (int ks = 0; ks < 8; ++ks) {
    int k = ks * 32 + (lane >> 4) * 8;
    s8v a[4], bb[4];
    #pragma unroll
    for (int mi = 0; mi < 4; ++mi)
      a[mi] = *(const s8v*)(msaN + (rowBase + mi * 16 + (lane & 15)) * 256 + k);
    #pragma unroll
    for (int ni = 0; ni < 4; ++ni)
      bb[ni] = *(const s8v*)(WlrT + (size_t)(ni * 16 + (lane & 15)) * 256 + k);
    #pragma unroll
    for (int mi = 0; mi < 4; ++mi)
      #pragma unroll
      for (int ni = 0; ni < 4; ++ni)
        acc[mi][ni] = MFMA(a[mi], bb[ni], acc[mi][ni]);
  }
  #pragma unroll
  for (int mi = 0; mi < 4; ++mi) {
    #pragma unroll
    for (int ni = 0; ni < 4; ++ni) {
      int n = ni * 16 + (lane & 15);
      #pragma unroll
      for (int r = 0; r < 4; ++r) {
        int l = wid * 64 + mi * 16 + (lane >> 4) * 4 + r;
        float v = acc[mi][ni][r];
        if (n < 32) {
          leftT[((size_t)l * 32 + n) * 128 + sIdx] = f2bf(v + bl[n]);
        } else {
          rightT[((size_t)l * 32 + (n - 32)) * 128 + sIdx] =
              f2bf((v + br[n - 32]) * (1.f / NS));
        }
      }
    }
  }
}

// ---------------------------------------------------------------------------
// K3: fused outer-product + Wo-projection + proj_down, CHUNKED.
// Block = 64 px (2 l x 32 m), 512 thr. LDS 64 KB -> 2 blocks/CU. grid 1024.
// Loop jc=0..3: phase1 op[64][256] (j-chunk) -> LDS; phase2 ob += op @ WoT.
// Then phase3: p = [pairb|ob] @ WdT + bd -> pN NHWC bf16.
// ---------------------------------------------------------------------------
__global__ __launch_bounds__(512, 4) void k_fused(
    const u16* __restrict__ leftT, const u16* __restrict__ rightT,
    const u16* __restrict__ WoT, const u16* __restrict__ pairb,
    const u16* __restrict__ WdT, const float* __restrict__ bo,
    const float* __restrict__ bd, u16* __restrict__ pN)
{
  __shared__ alignas(16) u16 Als[64 * 128];    // 16 KB  leftT strip (swz pix)
  __shared__ alignas(16) u16 opL[64 * 256];    // 32 KB  op chunk (dbl-XOR swz)
  __shared__ alignas(16) u16 obL[64 * 128];    // 16 KB  ob (swz pix)
  int t = threadIdx.x, lane = t & 63, w = t >> 6;
  int rlo = lane & 15, slot = lane >> 4;
  int bx = blockIdx.x;
  int mg = bx >> 7, lp = bx & 127;
  int l0 = lp * 2, m0 = mg * 32;

  // stage A strip: 64 rows x 128 s
  {
    const u16* Asrc = leftT + (size_t)l0 * 32 * 128;
    #pragma unroll
    for (int i = 0; i < 2; ++i) {
      int u = t + 512 * i;                     // 1024 16B units
      int row = u >> 4, kc = u & 15;
      int byte = (row * 256 + kc * 16) ^ ((row & 7) << 4);
      *(s8v*)((char*)Als + byte) = *(const s8v*)(Asrc + (size_t)row * 128 + kc * 8);
    }
  }
  __syncthreads();

  // persistent phase-2 accumulators: wave w -> c slice [w*16, w*16+16), all 64 px
  f4v acc2[4] = {};
  // phase-1 per-lane B row addresses (chunk-invariant part)
  int rowBadr[2];
  #pragma unroll
  for (int ni = 0; ni < 2; ++ni) {
    int n = w * 32 + ni * 16 + rlo;            // chunk-local col
    rowBadr[ni] = ((m0 + (n >> 3)) * 32 + (n & 7)) * 128 + slot * 8;
  }

  for (int jc = 0; jc < 4; ++jc) {
    // ---- phase 1: op chunk (M=64 rows (l,i), N=256 cols (m,jj)) ----
    {
      f4v acc1[4][2] = {};
      #pragma unroll
      for (int ks = 0; ks < 4; ++ks) {
        s8v a[4], b[2];
        #pragma unroll
        for (int mi = 0; mi < 4; ++mi) {
          int row = mi * 16 + rlo;
          int byte = (row * 256 + ks * 64 + slot * 16) ^ ((row & 7) << 4);
          a[mi] = *(const s8v*)((const char*)Als + byte);
        }
        #pragma unroll
        for (int ni = 0; ni < 2; ++ni)
          b[ni] = *(const s8v*)(rightT + rowBadr[ni] + jc * 1024 + ks * 32);
        #pragma unroll
        for (int mi = 0; mi < 4; ++mi)
          #pragma unroll
          for (int ni = 0; ni < 2; ++ni)
            acc1[mi][ni] = MFMA(a[mi], b[ni], acc1[mi][ni]);
      }
      // store op chunk: pix = lLoc*32+mLoc, kpLoc = jj*32+i
      #pragma unroll
      for (int mi = 0; mi < 4; ++mi) {
        int i0 = (mi & 1) * 16 + slot * 4;
        int lLoc = mi >> 1;
        #pragma unroll
        for (int ni = 0; ni < 2; ++ni) {
          int n = w * 32 + ni * 16 + rlo;
          int pix = lLoc * 32 + (n >> 3);
          int jj = n & 7;
          s4v o;
          #pragma unroll
          for (int r = 0; r < 4; ++r) o[r] = (short)f2bf(acc1[mi][ni][r]);
          int byte = (pix * 512 + (jj * 32 + i0) * 2) ^ (((pix ^ jj) & 7) << 4);
          *(s4v*)((char*)opL + byte) = o;
        }
      }
    }
    __syncthreads();
    // ---- phase 2: ob += op_chunk @ WoT_chunk ----
    {
      int c = w * 16 + rlo;
      #pragma unroll
      for (int ks = 0; ks < 8; ++ks) {
        s8v a[4], b;
        #pragma unroll
        for (int mi = 0; mi < 4; ++mi) {
          int row = mi * 16 + rlo;
          int byte = (row * 512 + ks * 64 + slot * 16) ^ (((row ^ ks) & 7) << 4);
          a[mi] = *(const s8v*)((const char*)opL + byte);
        }
        b = *(const s8v*)(WoT + (size_t)c * 1024 + jc * 256 + ks * 32 + slot * 8);
        #pragma unroll
        for (int mi = 0; mi < 4; ++mi)
          acc2[mi] = MFMA(a[mi], b, acc2[mi]);
      }
    }
    __syncthreads();
  }

  // ob -> obL (+bo)
  {
    int c = w * 16 + rlo;
    float bias = bo[c];
    #pragma unroll
    for (int mi = 0; mi < 4; ++mi) {
      #pragma unroll
      for (int r = 0; r < 4; ++r) {
        int pix = mi * 16 + slot * 4 + r;
        int byte = (pix * 256 + c * 2) ^ ((pix & 7) << 4);
        *(u16*)((char*)obL + byte) = f2bf(acc2[mi][r] + bias);
      }
    }
  }
  __syncthreads();

  // ---- phase 3: p = [pairb | ob] @ WdT + bd ----
  int wr = w >> 2, wcq = w & 3;
  int pix0 = wr * 32, c0 = wcq * 32;
  {
    f4v acc[2][2] = {};
    #pragma unroll
    for (int ks = 0; ks < 4; ++ks) {           // K 0..127 from pairb
      int k = ks * 32 + slot * 8;
      s8v a[2], b[2];
      #pragma unroll
      for (int mi = 0; mi < 2; ++mi) {
        int pix = pix0 + mi * 16 + rlo;
        int pixG = (l0 + (pix >> 5)) * 256 + m0 + (pix & 31);
        a[mi] = *(const s8v*)(pairb + (size_t)pixG * 128 + k);
      }
      #pragma unroll
      for (int ni = 0; ni < 2; ++ni)
        b[ni] = *(const s8v*)(WdT + (size_t)(c0 + ni * 16 + rlo) * 256 + k);
      #pragma unroll
      for (int mi = 0; mi < 2; ++mi)
        #pragma unroll
        for (int ni = 0; ni < 2; ++ni)
          acc[mi][ni] = MFMA(a[mi], b[ni], acc[mi][ni]);
    }
    #pragma unroll
    for (int ks = 0; ks < 4; ++ks) {           // K 128..255 from obL
      int k = ks * 32 + slot * 8;
      s8v a[2], b[2];
      #pragma unroll
      for (int mi = 0; mi < 2; ++mi) {
        int pix = pix0 + mi * 16 + rlo;
        int byte = (pix * 256 + k * 2) ^ ((pix & 7) << 4);
        a[mi] = *(const s8v*)((const char*)obL + byte);
      }
      #pragma unroll
      for (int ni = 0; ni < 2; ++ni)
        b[ni] = *(const s8v*)(WdT + (size_t)(c0 + ni * 16 + rlo) * 256 + 128 + k);
      #pragma unroll
      for (int mi = 0; mi < 2; ++mi)
        #pragma unroll
        for (int ni = 0; ni < 2; ++ni)
          acc[mi][ni] = MFMA(a[mi], b[ni], acc[mi][ni]);
    }
    #pragma unroll
    for (int mi = 0; mi < 2; ++mi) {
      #pragma unroll
      for (int ni = 0; ni < 2; ++ni) {
        int c = c0 + ni * 16 + rlo;
        float bias = bd[c];
        #pragma unroll
        for (int r = 0; r < 4; ++r) {
          int pix = pix0 + mi * 16 + slot * 4 + r;
          int byte = (pix * 256 + c * 2) ^ ((pix & 7) << 4);
          *(u16*)((char*)opL + byte) = f2bf(acc[mi][ni][r] + bias);
        }
      }
    }
  }
  __syncthreads();

  // write pN coalesced: 1024 x 16B units
  #pragma unroll
  for (int q = 0; q < 2; ++q) {
    int u = q * 512 + t;
    int pix = u >> 4, off = u & 15;
    int byte = (pix * 256 + off * 16) ^ ((pix & 7) << 4);
    uint4 v = *(const uint4*)((const char*)opL + byte);
    int pixG = (l0 + (pix >> 5)) * 256 + m0 + (pix & 31);
    *(uint4*)(pN + (size_t)pixG * 128 + off * 8) = v;
  }
}

// ---------------------------------------------------------------------------
// K4: conv3x3 implicit-GEMM MFMA + fused IN partial stats.
// Input NHWC bf16; LDS 4x66x128 swizzled; wave 64px x 64co; out planar f32.
// grid (4, 128). gS/gQ: [bid*128 + c] partial sums.
// ---------------------------------------------------------------------------
__global__ __launch_bounds__(256, 2) void k_conv(const u16* __restrict__ inN,
                                                 const u16* __restrict__ wP,
                                                 float* __restrict__ out,
                                                 float* __restrict__ gS,
                                                 float* __restrict__ gQ)
{
  __shared__ alignas(16) u16 Ast[4 * 66 * 128];   // 67584 B
  __shared__ float partS[4][64], partQ[4][64];
  int t = threadIdx.x, lane = t & 63, w = t >> 6;
  int rlo = lane & 15, slot = lane >> 4;
  int x0 = blockIdx.x * 64, y0 = blockIdx.y * 2;
  for (int u = t; u < 4224; u += 256) {           // 4 rows x 66 px x 16 units
    int r = u / 1056;
    int rem = u - r * 1056;
    int p = rem >> 4, ku = rem & 15;
    int gy = y0 + r - 1, gx = x0 - 1 + p;
    s8v v = zero8();
    if ((unsigned)gy < 256u && (unsigned)gx < 256u)
      v = *(const s8v*)(inN + ((size_t)gy * LL + gx) * 128 + ku * 8);
    int lb = (u * 16) ^ ((p & 7) << 4);
    *(s8v*)((char*)Ast + lb) = v;
  }
  __syncthreads();
  int wpy = w >> 1, co0 = (w & 1) * 64;
  f4v acc[4][4] = {};
  #pragma unroll
  for (int tap = 0; tap < 9; ++tap) {
    const int dy = tap / 3, dx = tap % 3;
    #pragma unroll
    for (int kk = 0; kk < 4; ++kk) {
      s8v a[4], b[4];
      #pragma unroll
      for (int mi = 0; mi < 4; ++mi) {
        int p = mi * 16 + rlo + dx;
        int lb = (((wpy + dy) * 66 + p) * 256 + kk * 64 + slot * 16) ^ ((p & 7) << 4);
        a[mi] = *(const s8v*)((const char*)Ast + lb);
      }
      #pragma unroll
      for (int ni = 0; ni < 4; ++ni) {
        int co = co0 + ni * 16 + rlo;
        b[ni] = *(const s8v*)(wP + ((size_t)((tap * 4 + kk) * 128 + co) * 4 + slot) * 8);
      }
      #pragma unroll
      for (int mi = 0; mi < 4; ++mi)
        #pragma unroll
        for (int ni = 0; ni < 4; ++ni)
          acc[mi][ni] = MFMA(a[mi], b[ni], acc[mi][ni]);
    }
  }
  int y = y0 + wpy;
  #pragma unroll
  for (int mi = 0; mi < 4; ++mi) {
    #pragma unroll
    for (int ni = 0; ni < 4; ++ni) {
      int co = co0 + ni * 16 + rlo;
      int x = x0 + mi * 16 + slot * 4;
      float4 v; v.x = acc[mi][ni][0]; v.y = acc[mi][ni][1];
      v.z = acc[mi][ni][2]; v.w = acc[mi][ni][3];
      *(float4*)(out + (size_t)co * HW + (size_t)y * LL + x) = v;
    }
  }
  // fused IN partial stats
  #pragma unroll
  for (int ni = 0; ni < 4; ++ni) {
    float s = 0.f, q = 0.f;
    #pragma unroll
    for (int mi = 0; mi < 4; ++mi)
      #pragma unroll
      for (int r = 0; r < 4; ++r) {
        float v = acc[mi][ni][r];
        s += v; q += v * v;
      }
    s += __shfl_xor(s, 16); s += __shfl_xor(s, 32);
    q += __shfl_xor(q, 16); q += __shfl_xor(q, 32);
    if (slot == 0) { partS[w][ni * 16 + rlo] = s; partQ[w][ni * 16 + rlo] = q; }
  }
  __syncthreads();
  if (t < 128) {
    int half = t >> 6, cl = t & 63;
    int bid = blockIdx.y * 4 + blockIdx.x;
    gS[bid * 128 + t] = partS[half][cl] + partS[2 + half][cl];
    gQ[bid * 128 + t] = partQ[half][cl] + partQ[2 + half][cl];
  }
}

// ---------------------------------------------------------------------------
// K5: reduce 512 partials -> stats. grid 1, block 512.
// ---------------------------------------------------------------------------
__global__ __launch_bounds__(512) void k_instat2(const float* __restrict__ gS,
                                                 const float* __restrict__ gQ,
                                                 float* __restrict__ st)
{
  __shared__ float redS[512], redQ[512];
  int t = threadIdx.x, c = t & 127, q = t >> 7;
  float s = 0.f, s2 = 0.f;
  for (int i = q * 128; i < q * 128 + 128; ++i) {
    s  += gS[i * 128 + c];
    s2 += gQ[i * 128 + c];
  }
  redS[t] = s; redQ[t] = s2;
  __syncthreads();
  if (t < 128) {
    s  = redS[t] + redS[t + 128] + redS[t + 256] + redS[t + 384];
    s2 = redQ[t] + redQ[t + 128] + redQ[t + 256] + redQ[t + 384];
    float m = s * (1.f / HW);
    float var = s2 * (1.f / HW) - m * m;
    st[t] = m;
    st[128 + t] = rsqrtf(var + 1e-6f);
  }
}

// ---------------------------------------------------------------------------
// K6: h1N = NHWC bf16 of elu(IN(h1)). grid (8, 256).
// ---------------------------------------------------------------------------
__global__ __launch_bounds__(256) void k_in_elu_t(const float* __restrict__ h1,
                                                  const float* __restrict__ st,
                                                  const float* __restrict__ g,
                                                  const float* __restrict__ b,
                                                  u16* __restrict__ h1N)
{
  __shared__ float lds[128 * 33];
  int t = threadIdx.x;
  int x0 = blockIdx.x * 32, y = blockIdx.y;
  #pragma unroll
  for (int k = 0; k < 16; ++k) {
    int idx = k * 256 + t;
    int c = idx >> 5, xl = idx & 31;
    float m = st[c], r = st[128 + c];
    float sc = r * g[c], bb = b[c] - m * sc;
    float v = h1[(size_t)c * HW + y * LL + x0 + xl];
    lds[c * 33 + xl] = elu1(v * sc + bb);
  }
  __syncthreads();
  #pragma unroll
  for (int k = 0; k < 8; ++k) {
    int idx = k * 256 + t;
    int px = idx >> 6, cu = idx & 63;
    unsigned o = pack2(lds[(2 * cu) * 33 + px], lds[(2 * cu + 1) * 33 + px]);
    *(unsigned*)(h1N + ((size_t)(y * LL + x0 + px) * DP + 2 * cu)) = o;
  }
}

// ---------------------------------------------------------------------------
// K7: out_nhwc = elu(pN + IN2(h2)). grid (8, 256).
// ---------------------------------------------------------------------------
__global__ __launch_bounds__(256) void k_final(
    const u16* __restrict__ pN, const float* __restrict__ h2, const float* __restrict__ st,
    const float* __restrict__ g, const float* __restrict__ b, float* __restrict__ out)
{
  __shared__ float lds[128 * 33];
  int t = threadIdx.x;
  int x0 = blockIdx.x * 32, y = blockIdx.y;
  #pragma unroll
  for (int k = 0; k < 16; ++k) {
    int idx = k * 256 + t;
    int c = idx >> 5, xl = idx & 31;
    size_t gi = (size_t)c * HW + y * LL + x0 + xl;
    lds[c * 33 + xl] = (h2[gi] - st[c]) * st[128 + c] * g[c] + b[c];
  }
  __syncthreads();
  #pragma unroll
  for (int k = 0; k < 16; ++k) {
    int idx = k * 256 + t;
    int px = idx >> 7, c = idx & 127;
    size_t pixG = (size_t)(y * LL) + x0 + px;
    float v = lds[c * 33 + px] + bf2f(pN[pixG * DP + c]);
    out[pixG * DP + c] = v > 0.f ? v : expm1f(v);
  }
}

// ---------------------------------------------------------------------------
extern "C" void kernel_launch(void* const* d_in, const int* in_sizes, int n_in,
                              void* d_out, int out_size, void* d_ws, size_t ws_size,
                              hipStream_t stream)
{
  const float* msa   = (const float*)d_in[0];
  const float* pair  = (const float*)d_in[1];
  const float* ln_g  = (const float*)d_in[2];
  const float* ln_b  = (const float*)d_in[3];
  const float* Wl    = (const float*)d_in[4];
  const float* bl    = (const float*)d_in[5];
  const float* Wr    = (const float*)d_in[6];
  const float* br    = (const float*)d_in[7];
  const float* Wo    = (const float*)d_in[8];
  const float* bo    = (const float*)d_in[9];
  const float* Wd    = (const float*)d_in[10];
  const float* bd    = (const float*)d_in[11];
  const float* conv1 = (const float*)d_in[12];
  const float* in1_g = (const float*)d_in[13];
  const float* in1_b = (const float*)d_in[14];
  const float* conv2 = (const float*)d_in[15];
  const float* in2_g = (const float*)d_in[16];
  const float* in2_b = (const float*)d_in[17];
  float* out = (float*)d_out;

  // Workspace (float units, F = 1Mi floats = 4 MB):
  //  [0,4F)    msaN (bf16)
  //  [4F,4.5F) leftT ; [4.5F,5F) rightT
  //  [5F,9F)   pN (NHWC bf16, live to end)
  //  [9F,17F)  h1 (planar f32)
  //  [17F,21F) pairb (bf16) -> h1N (bf16, after k_fused)
  //  [21F,29F) h2 (planar f32)
  //  [29F,+128K) gS/gQ ; then stats ; then packed weights
  float* ws = (float*)d_ws;
  const size_t F = 1048576;
  u16* msaN   = (u16*)ws;
  u16* leftT  = (u16*)(ws + 4 * F);
  u16* rightT = (u16*)(ws + 4 * F + F / 2);
  u16* pN     = (u16*)(ws + 5 * F);
  float* h1   = ws + 9 * F;
  u16* pairb  = (u16*)(ws + 17 * F);
  u16* h1N    = (u16*)(ws + 17 * F);
  float* h2   = ws + 21 * F;
  float* gS   = ws + 29 * F;                 // 65536
  float* gQ   = ws + 29 * F + 65536;         // 65536
  float* stats = ws + 29 * F + 131072;       // 512
  u16* aux    = (u16*)(ws + 29 * F + 131584);
  u16* wP1    = aux;                         // 147456
  u16* wP2    = aux + 147456;                // 147456
  u16* WoT    = aux + 294912;                // 131072
  u16* WlrT   = aux + 425984;                // 16384
  u16* WdT    = aux + 442368;                // 32768

  k_prep_all<<<dim3(9040), dim3(256), 0, stream>>>(Wl, Wr, Wo, Wd, conv1, conv2,
                                                   pair, WlrT, WoT, WdT, wP1, wP2, pairb);
  k_ln<<<dim3(8192), dim3(256), 0, stream>>>(msa, ln_g, ln_b, msaN);
  k_gemm_lr<<<dim3(128), dim3(256), 0, stream>>>(msaN, WlrT, bl, br, leftT, rightT);

  k_fused<<<dim3(1024), dim3(512), 0, stream>>>(leftT, rightT, WoT, pairb, WdT,
                                                bo, bd, pN);

  k_conv<<<dim3(4, 128), dim3(256), 0, stream>>>(pN, wP1, h1, gS, gQ);
  k_instat2<<<dim3(1), dim3(512), 0, stream>>>(gS, gQ, stats);
  k_in_elu_t<<<dim3(8, 256), dim3(256), 0, stream>>>(h1, stats, in1_g, in1_b, h1N);

  k_conv<<<dim3(4, 128), dim3(256), 0, stream>>>(h1N, wP2, h2, gS, gQ);
  k_instat2<<<dim3(1), dim3(512), 0, stream>>>(gS, gQ, stats + 256);

  k_final<<<dim3(8, 256), dim3(256), 0, stream>>>(pN, h2, stats + 256, in2_g, in2_b, out);
}

// Round 8
// 244.227 us; speedup vs baseline: 8.5264x; 1.2039x over previous
//
#include <hip/hip_runtime.h>
#include <math.h>

#define LL 256      // L
#define NS 128      // N sequences
#define DM 256      // d_msa
#define DH 32       // d_h
#define DP 128      // d_pair
#define HW 65536    // L*L

using u16 = unsigned short;
typedef __attribute__((ext_vector_type(8))) short s8v;   // 8 bf16 (A/B frag)
typedef __attribute__((ext_vector_type(4))) short s4v;   // 4 bf16
typedef __attribute__((ext_vector_type(4))) float f4v;   // C/D frag

#define MFMA(a, b, c) __builtin_amdgcn_mfma_f32_16x16x32_bf16((a), (b), (c), 0, 0, 0)

__device__ __forceinline__ u16 f2bf(float f) {
  unsigned u = __float_as_uint(f);
  u = (u + 0x7FFFu + ((u >> 16) & 1u)) >> 16;   // RNE
  return (u16)u;
}
__device__ __forceinline__ float bf2f(u16 h) { return __uint_as_float(((unsigned)h) << 16); }
__device__ __forceinline__ float elu1(float v) { return v > 0.f ? v : expm1f(v); }
__device__ __forceinline__ s8v zero8() {
  s8v v;
  #pragma unroll
  for (int j = 0; j < 8; ++j) v[j] = 0;
  return v;
}
__device__ __forceinline__ unsigned pack2(float a, float b) {
  return (unsigned)f2bf(a) | ((unsigned)f2bf(b) << 16);
}

// Fragment-tile layout everywhere: 1 KB tile = 16 rows x 32 k (bf16).
// unit(16B) = ((k>>3)&3)*16 + (row&15) ; elem = k&7.
// A wave's fragment load = tile_base + lane*16  (fully coalesced).

// ---------------------------------------------------------------------------
// P: all weight preps (fragment-tiled) + pairF. grid 4328 (s8v units/thread).
//  [0,64) WoF (16384 units) ; [64,80) WdF (4096) ; [80,88) WlrF (2048) ;
//  [88,160) wP1 (18432) ; [160,232) wP2 ; [232,4328) pairF.
//  R7 bug fixed: WoF branch had 512 blocks writing 8x past the buffer,
//  clobbering WdF/WlrF.
// ---------------------------------------------------------------------------
__device__ __forceinline__ void prep_convw(const float* __restrict__ w,
                                           u16* __restrict__ wP, int idx)
{
  int h = idx & 3, co = (idx >> 2) & 127, kk = (idx >> 9) & 3, tap = idx >> 11;
  s8v o;
  #pragma unroll
  for (int j = 0; j < 8; ++j) {
    int ci = kk * 32 + h * 8 + j;
    o[j] = (short)f2bf(w[((size_t)co * DP + ci) * 9 + tap]);
  }
  *(s8v*)(wP + (size_t)idx * 8) = o;
}

__global__ __launch_bounds__(256) void k_prep_all(
    const float* __restrict__ Wl, const float* __restrict__ Wr,
    const float* __restrict__ Wo, const float* __restrict__ Wd,
    const float* __restrict__ conv1, const float* __restrict__ conv2,
    const float* __restrict__ pair,
    u16* __restrict__ WlrF, u16* __restrict__ WoF, u16* __restrict__ WdF,
    u16* __restrict__ wP1, u16* __restrict__ wP2, u16* __restrict__ pairF)
{
  __shared__ alignas(16) u16 plds[16 * 136];
  int bx = blockIdx.x, t = threadIdx.x;
  if (bx < 64) {
    // WoF: 128 c-rows x 1024 kp (kp = j*32+i). tile = (c>>4)*32 + (kp>>5).
    // 16384 units total; o is the UNIT index.
    int o = bx * 256 + t;                       // 0..16383
    int tile = o >> 6, u = o & 63;
    int cblk = tile >> 5, j = tile & 31;        // kp>>5 == j
    int kslot = u >> 4, cl = u & 15;
    int c = cblk * 16 + cl;
    s8v v;
    #pragma unroll
    for (int e = 0; e < 8; ++e) {
      int i = kslot * 8 + e;
      v[e] = (short)f2bf(Wo[(size_t)(i * 32 + j) * DP + c]);
    }
    *(s8v*)(WoF + (size_t)o * 8) = v;
  } else if (bx < 80) {
    // WdF: 128 c-rows x 256 k. tile = (c>>4)*8 + (k>>5). 4096 units.
    int o = (bx - 64) * 256 + t;                // 0..4095
    int tile = o >> 6, u = o & 63;
    int cblk = tile >> 3, kch = tile & 7;
    int kslot = u >> 4, cl = u & 15;
    int c = cblk * 16 + cl;
    s8v v;
    #pragma unroll
    for (int e = 0; e < 8; ++e) {
      int k = kch * 32 + kslot * 8 + e;
      v[e] = (short)f2bf(Wd[(size_t)k * DP + c]);
    }
    *(s8v*)(WdF + (size_t)o * 8) = v;
  } else if (bx < 88) {
    // WlrF: 64 n-rows x 256 k. tile = (n>>4)*8 + (k>>5). 2048 units.
    int o = (bx - 80) * 256 + t;                // 0..2047
    int tile = o >> 6, u = o & 63;
    int nblk = tile >> 3, kch = tile & 7;
    int kslot = u >> 4, cl = u & 15;
    int n = nblk * 16 + cl;
    s8v v;
    #pragma unroll
    for (int e = 0; e < 8; ++e) {
      int k = kch * 32 + kslot * 8 + e;
      float x = (n < 32) ? Wl[k * DH + n] : Wr[k * DH + (n - 32)];
      v[e] = (short)f2bf(x);
    }
    *(s8v*)(WlrF + (size_t)o * 8) = v;
  } else if (bx < 160) {
    prep_convw(conv1, wP1, (bx - 88) * 256 + t);
  } else if (bx < 232) {
    prep_convw(conv2, wP2, (bx - 160) * 256 + t);
  } else {
    // pairF: one 16-pix block per block. read coalesced, LDS, write tiled.
    int pb = bx - 232;                          // 0..4095
    #pragma unroll
    for (int it = 0; it < 2; ++it) {
      int idx = it * 256 + t;                   // 512 float4 units
      int pix = idx >> 5, f4i = idx & 31;
      float4 v = ((const float4*)pair)[(size_t)(pb * 16 + pix) * 32 + f4i];
      s4v o;
      o[0] = (short)f2bf(v.x); o[1] = (short)f2bf(v.y);
      o[2] = (short)f2bf(v.z); o[3] = (short)f2bf(v.w);
      *(s4v*)(plds + pix * 136 + f4i * 4) = o;
    }
    __syncthreads();
    int kch = t >> 6, u = t & 63;
    int kslot = u >> 4, cl = u & 15;
    int k0 = kch * 32 + kslot * 8;
    s8v v = *(const s8v*)(plds + cl * 136 + k0);
    *(s8v*)(pairF + ((size_t)pb * 256 + t) * 8) = v;
  }
}

// ---------------------------------------------------------------------------
// K1: LayerNorm -> msaF fragment-tiled [32768 rows][256 k]. grid 2048 (16 rows).
// ---------------------------------------------------------------------------
__global__ __launch_bounds__(256) void k_ln(const float* __restrict__ msa,
                                            const float* __restrict__ g,
                                            const float* __restrict__ b,
                                            u16* __restrict__ msaF)
{
  __shared__ alignas(16) u16 lds[16 * 264];
  int t = threadIdx.x, lane = t & 63, wid = t >> 6;
  int row0 = blockIdx.x * 16;
  const float4 gv = ((const float4*)g)[lane];
  const float4 bv = ((const float4*)b)[lane];
  #pragma unroll
  for (int rr = 0; rr < 4; ++rr) {
    int row = row0 + wid * 4 + rr;
    float4 v = ((const float4*)(msa + (size_t)row * DM))[lane];
    float s = v.x + v.y + v.z + v.w;
    float q = v.x * v.x + v.y * v.y + v.z * v.z + v.w * v.w;
    #pragma unroll
    for (int off = 32; off; off >>= 1) { s += __shfl_down(s, off); q += __shfl_down(q, off); }
    s = __shfl(s, 0); q = __shfl(q, 0);
    float mean = s * (1.f / DM);
    float var  = q * (1.f / DM) - mean * mean;
    float rstd = rsqrtf(var + 1e-5f);
    s4v o;
    o[0] = (short)f2bf((v.x - mean) * rstd * gv.x + bv.x);
    o[1] = (short)f2bf((v.y - mean) * rstd * gv.y + bv.y);
    o[2] = (short)f2bf((v.z - mean) * rstd * gv.z + bv.z);
    o[3] = (short)f2bf((v.w - mean) * rstd * gv.w + bv.w);
    *(s4v*)(lds + (wid * 4 + rr) * 264 + lane * 4) = o;
  }
  __syncthreads();
  #pragma unroll
  for (int it = 0; it < 2; ++it) {
    int o = it * 256 + t;                   // 512 units
    int kch = o >> 6, kslot = (o >> 4) & 3, rr = o & 15;
    int k0 = kch * 32 + kslot * 8;
    s8v v = *(const s8v*)(lds + rr * 264 + k0);
    *(s8v*)(msaF + (size_t)blockIdx.x * 4096 + (size_t)o * 8) = v;
  }
}

// ---------------------------------------------------------------------------
// K2: msaF @ WlrF -> leftT/rightT bf16 (row-major [row][s], scattered writes;
// fragpack fixes layout). grid 128 (one s per block).
// ---------------------------------------------------------------------------
__global__ __launch_bounds__(256) void k_gemm_lr(const u16* __restrict__ msaF,
                                                 const u16* __restrict__ WlrF,
                                                 const float* __restrict__ bl,
                                                 const float* __restrict__ br,
                                                 u16* __restrict__ leftT,
                                                 u16* __restrict__ rightT)
{
  int lane = threadIdx.x & 63, wid = threadIdx.x >> 6;
  int sIdx = blockIdx.x;
  f4v acc[4][4] = {};
  #pragma unroll
  for (int ks = 0; ks < 8; ++ks) {
    s8v a[4], bb[4];
    #pragma unroll
    for (int mi = 0; mi < 4; ++mi)
      a[mi] = *(const s8v*)(msaF + ((size_t)(sIdx * 16 + wid * 4 + mi) * 8 + ks) * 512 + lane * 8);
    #pragma unroll
    for (int ni = 0; ni < 4; ++ni)
      bb[ni] = *(const s8v*)(WlrF + ((size_t)(ni * 8 + ks)) * 512 + lane * 8);
    #pragma unroll
    for (int mi = 0; mi < 4; ++mi)
      #pragma unroll
      for (int ni = 0; ni < 4; ++ni)
        acc[mi][ni] = MFMA(a[mi], bb[ni], acc[mi][ni]);
  }
  #pragma unroll
  for (int mi = 0; mi < 4; ++mi) {
    #pragma unroll
    for (int ni = 0; ni < 4; ++ni) {
      int n = ni * 16 + (lane & 15);
      #pragma unroll
      for (int r = 0; r < 4; ++r) {
        int l = wid * 64 + mi * 16 + (lane >> 4) * 4 + r;
        float v = acc[mi][ni][r];
        if (n < 32) {
          leftT[((size_t)l * 32 + n) * 128 + sIdx] = f2bf(v + bl[n]);
        } else {
          rightT[((size_t)l * 32 + (n - 32)) * 128 + sIdx] =
              f2bf((v + br[n - 32]) * (1.f / NS));
        }
      }
    }
  }
}

// ---------------------------------------------------------------------------
// K3: fragpack: leftT/rightT row-major -> leftF (strip-major) / rightF
// (gcol-order) fragment tiles. grid 256 (128 left strips + 128 right blocks).
// ---------------------------------------------------------------------------
__global__ __launch_bounds__(256) void k_fragpack(const u16* __restrict__ leftT,
                                                  const u16* __restrict__ rightT,
                                                  u16* __restrict__ leftF,
                                                  u16* __restrict__ rightF)
{
  __shared__ alignas(16) u16 lds[64 * 136];
  int t = threadIdx.x, bx = blockIdx.x;
  bool isR = bx >= 128;
  int blk = isR ? (bx - 128) : bx;
  #pragma unroll
  for (int it = 0; it < 4; ++it) {
    int u = it * 256 + t;                   // 1024 units in
    int row = u >> 4, sc = u & 15;
    const u16* src;
    if (!isR) {
      src = leftT + ((size_t)(blk * 64 + row)) * 128 + sc * 8;
    } else {
      int gcol = blk * 64 + row;
      int mg = gcol >> 10, rem = gcol & 1023;
      int jc = rem >> 8, nc = rem & 255;
      int m = mg * 32 + (nc >> 3), j = jc * 8 + (nc & 7);
      src = rightT + ((size_t)(m * 32 + j)) * 128 + sc * 8;
    }
    *(s8v*)(lds + row * 136 + sc * 8) = *(const s8v*)src;
  }
  __syncthreads();
  u16* dst = (isR ? rightF : leftF) + (size_t)blk * 8192;
  #pragma unroll
  for (int it = 0; it < 4; ++it) {
    int o = it * 256 + t;                   // 1024 units out
    int tloc = o >> 6, u = o & 63;
    int rb = tloc >> 2, sc2 = tloc & 3;
    int kslot = u >> 4, rr = u & 15;
    int row = rb * 16 + rr, s0 = sc2 * 32 + kslot * 8;
    *(s8v*)(dst + (size_t)o * 8) = *(const s8v*)(lds + row * 136 + s0);
  }
}

// ---------------------------------------------------------------------------
// K4: fused outer-product + Wo-proj + proj_down. All operands fragment-tiled,
// all global loads coalesced 1KB wave-bursts. Block 64 px, 512 thr, grid 1024.
// ---------------------------------------------------------------------------
__global__ __launch_bounds__(512, 4) void k_fused(
    const u16* __restrict__ leftF, const u16* __restrict__ rightF,
    const u16* __restrict__ WoF, const u16* __restrict__ pairF,
    const u16* __restrict__ WdF, const float* __restrict__ bo,
    const float* __restrict__ bd, u16* __restrict__ pN)
{
  __shared__ alignas(16) u16 Als[8192];    // 16 KB: A strip, 16 tiles
  __shared__ alignas(16) u16 opL[16384];   // 32 KB: op chunk, 32 tiles (XOR jj)
  __shared__ alignas(16) u16 obL[8192];    // 16 KB: ob [pix][c] ^ pix-XOR
  int t = threadIdx.x, lane = t & 63, w = t >> 6;
  int rlo = lane & 15, slot = lane >> 4;
  int mg = blockIdx.x >> 7, lp = blockIdx.x & 127;
  int l0 = lp * 2, m0 = mg * 32;

  #pragma unroll
  for (int i = 0; i < 2; ++i) {
    int u = t + 512 * i;
    *(s8v*)(Als + (size_t)u * 8) = *(const s8v*)(leftF + (size_t)lp * 8192 + (size_t)u * 8);
  }
  __syncthreads();

  f4v acc2[4] = {};
  #pragma unroll
  for (int jc = 0; jc < 4; ++jc) {
    // ---- phase 1: op chunk (64 rows (l,i) x 256 cols (m,jj)) ----
    {
      s8v bb[8];
      #pragma unroll
      for (int ks = 0; ks < 4; ++ks)
        #pragma unroll
        for (int ni = 0; ni < 2; ++ni)
          bb[ks * 2 + ni] = *(const s8v*)(rightF +
              ((size_t)((mg * 64 + jc * 16 + w * 2 + ni) * 4 + ks)) * 512 + lane * 8);
      f4v acc1[4][2] = {};
      #pragma unroll
      for (int ks = 0; ks < 4; ++ks) {
        s8v a[4];
        #pragma unroll
        for (int mi = 0; mi < 4; ++mi)
          a[mi] = *(const s8v*)(Als + (size_t)(mi * 4 + ks) * 512 + lane * 8);
        #pragma unroll
        for (int mi = 0; mi < 4; ++mi)
          #pragma unroll
          for (int ni = 0; ni < 2; ++ni)
            acc1[mi][ni] = MFMA(a[mi], bb[ks * 2 + ni], acc1[mi][ni]);
      }
      #pragma unroll
      for (int mi = 0; mi < 4; ++mi) {
        int i0 = (mi & 1) * 16 + slot * 4;
        int lLoc = mi >> 1;
        int kslot = (i0 >> 3) & 3;
        #pragma unroll
        for (int ni = 0; ni < 2; ++ni) {
          int n = w * 32 + ni * 16 + rlo;
          int pix = lLoc * 32 + (n >> 3);
          int jj = n & 7;
          s4v o;
          #pragma unroll
          for (int r = 0; r < 4; ++r) o[r] = (short)f2bf(acc1[mi][ni][r]);
          int byte = ((pix >> 4) * 8 + jj) * 1024 +
                     (kslot * 16 + ((pix & 15) ^ jj)) * 16 + (i0 & 7) * 2;
          *(s4v*)((char*)opL + byte) = o;
        }
      }
    }
    __syncthreads();
    // ---- phase 2: acc2 += op_chunk @ WoF_chunk (wave w -> c slice w*16) ----
    {
      s8v wb[8];
      #pragma unroll
      for (int ks = 0; ks < 8; ++ks)
        wb[ks] = *(const s8v*)(WoF + ((size_t)(w * 32 + jc * 8 + ks)) * 512 + lane * 8);
      #pragma unroll
      for (int ks = 0; ks < 8; ++ks) {
        s8v a[4];
        #pragma unroll
        for (int mi = 0; mi < 4; ++mi) {
          int byte = (mi * 8 + ks) * 1024 + (slot * 16 + (rlo ^ ks)) * 16;
          a[mi] = *(const s8v*)((const char*)opL + byte);
        }
        #pragma unroll
        for (int mi = 0; mi < 4; ++mi)
          acc2[mi] = MFMA(a[mi], wb[ks], acc2[mi]);
      }
    }
    __syncthreads();
  }

  // ob -> obL (+bo)
  {
    int c = w * 16 + rlo;
    float bias = bo[c];
    #pragma unroll
    for (int mi = 0; mi < 4; ++mi)
      #pragma unroll
      for (int r = 0; r < 4; ++r) {
        int pix = mi * 16 + slot * 4 + r;
        int byte = (pix * 256 + c * 2) ^ ((pix & 7) << 4);
        *(u16*)((char*)obL + byte) = f2bf(acc2[mi][r] + bias);
      }
  }
  __syncthreads();

  // ---- phase 3: p = [pairF | ob] @ WdF + bd ----
  int wr = w >> 2, wcq = w & 3;
  int pix0 = wr * 32, c0 = wcq * 32;
  {
    f4v acc[2][2] = {};
    #pragma unroll
    for (int ks = 0; ks < 4; ++ks) {        // K 0..127 from pairF
      s8v a[2], b[2];
      #pragma unroll
      for (int mi = 0; mi < 2; ++mi) {
        int pb = (l0 + wr) * 16 + (m0 >> 4) + mi;
        a[mi] = *(const s8v*)(pairF + ((size_t)(pb * 4 + ks)) * 512 + lane * 8);
      }
      #pragma unroll
      for (int ni = 0; ni < 2; ++ni) {
        int cblk = wcq * 2 + ni;
        b[ni] = *(const s8v*)(WdF + ((size_t)(cblk * 8 + ks)) * 512 + lane * 8);
      }
      #pragma unroll
      for (int mi = 0; mi < 2; ++mi)
        #pragma unroll
        for (int ni = 0; ni < 2; ++ni)
          acc[mi][ni] = MFMA(a[mi], b[ni], acc[mi][ni]);
    }
    #pragma unroll
    for (int ks = 0; ks < 4; ++ks) {        // K 128..255 from obL
      s8v a[2], b[2];
      #pragma unroll
      for (int mi = 0; mi < 2; ++mi) {
        int pix = pix0 + mi * 16 + rlo;
        int k = ks * 32 + slot * 8;
        int byte = (pix * 256 + k * 2) ^ ((pix & 7) << 4);
        a[mi] = *(const s8v*)((const char*)obL + byte);
      }
      #pragma unroll
      for (int ni = 0; ni < 2; ++ni) {
        int cblk = wcq * 2 + ni;
        b[ni] = *(const s8v*)(WdF + ((size_t)(cblk * 8 + 4 + ks)) * 512 + lane * 8);
      }
      #pragma unroll
      for (int mi = 0; mi < 2; ++mi)
        #pragma unroll
        for (int ni = 0; ni < 2; ++ni)
          acc[mi][ni] = MFMA(a[mi], b[ni], acc[mi][ni]);
    }
    #pragma unroll
    for (int mi = 0; mi < 2; ++mi)
      #pragma unroll
      for (int ni = 0; ni < 2; ++ni) {
        int c = c0 + ni * 16 + rlo;
        float bias = bd[c];
        #pragma unroll
        for (int r = 0; r < 4; ++r) {
          int pix = pix0 + mi * 16 + slot * 4 + r;
          int byte = (pix * 256 + c * 2) ^ ((pix & 7) << 4);
          *(u16*)((char*)opL + byte) = f2bf(acc[mi][ni][r] + bias);
        }
      }
  }
  __syncthreads();

  // write pN coalesced
  #pragma unroll
  for (int q = 0; q < 2; ++q) {
    int u = q * 512 + t;
    int pix = u >> 4, off = u & 15;
    int byte = (pix * 256 + off * 16) ^ ((pix & 7) << 4);
    uint4 v = *(const uint4*)((const char*)opL + byte);
    int pixG = (l0 + (pix >> 5)) * 256 + m0 + (pix & 31);
    *(uint4*)(pN + (size_t)pixG * 128 + off * 8) = v;
  }
}

// ---------------------------------------------------------------------------
// K5: conv3x3 implicit-GEMM MFMA. NHWC bf16 in -> NHWC f32 out (LDS-transpose
// epilogue, coalesced stores) + fused IN partials. grid (4, 128).
// ---------------------------------------------------------------------------
__global__ __launch_bounds__(256, 2) void k_conv(const u16* __restrict__ inN,
                                                 const u16* __restrict__ wP,
                                                 float* __restrict__ out,
                                                 float* __restrict__ gS,
                                                 float* __restrict__ gQ)
{
  __shared__ alignas(16) u16 Ast[4 * 66 * 128];   // 67584 B (reused as f32 out)
  __shared__ float partS[4][64], partQ[4][64];
  int t = threadIdx.x, lane = t & 63, w = t >> 6;
  int rlo = lane & 15, slot = lane >> 4;
  int x0 = blockIdx.x * 64, y0 = blockIdx.y * 2;
  for (int u = t; u < 4224; u += 256) {
    int r = u / 1056;
    int rem = u - r * 1056;
    int p = rem >> 4, ku = rem & 15;
    int gy = y0 + r - 1, gx = x0 - 1 + p;
    s8v v = zero8();
    if ((unsigned)gy < 256u && (unsigned)gx < 256u)
      v = *(const s8v*)(inN + ((size_t)gy * LL + gx) * 128 + ku * 8);
    int lb = (u * 16) ^ ((p & 7) << 4);
    *(s8v*)((char*)Ast + lb) = v;
  }
  __syncthreads();
  int wpy = w >> 1, co0 = (w & 1) * 64;
  f4v acc[4][4] = {};
  #pragma unroll
  for (int tap = 0; tap < 9; ++tap) {
    const int dy = tap / 3, dx = tap % 3;
    #pragma unroll
    for (int kk = 0; kk < 4; ++kk) {
      s8v a[4], b[4];
      #pragma unroll
      for (int mi = 0; mi < 4; ++mi) {
        int p = mi * 16 + rlo + dx;
        int lb = (((wpy + dy) * 66 + p) * 256 + kk * 64 + slot * 16) ^ ((p & 7) << 4);
        a[mi] = *(const s8v*)((const char*)Ast + lb);
      }
      #pragma unroll
      for (int ni = 0; ni < 4; ++ni) {
        int co = co0 + ni * 16 + rlo;
        b[ni] = *(const s8v*)(wP + ((size_t)((tap * 4 + kk) * 128 + co) * 4 + slot) * 8);
      }
      #pragma unroll
      for (int mi = 0; mi < 4; ++mi)
        #pragma unroll
        for (int ni = 0; ni < 4; ++ni)
          acc[mi][ni] = MFMA(a[mi], b[ni], acc[mi][ni]);
    }
  }
  // IN partial stats from registers
  #pragma unroll
  for (int ni = 0; ni < 4; ++ni) {
    float s = 0.f, q = 0.f;
    #pragma unroll
    for (int mi = 0; mi < 4; ++mi)
      #pragma unroll
      for (int r = 0; r < 4; ++r) {
        float v = acc[mi][ni][r];
        s += v; q += v * v;
      }
    s += __shfl_xor(s, 16); s += __shfl_xor(s, 32);
    q += __shfl_xor(q, 16); q += __shfl_xor(q, 32);
    if (slot == 0) { partS[w][ni * 16 + rlo] = s; partQ[w][ni * 16 + rlo] = q; }
  }
  __syncthreads();           // all Ast reads done; safe to reuse
  float* AstF = (float*)Ast; // [wpy][64 px][128 co] f32, XOR (pix&7)<<4
  #pragma unroll
  for (int mi = 0; mi < 4; ++mi)
    #pragma unroll
    for (int ni = 0; ni < 4; ++ni) {
      int co = co0 + ni * 16 + rlo;
      #pragma unroll
      for (int r = 0; r < 4; ++r) {
        int pix = mi * 16 + slot * 4 + r;
        int byte = wpy * 32768 + ((pix * 512 + co * 4) ^ ((pix & 7) << 4));
        *(float*)((char*)AstF + byte) = acc[mi][ni][r];
      }
    }
  if (t < 128) {
    int half = t >> 6, cl = t & 63;
    int bid = blockIdx.y * 4 + blockIdx.x;
    gS[bid * 128 + t] = partS[half][cl] + partS[2 + half][cl];
    gQ[bid * 128 + t] = partQ[half][cl] + partQ[2 + half][cl];
  }
  __syncthreads();
  #pragma unroll
  for (int it = 0; it < 16; ++it) {
    int u = it * 256 + t;                   // 4096 float4 units
    int wpy2 = u >> 11, rem = u & 2047;
    int pix = rem >> 5, cv = rem & 31;
    int byte = wpy2 * 32768 + ((pix * 512 + cv * 16) ^ ((pix & 7) << 4));
    float4 v = *(const float4*)((const char*)AstF + byte);
    *(float4*)(out + ((size_t)(y0 + wpy2) * LL + x0 + pix) * 128 + cv * 4) = v;
  }
}

// ---------------------------------------------------------------------------
// K6: reduce 512 partials -> stats. grid 1, block 512.
// ---------------------------------------------------------------------------
__global__ __launch_bounds__(512) void k_instat2(const float* __restrict__ gS,
                                                 const float* __restrict__ gQ,
                                                 float* __restrict__ st)
{
  __shared__ float redS[512], redQ[512];
  int t = threadIdx.x, c = t & 127, q = t >> 7;
  float s = 0.f, s2 = 0.f;
  for (int i = q * 128; i < q * 128 + 128; ++i) {
    s  += gS[i * 128 + c];
    s2 += gQ[i * 128 + c];
  }
  redS[t] = s; redQ[t] = s2;
  __syncthreads();
  if (t < 128) {
    s  = redS[t] + redS[t + 128] + redS[t + 256] + redS[t + 384];
    s2 = redQ[t] + redQ[t + 128] + redQ[t + 256] + redQ[t + 384];
    float m = s * (1.f / HW);
    float var = s2 * (1.f / HW) - m * m;
    st[t] = m;
    st[128 + t] = rsqrtf(var + 1e-6f);
  }
}

// ---------------------------------------------------------------------------
// K7: h1N = NHWC bf16 of elu(IN(h1)); pure streaming. grid 8192.
// ---------------------------------------------------------------------------
__global__ __launch_bounds__(256) void k_in_elu(const float* __restrict__ h,
                                                const float* __restrict__ st,
                                                const float* __restrict__ g,
                                                const float* __restrict__ b,
                                                u16* __restrict__ hN)
{
  int i = blockIdx.x * 256 + threadIdx.x;   // 2M float4 units
  int c4 = i & 31;
  float4 v = ((const float4*)h)[i];
  float4 m = ((const float4*)st)[c4];
  float4 r = ((const float4*)(st + 128))[c4];
  float4 gg = ((const float4*)g)[c4];
  float4 bb = ((const float4*)b)[c4];
  float o0 = elu1((v.x - m.x) * r.x * gg.x + bb.x);
  float o1 = elu1((v.y - m.y) * r.y * gg.y + bb.y);
  float o2 = elu1((v.z - m.z) * r.z * gg.z + bb.z);
  float o3 = elu1((v.w - m.w) * r.w * gg.w + bb.w);
  uint2 o; o.x = pack2(o0, o1); o.y = pack2(o2, o3);
  ((uint2*)hN)[i] = o;
}

// ---------------------------------------------------------------------------
// K8: out = elu(pN + IN2(h2)); pure streaming. grid 8192.
// ---------------------------------------------------------------------------
__global__ __launch_bounds__(256) void k_final(const u16* __restrict__ pN,
                                               const float* __restrict__ h2,
                                               const float* __restrict__ st,
                                               const float* __restrict__ g,
                                               const float* __restrict__ b,
                                               float* __restrict__ out)
{
  int i = blockIdx.x * 256 + threadIdx.x;
  int c4 = i & 31;
  float4 v = ((const float4*)h2)[i];
  uint2 pv = ((const uint2*)pN)[i];
  float4 m = ((const float4*)st)[c4];
  float4 r = ((const float4*)(st + 128))[c4];
  float4 gg = ((const float4*)g)[c4];
  float4 bb = ((const float4*)b)[c4];
  float4 o;
  o.x = bf2f((u16)(pv.x & 0xffff)) + (v.x - m.x) * r.x * gg.x + bb.x;
  o.y = bf2f((u16)(pv.x >> 16))    + (v.y - m.y) * r.y * gg.y + bb.y;
  o.z = bf2f((u16)(pv.y & 0xffff)) + (v.z - m.z) * r.z * gg.z + bb.z;
  o.w = bf2f((u16)(pv.y >> 16))    + (v.w - m.w) * r.w * gg.w + bb.w;
  o.x = o.x > 0.f ? o.x : expm1f(o.x);
  o.y = o.y > 0.f ? o.y : expm1f(o.y);
  o.z = o.z > 0.f ? o.z : expm1f(o.z);
  o.w = o.w > 0.f ? o.w : expm1f(o.w);
  ((float4*)out)[i] = o;
}

// ---------------------------------------------------------------------------
extern "C" void kernel_launch(void* const* d_in, const int* in_sizes, int n_in,
                              void* d_out, int out_size, void* d_ws, size_t ws_size,
                              hipStream_t stream)
{
  const float* msa   = (const float*)d_in[0];
  const float* pair  = (const float*)d_in[1];
  const float* ln_g  = (const float*)d_in[2];
  const float* ln_b  = (const float*)d_in[3];
  const float* Wl    = (const float*)d_in[4];
  const float* bl    = (const float*)d_in[5];
  const float* Wr    = (const float*)d_in[6];
  const float* br    = (const float*)d_in[7];
  const float* Wo    = (const float*)d_in[8];
  const float* bo    = (const float*)d_in[9];
  const float* Wd    = (const float*)d_in[10];
  const float* bd    = (const float*)d_in[11];
  const float* conv1 = (const float*)d_in[12];
  const float* in1_g = (const float*)d_in[13];
  const float* in1_b = (const float*)d_in[14];
  const float* conv2 = (const float*)d_in[15];
  const float* in2_g = (const float*)d_in[16];
  const float* in2_b = (const float*)d_in[17];
  float* out = (float*)d_out;

  // Workspace (F = 1Mi floats = 4 MB), peak ~105.4 MB:
  //  [0,4F)    msaF (dead after gemm_lr) -> h1N (bf16)
  //  [4F,5F)   leftT+rightT (dead after fragpack)
  //  [5F,5.5F) leftF ; [5.5F,6F) rightF
  //  [6F,10F)  pN (NHWC bf16, live to end)
  //  [10F,18F) h1 (NHWC f32)
  //  [18F,26F) h2 (NHWC f32); pairF overlays its back half [22F,26F)
  //            (pairF dead after k_fused, h2 written later by conv2)
  //  [26F,..)  gS/gQ + stats + fragment weights
  float* ws = (float*)d_ws;
  const size_t F = 1048576;
  u16* msaF   = (u16*)ws;
  u16* h1N    = (u16*)ws;
  u16* leftT  = (u16*)(ws + 4 * F);
  u16* rightT = (u16*)(ws + 4 * F + F / 2);
  u16* leftF  = (u16*)(ws + 5 * F);
  u16* rightF = (u16*)(ws + 5 * F + F / 2);
  u16* pN     = (u16*)(ws + 6 * F);
  float* h1   = ws + 10 * F;
  float* h2   = ws + 18 * F;
  u16* pairF  = (u16*)(ws + 22 * F);
  float* gS   = ws + 26 * F;                 // 65536
  float* gQ   = ws + 26 * F + 65536;         // 65536
  float* stats = ws + 26 * F + 131072;       // 512
  u16* aux    = (u16*)(ws + 26 * F + 131584);
  u16* wP1    = aux;                         // 147456
  u16* wP2    = aux + 147456;                // 147456
  u16* WoF    = aux + 294912;                // 131072
  u16* WdF    = aux + 425984;                // 32768
  u16* WlrF   = aux + 458752;                // 16384

  k_prep_all<<<dim3(4328), dim3(256), 0, stream>>>(Wl, Wr, Wo, Wd, conv1, conv2,
                                                   pair, WlrF, WoF, WdF, wP1, wP2, pairF);
  k_ln<<<dim3(2048), dim3(256), 0, stream>>>(msa, ln_g, ln_b, msaF);
  k_gemm_lr<<<dim3(128), dim3(256), 0, stream>>>(msaF, WlrF, bl, br, leftT, rightT);
  k_fragpack<<<dim3(256), dim3(256), 0, stream>>>(leftT, rightT, leftF, rightF);

  k_fused<<<dim3(1024), dim3(512), 0, stream>>>(leftF, rightF, WoF, pairF, WdF,
                                                bo, bd, pN);

  k_conv<<<dim3(4, 128), dim3(256), 0, stream>>>(pN, wP1, h1, gS, gQ);
  k_instat2<<<dim3(1), dim3(512), 0, stream>>>(gS, gQ, stats);
  k_in_elu<<<dim3(8192), dim3(256), 0, stream>>>(h1, stats, in1_g, in1_b, h1N);

  k_conv<<<dim3(4, 128), dim3(256), 0, stream>>>(h1N, wP2, h2, gS, gQ);
  k_instat2<<<dim3(1), dim3(512), 0, stream>>>(gS, gQ, stats + 256);

  k_final<<<dim3(8192), dim3(256), 0, stream>>>(pN, h2, stats + 256, in2_g, in2_b, out);
}

// Round 9
// 234.962 us; speedup vs baseline: 8.8626x; 1.0394x over previous
//
#include <hip/hip_runtime.h>
#include <math.h>

#define LL 256      // L
#define NS 128      // N sequences
#define DM 256      // d_msa
#define DH 32       // d_h
#define DP 128      // d_pair
#define HW 65536    // L*L

using u16 = unsigned short;
typedef __attribute__((ext_vector_type(8))) short s8v;   // 8 bf16 (A/B frag)
typedef __attribute__((ext_vector_type(4))) short s4v;   // 4 bf16
typedef __attribute__((ext_vector_type(4))) float f4v;   // C/D frag

#define MFMA(a, b, c) __builtin_amdgcn_mfma_f32_16x16x32_bf16((a), (b), (c), 0, 0, 0)

__device__ __forceinline__ u16 f2bf(float f) {
  unsigned u = __float_as_uint(f);
  u = (u + 0x7FFFu + ((u >> 16) & 1u)) >> 16;   // RNE
  return (u16)u;
}
__device__ __forceinline__ unsigned cvtpk2(float lo, float hi) {
  unsigned r;
  asm("v_cvt_pk_bf16_f32 %0, %1, %2" : "=v"(r) : "v"(lo), "v"(hi));
  return r;
}
__device__ __forceinline__ float bf2f(u16 h) { return __uint_as_float(((unsigned)h) << 16); }
__device__ __forceinline__ float elu1(float v) { return v > 0.f ? v : expm1f(v); }
__device__ __forceinline__ s8v zero8() {
  s8v v;
  #pragma unroll
  for (int j = 0; j < 8; ++j) v[j] = 0;
  return v;
}

// Fragment-tile layout: 1 KB tile = 16 rows x 32 k (bf16).
// unit(16B) = ((k>>3)&3)*16 + (row&15) ; elem = k&7.
// Wave fragment load = tile_base + lane*16 (fully coalesced).

// ---------------------------------------------------------------------------
// P: weight preps (fragment-tiled) + pairF + LayerNorm->msaF, one launch.
//  [0,64) WoF ; [64,80) WdF ; [80,88) WlrF ; [88,160) wP1 ; [160,232) wP2 ;
//  [232,4328) pairF ; [4328,6376) LN blocks.
// ---------------------------------------------------------------------------
__device__ __forceinline__ void prep_convw(const float* __restrict__ w,
                                           u16* __restrict__ wP, int idx)
{
  int h = idx & 3, co = (idx >> 2) & 127, kk = (idx >> 9) & 3, tap = idx >> 11;
  s8v o;
  #pragma unroll
  for (int j = 0; j < 8; ++j) {
    int ci = kk * 32 + h * 8 + j;
    o[j] = (short)f2bf(w[((size_t)co * DP + ci) * 9 + tap]);
  }
  *(s8v*)(wP + (size_t)idx * 8) = o;
}

__global__ __launch_bounds__(256) void k_prep_ln(
    const float* __restrict__ Wl, const float* __restrict__ Wr,
    const float* __restrict__ Wo, const float* __restrict__ Wd,
    const float* __restrict__ conv1, const float* __restrict__ conv2,
    const float* __restrict__ pair,
    const float* __restrict__ msa, const float* __restrict__ ln_g,
    const float* __restrict__ ln_b,
    u16* __restrict__ WlrF, u16* __restrict__ WoF, u16* __restrict__ WdF,
    u16* __restrict__ wP1, u16* __restrict__ wP2, u16* __restrict__ pairF,
    u16* __restrict__ msaF)
{
  __shared__ alignas(16) u16 buf[16 * 264];
  int bx = blockIdx.x, t = threadIdx.x;
  if (bx < 64) {
    // WoF: 128 c-rows x 1024 kp (kp=j*32+i). tile=(c>>4)*32 + j. 16384 units.
    int o = bx * 256 + t;
    int tile = o >> 6, u = o & 63;
    int cblk = tile >> 5, j = tile & 31;
    int kslot = u >> 4, cl = u & 15;
    int c = cblk * 16 + cl;
    s8v v;
    #pragma unroll
    for (int e = 0; e < 8; ++e) {
      int i = kslot * 8 + e;
      v[e] = (short)f2bf(Wo[(size_t)(i * 32 + j) * DP + c]);
    }
    *(s8v*)(WoF + (size_t)o * 8) = v;
  } else if (bx < 80) {
    int o = (bx - 64) * 256 + t;                // 4096 units
    int tile = o >> 6, u = o & 63;
    int cblk = tile >> 3, kch = tile & 7;
    int kslot = u >> 4, cl = u & 15;
    int c = cblk * 16 + cl;
    s8v v;
    #pragma unroll
    for (int e = 0; e < 8; ++e) {
      int k = kch * 32 + kslot * 8 + e;
      v[e] = (short)f2bf(Wd[(size_t)k * DP + c]);
    }
    *(s8v*)(WdF + (size_t)o * 8) = v;
  } else if (bx < 88) {
    int o = (bx - 80) * 256 + t;                // 2048 units
    int tile = o >> 6, u = o & 63;
    int nblk = tile >> 3, kch = tile & 7;
    int kslot = u >> 4, cl = u & 15;
    int n = nblk * 16 + cl;
    s8v v;
    #pragma unroll
    for (int e = 0; e < 8; ++e) {
      int k = kch * 32 + kslot * 8 + e;
      float x = (n < 32) ? Wl[k * DH + n] : Wr[k * DH + (n - 32)];
      v[e] = (short)f2bf(x);
    }
    *(s8v*)(WlrF + (size_t)o * 8) = v;
  } else if (bx < 160) {
    prep_convw(conv1, wP1, (bx - 88) * 256 + t);
  } else if (bx < 232) {
    prep_convw(conv2, wP2, (bx - 160) * 256 + t);
  } else if (bx < 4328) {
    // pairF: one 16-pix block per block.
    int pb = bx - 232;                          // 0..4095
    #pragma unroll
    for (int it = 0; it < 2; ++it) {
      int idx = it * 256 + t;
      int pix = idx >> 5, f4i = idx & 31;
      float4 v = ((const float4*)pair)[(size_t)(pb * 16 + pix) * 32 + f4i];
      s4v o;
      o[0] = (short)f2bf(v.x); o[1] = (short)f2bf(v.y);
      o[2] = (short)f2bf(v.z); o[3] = (short)f2bf(v.w);
      *(s4v*)(buf + pix * 136 + f4i * 4) = o;
    }
    __syncthreads();
    int kch = t >> 6, u = t & 63;
    int kslot = u >> 4, cl = u & 15;
    int k0 = kch * 32 + kslot * 8;
    s8v v = *(const s8v*)(buf + cl * 136 + k0);
    *(s8v*)(pairF + ((size_t)pb * 256 + t) * 8) = v;
  } else {
    // LayerNorm -> msaF fragment-tiled. 2048 blocks x 16 rows.
    int bid = bx - 4328;
    int lane = t & 63, wid = t >> 6;
    int row0 = bid * 16;
    const float4 gv = ((const float4*)ln_g)[lane];
    const float4 bv = ((const float4*)ln_b)[lane];
    #pragma unroll
    for (int rr = 0; rr < 4; ++rr) {
      int row = row0 + wid * 4 + rr;
      float4 v = ((const float4*)(msa + (size_t)row * DM))[lane];
      float s = v.x + v.y + v.z + v.w;
      float q = v.x * v.x + v.y * v.y + v.z * v.z + v.w * v.w;
      #pragma unroll
      for (int off = 32; off; off >>= 1) { s += __shfl_down(s, off); q += __shfl_down(q, off); }
      s = __shfl(s, 0); q = __shfl(q, 0);
      float mean = s * (1.f / DM);
      float var  = q * (1.f / DM) - mean * mean;
      float rstd = rsqrtf(var + 1e-5f);
      s4v o;
      o[0] = (short)f2bf((v.x - mean) * rstd * gv.x + bv.x);
      o[1] = (short)f2bf((v.y - mean) * rstd * gv.y + bv.y);
      o[2] = (short)f2bf((v.z - mean) * rstd * gv.z + bv.z);
      o[3] = (short)f2bf((v.w - mean) * rstd * gv.w + bv.w);
      *(s4v*)(buf + (wid * 4 + rr) * 264 + lane * 4) = o;
    }
    __syncthreads();
    #pragma unroll
    for (int it = 0; it < 2; ++it) {
      int o = it * 256 + t;                   // 512 units
      int kch = o >> 6, kslot = (o >> 4) & 3, rr = o & 15;
      int k0 = kch * 32 + kslot * 8;
      s8v v = *(const s8v*)(buf + rr * 264 + k0);
      *(s8v*)(msaF + (size_t)bid * 4096 + (size_t)o * 8) = v;
    }
  }
}

// ---------------------------------------------------------------------------
// K2: msaF @ WlrF -> leftT/rightT bf16 (row-major; fragpack fixes layout).
// ---------------------------------------------------------------------------
__global__ __launch_bounds__(256) void k_gemm_lr(const u16* __restrict__ msaF,
                                                 const u16* __restrict__ WlrF,
                                                 const float* __restrict__ bl,
                                                 const float* __restrict__ br,
                                                 u16* __restrict__ leftT,
                                                 u16* __restrict__ rightT)
{
  int lane = threadIdx.x & 63, wid = threadIdx.x >> 6;
  int sIdx = blockIdx.x;
  f4v acc[4][4] = {};
  #pragma unroll
  for (int ks = 0; ks < 8; ++ks) {
    s8v a[4], bb[4];
    #pragma unroll
    for (int mi = 0; mi < 4; ++mi)
      a[mi] = *(const s8v*)(msaF + ((size_t)(sIdx * 16 + wid * 4 + mi) * 8 + ks) * 512 + lane * 8);
    #pragma unroll
    for (int ni = 0; ni < 4; ++ni)
      bb[ni] = *(const s8v*)(WlrF + ((size_t)(ni * 8 + ks)) * 512 + lane * 8);
    #pragma unroll
    for (int mi = 0; mi < 4; ++mi)
      #pragma unroll
      for (int ni = 0; ni < 4; ++ni)
        acc[mi][ni] = MFMA(a[mi], bb[ni], acc[mi][ni]);
  }
  #pragma unroll
  for (int mi = 0; mi < 4; ++mi) {
    #pragma unroll
    for (int ni = 0; ni < 4; ++ni) {
      int n = ni * 16 + (lane & 15);
      #pragma unroll
      for (int r = 0; r < 4; ++r) {
        int l = wid * 64 + mi * 16 + (lane >> 4) * 4 + r;
        float v = acc[mi][ni][r];
        if (n < 32) {
          leftT[((size_t)l * 32 + n) * 128 + sIdx] = f2bf(v + bl[n]);
        } else {
          rightT[((size_t)l * 32 + (n - 32)) * 128 + sIdx] =
              f2bf((v + br[n - 32]) * (1.f / NS));
        }
      }
    }
  }
}

// ---------------------------------------------------------------------------
// K3: fragpack -> leftF / rightF fragment tiles. grid 256.
// ---------------------------------------------------------------------------
__global__ __launch_bounds__(256) void k_fragpack(const u16* __restrict__ leftT,
                                                  const u16* __restrict__ rightT,
                                                  u16* __restrict__ leftF,
                                                  u16* __restrict__ rightF)
{
  __shared__ alignas(16) u16 lds[64 * 136];
  int t = threadIdx.x, bx = blockIdx.x;
  bool isR = bx >= 128;
  int blk = isR ? (bx - 128) : bx;
  #pragma unroll
  for (int it = 0; it < 4; ++it) {
    int u = it * 256 + t;
    int row = u >> 4, sc = u & 15;
    const u16* src;
    if (!isR) {
      src = leftT + ((size_t)(blk * 64 + row)) * 128 + sc * 8;
    } else {
      int gcol = blk * 64 + row;
      int mg = gcol >> 10, rem = gcol & 1023;
      int jc = rem >> 8, nc = rem & 255;
      int m = mg * 32 + (nc >> 3), j = jc * 8 + (nc & 7);
      src = rightT + ((size_t)(m * 32 + j)) * 128 + sc * 8;
    }
    *(s8v*)(lds + row * 136 + sc * 8) = *(const s8v*)src;
  }
  __syncthreads();
  u16* dst = (isR ? rightF : leftF) + (size_t)blk * 8192;
  #pragma unroll
  for (int it = 0; it < 4; ++it) {
    int o = it * 256 + t;
    int tloc = o >> 6, u = o & 63;
    int rb = tloc >> 2, sc2 = tloc & 3;
    int kslot = u >> 4, rr = u & 15;
    int row = rb * 16 + rr, s0 = sc2 * 32 + kslot * 8;
    *(s8v*)(dst + (size_t)o * 8) = *(const s8v*)(lds + row * 136 + s0);
  }
}

// ---------------------------------------------------------------------------
// K4: fused outer-product + Wo-proj + proj_down, software-pipelined:
// wb loads hoisted pre-barrier, bb(jc+1) prefetched pre-barrier, cvt_pk
// stores, setprio around MFMA clusters. Block 64 px, 512 thr, grid 1024.
// ---------------------------------------------------------------------------
__global__ __launch_bounds__(512, 4) void k_fused(
    const u16* __restrict__ leftF, const u16* __restrict__ rightF,
    const u16* __restrict__ WoF, const u16* __restrict__ pairF,
    const u16* __restrict__ WdF, const float* __restrict__ bo,
    const float* __restrict__ bd, u16* __restrict__ pN)
{
  __shared__ alignas(16) u16 Als[8192];    // 16 KB
  __shared__ alignas(16) u16 opL[16384];   // 32 KB
  __shared__ alignas(16) u16 obL[8192];    // 16 KB
  int t = threadIdx.x, lane = t & 63, w = t >> 6;
  int rlo = lane & 15, slot = lane >> 4;
  int mg = blockIdx.x >> 7, lp = blockIdx.x & 127;
  int l0 = lp * 2, m0 = mg * 32;

  #pragma unroll
  for (int i = 0; i < 2; ++i) {
    int u = t + 512 * i;
    *(s8v*)(Als + (size_t)u * 8) = *(const s8v*)(leftF + (size_t)lp * 8192 + (size_t)u * 8);
  }

  f4v acc2[4] = {};
  s8v bb[8];
  #pragma unroll
  for (int ks = 0; ks < 4; ++ks)
    #pragma unroll
    for (int ni = 0; ni < 2; ++ni)
      bb[ks * 2 + ni] = *(const s8v*)(rightF +
          ((size_t)((mg * 64 + 0 * 16 + w * 2 + ni) * 4 + ks)) * 512 + lane * 8);
  __syncthreads();

  #pragma unroll
  for (int jc = 0; jc < 4; ++jc) {
    // ---- phase 1: op chunk ----
    f4v acc1[4][2] = {};
    __builtin_amdgcn_s_setprio(1);
    #pragma unroll
    for (int ks = 0; ks < 4; ++ks) {
      s8v a[4];
      #pragma unroll
      for (int mi = 0; mi < 4; ++mi)
        a[mi] = *(const s8v*)(Als + (size_t)(mi * 4 + ks) * 512 + lane * 8);
      #pragma unroll
      for (int mi = 0; mi < 4; ++mi)
        #pragma unroll
        for (int ni = 0; ni < 2; ++ni)
          acc1[mi][ni] = MFMA(a[mi], bb[ks * 2 + ni], acc1[mi][ni]);
    }
    __builtin_amdgcn_s_setprio(0);
    #pragma unroll
    for (int mi = 0; mi < 4; ++mi) {
      int i0 = (mi & 1) * 16 + slot * 4;
      int lLoc = mi >> 1;
      int kslot = (i0 >> 3) & 3;
      #pragma unroll
      for (int ni = 0; ni < 2; ++ni) {
        int n = w * 32 + ni * 16 + rlo;
        int pix = lLoc * 32 + (n >> 3);
        int jj = n & 7;
        uint2 o2;
        o2.x = cvtpk2(acc1[mi][ni][0], acc1[mi][ni][1]);
        o2.y = cvtpk2(acc1[mi][ni][2], acc1[mi][ni][3]);
        int byte = ((pix >> 4) * 8 + jj) * 1024 +
                   (kslot * 16 + ((pix & 15) ^ jj)) * 16 + (i0 & 7) * 2;
        *(uint2*)((char*)opL + byte) = o2;
      }
    }
    // hoist phase-2 B loads before the barrier (drain => arrived after it)
    s8v wb[8];
    #pragma unroll
    for (int ks = 0; ks < 8; ++ks)
      wb[ks] = *(const s8v*)(WoF + ((size_t)(w * 32 + jc * 8 + ks)) * 512 + lane * 8);
    __syncthreads();
    // ---- phase 2: acc2 += op_chunk @ WoF_chunk ----
    __builtin_amdgcn_s_setprio(1);
    #pragma unroll
    for (int ks = 0; ks < 8; ++ks) {
      s8v a[4];
      #pragma unroll
      for (int mi = 0; mi < 4; ++mi) {
        int byte = (mi * 8 + ks) * 1024 + (slot * 16 + (rlo ^ ks)) * 16;
        a[mi] = *(const s8v*)((const char*)opL + byte);
      }
      #pragma unroll
      for (int mi = 0; mi < 4; ++mi)
        acc2[mi] = MFMA(a[mi], wb[ks], acc2[mi]);
    }
    __builtin_amdgcn_s_setprio(0);
    // prefetch next-jc B fragments before the barrier
    if (jc < 3) {
      #pragma unroll
      for (int ks = 0; ks < 4; ++ks)
        #pragma unroll
        for (int ni = 0; ni < 2; ++ni)
          bb[ks * 2 + ni] = *(const s8v*)(rightF +
              ((size_t)((mg * 64 + (jc + 1) * 16 + w * 2 + ni) * 4 + ks)) * 512 + lane * 8);
    }
    __syncthreads();
  }

  // ob -> obL (+bo)
  {
    int c = w * 16 + rlo;
    float bias = bo[c];
    #pragma unroll
    for (int mi = 0; mi < 4; ++mi)
      #pragma unroll
      for (int r = 0; r < 4; ++r) {
        int pix = mi * 16 + slot * 4 + r;
        int byte = (pix * 256 + c * 2) ^ ((pix & 7) << 4);
        *(u16*)((char*)obL + byte) = f2bf(acc2[mi][r] + bias);
      }
  }
  __syncthreads();

  // ---- phase 3: p = [pairF | ob] @ WdF + bd ----
  int wr = w >> 2, wcq = w & 3;
  int pix0 = wr * 32, c0 = wcq * 32;
  {
    f4v acc[2][2] = {};
    #pragma unroll
    for (int ks = 0; ks < 4; ++ks) {        // K 0..127 from pairF
      s8v a[2], b[2];
      #pragma unroll
      for (int mi = 0; mi < 2; ++mi) {
        int pb = (l0 + wr) * 16 + (m0 >> 4) + mi;
        a[mi] = *(const s8v*)(pairF + ((size_t)(pb * 4 + ks)) * 512 + lane * 8);
      }
      #pragma unroll
      for (int ni = 0; ni < 2; ++ni) {
        int cblk = wcq * 2 + ni;
        b[ni] = *(const s8v*)(WdF + ((size_t)(cblk * 8 + ks)) * 512 + lane * 8);
      }
      #pragma unroll
      for (int mi = 0; mi < 2; ++mi)
        #pragma unroll
        for (int ni = 0; ni < 2; ++ni)
          acc[mi][ni] = MFMA(a[mi], b[ni], acc[mi][ni]);
    }
    #pragma unroll
    for (int ks = 0; ks < 4; ++ks) {        // K 128..255 from obL
      s8v a[2], b[2];
      #pragma unroll
      for (int mi = 0; mi < 2; ++mi) {
        int pix = pix0 + mi * 16 + rlo;
        int k = ks * 32 + slot * 8;
        int byte = (pix * 256 + k * 2) ^ ((pix & 7) << 4);
        a[mi] = *(const s8v*)((const char*)obL + byte);
      }
      #pragma unroll
      for (int ni = 0; ni < 2; ++ni) {
        int cblk = wcq * 2 + ni;
        b[ni] = *(const s8v*)(WdF + ((size_t)(cblk * 8 + 4 + ks)) * 512 + lane * 8);
      }
      #pragma unroll
      for (int mi = 0; mi < 2; ++mi)
        #pragma unroll
        for (int ni = 0; ni < 2; ++ni)
          acc[mi][ni] = MFMA(a[mi], b[ni], acc[mi][ni]);
    }
    #pragma unroll
    for (int mi = 0; mi < 2; ++mi)
      #pragma unroll
      for (int ni = 0; ni < 2; ++ni) {
        int c = c0 + ni * 16 + rlo;
        float bias = bd[c];
        #pragma unroll
        for (int r = 0; r < 4; ++r) {
          int pix = pix0 + mi * 16 + slot * 4 + r;
          int byte = (pix * 256 + c * 2) ^ ((pix & 7) << 4);
          *(u16*)((char*)opL + byte) = f2bf(acc[mi][ni][r] + bias);
        }
      }
  }
  __syncthreads();

  // write pN coalesced
  #pragma unroll
  for (int q = 0; q < 2; ++q) {
    int u = q * 512 + t;
    int pix = u >> 4, off = u & 15;
    int byte = (pix * 256 + off * 16) ^ ((pix & 7) << 4);
    uint4 v = *(const uint4*)((const char*)opL + byte);
    int pixG = (l0 + (pix >> 5)) * 256 + m0 + (pix & 31);
    *(uint4*)(pN + (size_t)pixG * 128 + off * 8) = v;
  }
}

// ---------------------------------------------------------------------------
// K5: conv3x3 implicit-GEMM MFMA. NHWC bf16 in -> NHWC bf16 out + IN partials.
// grid (4, 128).
// ---------------------------------------------------------------------------
__global__ __launch_bounds__(256, 2) void k_conv(const u16* __restrict__ inN,
                                                 const u16* __restrict__ wP,
                                                 u16* __restrict__ outB,
                                                 float* __restrict__ gS,
                                                 float* __restrict__ gQ)
{
  __shared__ alignas(16) u16 Ast[4 * 66 * 128];   // 67584 B (reused as f32 out)
  __shared__ float partS[4][64], partQ[4][64];
  int t = threadIdx.x, lane = t & 63, w = t >> 6;
  int rlo = lane & 15, slot = lane >> 4;
  int x0 = blockIdx.x * 64, y0 = blockIdx.y * 2;
  for (int u = t; u < 4224; u += 256) {
    int r = u / 1056;
    int rem = u - r * 1056;
    int p = rem >> 4, ku = rem & 15;
    int gy = y0 + r - 1, gx = x0 - 1 + p;
    s8v v = zero8();
    if ((unsigned)gy < 256u && (unsigned)gx < 256u)
      v = *(const s8v*)(inN + ((size_t)gy * LL + gx) * 128 + ku * 8);
    int lb = (u * 16) ^ ((p & 7) << 4);
    *(s8v*)((char*)Ast + lb) = v;
  }
  __syncthreads();
  int wpy = w >> 1, co0 = (w & 1) * 64;
  f4v acc[4][4] = {};
  #pragma unroll
  for (int tap = 0; tap < 9; ++tap) {
    const int dy = tap / 3, dx = tap % 3;
    #pragma unroll
    for (int kk = 0; kk < 4; ++kk) {
      s8v a[4], b[4];
      #pragma unroll
      for (int mi = 0; mi < 4; ++mi) {
        int p = mi * 16 + rlo + dx;
        int lb = (((wpy + dy) * 66 + p) * 256 + kk * 64 + slot * 16) ^ ((p & 7) << 4);
        a[mi] = *(const s8v*)((const char*)Ast + lb);
      }
      #pragma unroll
      for (int ni = 0; ni < 4; ++ni) {
        int co = co0 + ni * 16 + rlo;
        b[ni] = *(const s8v*)(wP + ((size_t)((tap * 4 + kk) * 128 + co) * 4 + slot) * 8);
      }
      #pragma unroll
      for (int mi = 0; mi < 4; ++mi)
        #pragma unroll
        for (int ni = 0; ni < 4; ++ni)
          acc[mi][ni] = MFMA(a[mi], b[ni], acc[mi][ni]);
    }
  }
  // IN partial stats from registers
  #pragma unroll
  for (int ni = 0; ni < 4; ++ni) {
    float s = 0.f, q = 0.f;
    #pragma unroll
    for (int mi = 0; mi < 4; ++mi)
      #pragma unroll
      for (int r = 0; r < 4; ++r) {
        float v = acc[mi][ni][r];
        s += v; q += v * v;
      }
    s += __shfl_xor(s, 16); s += __shfl_xor(s, 32);
    q += __shfl_xor(q, 16); q += __shfl_xor(q, 32);
    if (slot == 0) { partS[w][ni * 16 + rlo] = s; partQ[w][ni * 16 + rlo] = q; }
  }
  __syncthreads();           // all Ast reads done; safe to reuse
  float* AstF = (float*)Ast; // [wpy][64 px][128 co] f32, XOR (pix&7)<<4
  #pragma unroll
  for (int mi = 0; mi < 4; ++mi)
    #pragma unroll
    for (int ni = 0; ni < 4; ++ni) {
      int co = co0 + ni * 16 + rlo;
      #pragma unroll
      for (int r = 0; r < 4; ++r) {
        int pix = mi * 16 + slot * 4 + r;
        int byte = wpy * 32768 + ((pix * 512 + co * 4) ^ ((pix & 7) << 4));
        *(float*)((char*)AstF + byte) = acc[mi][ni][r];
      }
    }
  if (t < 128) {
    int half = t >> 6, cl = t & 63;
    int bid = blockIdx.y * 4 + blockIdx.x;
    gS[bid * 128 + t] = partS[half][cl] + partS[2 + half][cl];
    gQ[bid * 128 + t] = partQ[half][cl] + partQ[2 + half][cl];
  }
  __syncthreads();
  #pragma unroll
  for (int it = 0; it < 8; ++it) {
    int u = it * 256 + t;                   // 2048 units of 8 channels
    int wpy2 = u >> 10, rem = u & 1023;
    int pix = rem >> 4, cv8 = rem & 15;
    int base = wpy2 * 32768;
    int b0 = base + ((pix * 512 + cv8 * 32) ^ ((pix & 7) << 4));
    int b1 = base + ((pix * 512 + cv8 * 32 + 16) ^ ((pix & 7) << 4));
    float4 a = *(const float4*)((const char*)AstF + b0);
    float4 b = *(const float4*)((const char*)AstF + b1);
    uint4 o;
    o.x = cvtpk2(a.x, a.y); o.y = cvtpk2(a.z, a.w);
    o.z = cvtpk2(b.x, b.y); o.w = cvtpk2(b.z, b.w);
    *(uint4*)(outB + ((size_t)(y0 + wpy2) * LL + x0 + pix) * 128 + cv8 * 8) = o;
  }
}

// ---------------------------------------------------------------------------
// K6: reduce 512 partials -> folded stats (sc = rstd*g, b2 = b - m*sc).
// grid 1, block 512.
// ---------------------------------------------------------------------------
__global__ __launch_bounds__(512) void k_instat2(const float* __restrict__ gS,
                                                 const float* __restrict__ gQ,
                                                 const float* __restrict__ g,
                                                 const float* __restrict__ b,
                                                 float* __restrict__ st)
{
  __shared__ float redS[512], redQ[512];
  int t = threadIdx.x, c = t & 127, q = t >> 7;
  float s = 0.f, s2 = 0.f;
  for (int i = q * 128; i < q * 128 + 128; ++i) {
    s  += gS[i * 128 + c];
    s2 += gQ[i * 128 + c];
  }
  redS[t] = s; redQ[t] = s2;
  __syncthreads();
  if (t < 128) {
    s  = redS[t] + redS[t + 128] + redS[t + 256] + redS[t + 384];
    s2 = redQ[t] + redQ[t + 128] + redQ[t + 256] + redQ[t + 384];
    float m = s * (1.f / HW);
    float var = s2 * (1.f / HW) - m * m;
    float rstd = rsqrtf(var + 1e-6f);
    float sc = rstd * g[t];
    st[t] = sc;
    st[128 + t] = b[t] - m * sc;
  }
}

// ---------------------------------------------------------------------------
// K7: h1N = bf16 of elu(IN(h1raw)); 8-ch units. grid 4096.
// ---------------------------------------------------------------------------
__global__ __launch_bounds__(256) void k_in_elu(const u16* __restrict__ h,
                                                const float* __restrict__ st,
                                                u16* __restrict__ hN)
{
  int i = blockIdx.x * 256 + threadIdx.x;   // 1,048,576 uint4 units
  int c8 = i & 15;
  uint4 hv = ((const uint4*)h)[i];
  float4 s0 = ((const float4*)st)[c8 * 2], s1 = ((const float4*)st)[c8 * 2 + 1];
  float4 q0 = ((const float4*)(st + 128))[c8 * 2], q1 = ((const float4*)(st + 128))[c8 * 2 + 1];
  float v0 = elu1(bf2f((u16)(hv.x & 0xffff)) * s0.x + q0.x);
  float v1 = elu1(bf2f((u16)(hv.x >> 16))    * s0.y + q0.y);
  float v2 = elu1(bf2f((u16)(hv.y & 0xffff)) * s0.z + q0.z);
  float v3 = elu1(bf2f((u16)(hv.y >> 16))    * s0.w + q0.w);
  float v4 = elu1(bf2f((u16)(hv.z & 0xffff)) * s1.x + q1.x);
  float v5 = elu1(bf2f((u16)(hv.z >> 16))    * s1.y + q1.y);
  float v6 = elu1(bf2f((u16)(hv.w & 0xffff)) * s1.z + q1.z);
  float v7 = elu1(bf2f((u16)(hv.w >> 16))    * s1.w + q1.w);
  uint4 o;
  o.x = cvtpk2(v0, v1); o.y = cvtpk2(v2, v3);
  o.z = cvtpk2(v4, v5); o.w = cvtpk2(v6, v7);
  ((uint4*)hN)[i] = o;
}

// ---------------------------------------------------------------------------
// K8: out = elu(pN + IN2(h2raw)); 8-ch units. grid 4096.
// ---------------------------------------------------------------------------
__global__ __launch_bounds__(256) void k_final(const u16* __restrict__ pN,
                                               const u16* __restrict__ h2,
                                               const float* __restrict__ st,
                                               float* __restrict__ out)
{
  int i = blockIdx.x * 256 + threadIdx.x;   // 1,048,576 uint4 units
  int c8 = i & 15;
  uint4 hv = ((const uint4*)h2)[i];
  uint4 pv = ((const uint4*)pN)[i];
  float4 s0 = ((const float4*)st)[c8 * 2], s1 = ((const float4*)st)[c8 * 2 + 1];
  float4 q0 = ((const float4*)(st + 128))[c8 * 2], q1 = ((const float4*)(st + 128))[c8 * 2 + 1];
  float4 f0, f1;
  f0.x = bf2f((u16)(hv.x & 0xffff)) * s0.x + q0.x + bf2f((u16)(pv.x & 0xffff));
  f0.y = bf2f((u16)(hv.x >> 16))    * s0.y + q0.y + bf2f((u16)(pv.x >> 16));
  f0.z = bf2f((u16)(hv.y & 0xffff)) * s0.z + q0.z + bf2f((u16)(pv.y & 0xffff));
  f0.w = bf2f((u16)(hv.y >> 16))    * s0.w + q0.w + bf2f((u16)(pv.y >> 16));
  f1.x = bf2f((u16)(hv.z & 0xffff)) * s1.x + q1.x + bf2f((u16)(pv.z & 0xffff));
  f1.y = bf2f((u16)(hv.z >> 16))    * s1.y + q1.y + bf2f((u16)(pv.z >> 16));
  f1.z = bf2f((u16)(hv.w & 0xffff)) * s1.z + q1.z + bf2f((u16)(pv.w & 0xffff));
  f1.w = bf2f((u16)(hv.w >> 16))    * s1.w + q1.w + bf2f((u16)(pv.w >> 16));
  f0.x = elu1(f0.x); f0.y = elu1(f0.y); f0.z = elu1(f0.z); f0.w = elu1(f0.w);
  f1.x = elu1(f1.x); f1.y = elu1(f1.y); f1.z = elu1(f1.z); f1.w = elu1(f1.w);
  ((float4*)out)[(size_t)i * 2]     = f0;
  ((float4*)out)[(size_t)i * 2 + 1] = f1;
}

// ---------------------------------------------------------------------------
extern "C" void kernel_launch(void* const* d_in, const int* in_sizes, int n_in,
                              void* d_out, int out_size, void* d_ws, size_t ws_size,
                              hipStream_t stream)
{
  const float* msa   = (const float*)d_in[0];
  const float* pair  = (const float*)d_in[1];
  const float* ln_g  = (const float*)d_in[2];
  const float* ln_b  = (const float*)d_in[3];
  const float* Wl    = (const float*)d_in[4];
  const float* bl    = (const float*)d_in[5];
  const float* Wr    = (const float*)d_in[6];
  const float* br    = (const float*)d_in[7];
  const float* Wo    = (const float*)d_in[8];
  const float* bo    = (const float*)d_in[9];
  const float* Wd    = (const float*)d_in[10];
  const float* bd    = (const float*)d_in[11];
  const float* conv1 = (const float*)d_in[12];
  const float* in1_g = (const float*)d_in[13];
  const float* in1_b = (const float*)d_in[14];
  const float* conv2 = (const float*)d_in[15];
  const float* in2_g = (const float*)d_in[16];
  const float* in2_b = (const float*)d_in[17];
  float* out = (float*)d_out;

  // Workspace (F = 1Mi floats = 4 MB), peak ~89 MB:
  //  [0,4F)    msaF (dead after gemm_lr) -> h1N (bf16)
  //  [4F,5F)   leftT+rightT (dead after fragpack)
  //  [5F,5.5F) leftF ; [5.5F,6F) rightF
  //  [6F,10F)  pN (NHWC bf16, live to end)
  //  [10F,14F) h1raw (NHWC bf16)
  //  [14F,18F) h2raw (NHWC bf16)
  //  [18F,22F) pairF (dead after k_fused)
  //  [22F,..)  gS/gQ + stats + fragment weights
  float* ws = (float*)d_ws;
  const size_t F = 1048576;
  u16* msaF   = (u16*)ws;
  u16* h1N    = (u16*)ws;
  u16* leftT  = (u16*)(ws + 4 * F);
  u16* rightT = (u16*)(ws + 4 * F + F / 2);
  u16* leftF  = (u16*)(ws + 5 * F);
  u16* rightF = (u16*)(ws + 5 * F + F / 2);
  u16* pN     = (u16*)(ws + 6 * F);
  u16* h1raw  = (u16*)(ws + 10 * F);
  u16* h2raw  = (u16*)(ws + 14 * F);
  u16* pairF  = (u16*)(ws + 18 * F);
  float* gS   = ws + 22 * F;                 // 65536
  float* gQ   = ws + 22 * F + 65536;         // 65536
  float* stats = ws + 22 * F + 131072;       // 512
  u16* aux    = (u16*)(ws + 22 * F + 131584);
  u16* wP1    = aux;                         // 147456
  u16* wP2    = aux + 147456;                // 147456
  u16* WoF    = aux + 294912;                // 131072
  u16* WdF    = aux + 425984;                // 32768
  u16* WlrF   = aux + 458752;                // 16384

  k_prep_ln<<<dim3(6376), dim3(256), 0, stream>>>(Wl, Wr, Wo, Wd, conv1, conv2,
                                                  pair, msa, ln_g, ln_b,
                                                  WlrF, WoF, WdF, wP1, wP2, pairF, msaF);
  k_gemm_lr<<<dim3(128), dim3(256), 0, stream>>>(msaF, WlrF, bl, br, leftT, rightT);
  k_fragpack<<<dim3(256), dim3(256), 0, stream>>>(leftT, rightT, leftF, rightF);

  k_fused<<<dim3(1024), dim3(512), 0, stream>>>(leftF, rightF, WoF, pairF, WdF,
                                                bo, bd, pN);

  k_conv<<<dim3(4, 128), dim3(256), 0, stream>>>(pN, wP1, h1raw, gS, gQ);
  k_instat2<<<dim3(1), dim3(512), 0, stream>>>(gS, gQ, in1_g, in1_b, stats);
  k_in_elu<<<dim3(4096), dim3(256), 0, stream>>>(h1raw, stats, h1N);

  k_conv<<<dim3(4, 128), dim3(256), 0, stream>>>(h1N, wP2, h2raw, gS, gQ);
  k_instat2<<<dim3(1), dim3(512), 0, stream>>>(gS, gQ, in2_g, in2_b, stats + 256);

  k_final<<<dim3(4096), dim3(256), 0, stream>>>(pN, h2raw, stats + 256, out);
}

// Round 10
// 234.493 us; speedup vs baseline: 8.8803x; 1.0020x over previous
//
#include <hip/hip_runtime.h>
#include <math.h>

#define LL 256      // L
#define NS 128      // N sequences
#define DM 256      // d_msa
#define DH 32       // d_h
#define DP 128      // d_pair
#define HW 65536    // L*L

using u16 = unsigned short;
typedef __attribute__((ext_vector_type(8))) short s8v;   // 8 bf16 (A/B frag)
typedef __attribute__((ext_vector_type(4))) short s4v;   // 4 bf16
typedef __attribute__((ext_vector_type(4))) float f4v;   // C/D frag

#define MFMA(a, b, c) __builtin_amdgcn_mfma_f32_16x16x32_bf16((a), (b), (c), 0, 0, 0)

__device__ __forceinline__ u16 f2bf(float f) {
  unsigned u = __float_as_uint(f);
  u = (u + 0x7FFFu + ((u >> 16) & 1u)) >> 16;   // RNE
  return (u16)u;
}
__device__ __forceinline__ unsigned cvtpk2(float lo, float hi) {
  unsigned r;
  asm("v_cvt_pk_bf16_f32 %0, %1, %2" : "=v"(r) : "v"(lo), "v"(hi));
  return r;
}
__device__ __forceinline__ float bf2f(u16 h) { return __uint_as_float(((unsigned)h) << 16); }
__device__ __forceinline__ float elu1(float v) { return v > 0.f ? v : expm1f(v); }
__device__ __forceinline__ s8v zero8() {
  s8v v;
  #pragma unroll
  for (int j = 0; j < 8; ++j) v[j] = 0;
  return v;
}

// Fragment-tile layout: 1 KB tile = 16 rows x 32 k (bf16).
// unit(16B) = ((k>>3)&3)*16 + (row&15) ; elem = k&7.
// Wave fragment load = tile_base + lane*16 (fully coalesced).

// ---------------------------------------------------------------------------
// P: weight preps (fragment-tiled) + pairF + LayerNorm->msaF, one launch.
//  [0,64) WoF ; [64,80) WdF ; [80,88) WlrF ; [88,160) wP1 ; [160,232) wP2 ;
//  [232,4328) pairF ; [4328,6376) LN blocks.
// ---------------------------------------------------------------------------
__device__ __forceinline__ void prep_convw(const float* __restrict__ w,
                                           u16* __restrict__ wP, int idx)
{
  int h = idx & 3, co = (idx >> 2) & 127, kk = (idx >> 9) & 3, tap = idx >> 11;
  s8v o;
  #pragma unroll
  for (int j = 0; j < 8; ++j) {
    int ci = kk * 32 + h * 8 + j;
    o[j] = (short)f2bf(w[((size_t)co * DP + ci) * 9 + tap]);
  }
  *(s8v*)(wP + (size_t)idx * 8) = o;
}

__global__ __launch_bounds__(256) void k_prep_ln(
    const float* __restrict__ Wl, const float* __restrict__ Wr,
    const float* __restrict__ Wo, const float* __restrict__ Wd,
    const float* __restrict__ conv1, const float* __restrict__ conv2,
    const float* __restrict__ pair,
    const float* __restrict__ msa, const float* __restrict__ ln_g,
    const float* __restrict__ ln_b,
    u16* __restrict__ WlrF, u16* __restrict__ WoF, u16* __restrict__ WdF,
    u16* __restrict__ wP1, u16* __restrict__ wP2, u16* __restrict__ pairF,
    u16* __restrict__ msaF)
{
  __shared__ alignas(16) u16 buf[16 * 264];
  int bx = blockIdx.x, t = threadIdx.x;
  if (bx < 64) {
    // WoF: 128 c-rows x 1024 kp (kp=j*32+i). tile=(c>>4)*32 + j. 16384 units.
    int o = bx * 256 + t;
    int tile = o >> 6, u = o & 63;
    int cblk = tile >> 5, j = tile & 31;
    int kslot = u >> 4, cl = u & 15;
    int c = cblk * 16 + cl;
    s8v v;
    #pragma unroll
    for (int e = 0; e < 8; ++e) {
      int i = kslot * 8 + e;
      v[e] = (short)f2bf(Wo[(size_t)(i * 32 + j) * DP + c]);
    }
    *(s8v*)(WoF + (size_t)o * 8) = v;
  } else if (bx < 80) {
    int o = (bx - 64) * 256 + t;                // 4096 units
    int tile = o >> 6, u = o & 63;
    int cblk = tile >> 3, kch = tile & 7;
    int kslot = u >> 4, cl = u & 15;
    int c = cblk * 16 + cl;
    s8v v;
    #pragma unroll
    for (int e = 0; e < 8; ++e) {
      int k = kch * 32 + kslot * 8 + e;
      v[e] = (short)f2bf(Wd[(size_t)k * DP + c]);
    }
    *(s8v*)(WdF + (size_t)o * 8) = v;
  } else if (bx < 88) {
    int o = (bx - 80) * 256 + t;                // 2048 units
    int tile = o >> 6, u = o & 63;
    int nblk = tile >> 3, kch = tile & 7;
    int kslot = u >> 4, cl = u & 15;
    int n = nblk * 16 + cl;
    s8v v;
    #pragma unroll
    for (int e = 0; e < 8; ++e) {
      int k = kch * 32 + kslot * 8 + e;
      float x = (n < 32) ? Wl[k * DH + n] : Wr[k * DH + (n - 32)];
      v[e] = (short)f2bf(x);
    }
    *(s8v*)(WlrF + (size_t)o * 8) = v;
  } else if (bx < 160) {
    prep_convw(conv1, wP1, (bx - 88) * 256 + t);
  } else if (bx < 232) {
    prep_convw(conv2, wP2, (bx - 160) * 256 + t);
  } else if (bx < 4328) {
    // pairF: one 16-pix block per block.
    int pb = bx - 232;                          // 0..4095
    #pragma unroll
    for (int it = 0; it < 2; ++it) {
      int idx = it * 256 + t;
      int pix = idx >> 5, f4i = idx & 31;
      float4 v = ((const float4*)pair)[(size_t)(pb * 16 + pix) * 32 + f4i];
      s4v o;
      o[0] = (short)f2bf(v.x); o[1] = (short)f2bf(v.y);
      o[2] = (short)f2bf(v.z); o[3] = (short)f2bf(v.w);
      *(s4v*)(buf + pix * 136 + f4i * 4) = o;
    }
    __syncthreads();
    int kch = t >> 6, u = t & 63;
    int kslot = u >> 4, cl = u & 15;
    int k0 = kch * 32 + kslot * 8;
    s8v v = *(const s8v*)(buf + cl * 136 + k0);
    *(s8v*)(pairF + ((size_t)pb * 256 + t) * 8) = v;
  } else {
    // LayerNorm -> msaF fragment-tiled. 2048 blocks x 16 rows.
    int bid = bx - 4328;
    int lane = t & 63, wid = t >> 6;
    int row0 = bid * 16;
    const float4 gv = ((const float4*)ln_g)[lane];
    const float4 bv = ((const float4*)ln_b)[lane];
    #pragma unroll
    for (int rr = 0; rr < 4; ++rr) {
      int row = row0 + wid * 4 + rr;
      float4 v = ((const float4*)(msa + (size_t)row * DM))[lane];
      float s = v.x + v.y + v.z + v.w;
      float q = v.x * v.x + v.y * v.y + v.z * v.z + v.w * v.w;
      #pragma unroll
      for (int off = 32; off; off >>= 1) { s += __shfl_down(s, off); q += __shfl_down(q, off); }
      s = __shfl(s, 0); q = __shfl(q, 0);
      float mean = s * (1.f / DM);
      float var  = q * (1.f / DM) - mean * mean;
      float rstd = rsqrtf(var + 1e-5f);
      s4v o;
      o[0] = (short)f2bf((v.x - mean) * rstd * gv.x + bv.x);
      o[1] = (short)f2bf((v.y - mean) * rstd * gv.y + bv.y);
      o[2] = (short)f2bf((v.z - mean) * rstd * gv.z + bv.z);
      o[3] = (short)f2bf((v.w - mean) * rstd * gv.w + bv.w);
      *(s4v*)(buf + (wid * 4 + rr) * 264 + lane * 4) = o;
    }
    __syncthreads();
    #pragma unroll
    for (int it = 0; it < 2; ++it) {
      int o = it * 256 + t;                   // 512 units
      int kch = o >> 6, kslot = (o >> 4) & 3, rr = o & 15;
      int k0 = kch * 32 + kslot * 8;
      s8v v = *(const s8v*)(buf + rr * 264 + k0);
      *(s8v*)(msaF + (size_t)bid * 4096 + (size_t)o * 8) = v;
    }
  }
}

// ---------------------------------------------------------------------------
// K2: msaF @ WlrF -> leftT/rightT bf16 (row-major; fragpack fixes layout).
// ---------------------------------------------------------------------------
__global__ __launch_bounds__(256) void k_gemm_lr(const u16* __restrict__ msaF,
                                                 const u16* __restrict__ WlrF,
                                                 const float* __restrict__ bl,
                                                 const float* __restrict__ br,
                                                 u16* __restrict__ leftT,
                                                 u16* __restrict__ rightT)
{
  int lane = threadIdx.x & 63, wid = threadIdx.x >> 6;
  int sIdx = blockIdx.x;
  f4v acc[4][4] = {};
  #pragma unroll
  for (int ks = 0; ks < 8; ++ks) {
    s8v a[4], bb[4];
    #pragma unroll
    for (int mi = 0; mi < 4; ++mi)
      a[mi] = *(const s8v*)(msaF + ((size_t)(sIdx * 16 + wid * 4 + mi) * 8 + ks) * 512 + lane * 8);
    #pragma unroll
    for (int ni = 0; ni < 4; ++ni)
      bb[ni] = *(const s8v*)(WlrF + ((size_t)(ni * 8 + ks)) * 512 + lane * 8);
    #pragma unroll
    for (int mi = 0; mi < 4; ++mi)
      #pragma unroll
      for (int ni = 0; ni < 4; ++ni)
        acc[mi][ni] = MFMA(a[mi], bb[ni], acc[mi][ni]);
  }
  #pragma unroll
  for (int mi = 0; mi < 4; ++mi) {
    #pragma unroll
    for (int ni = 0; ni < 4; ++ni) {
      int n = ni * 16 + (lane & 15);
      #pragma unroll
      for (int r = 0; r < 4; ++r) {
        int l = wid * 64 + mi * 16 + (lane >> 4) * 4 + r;
        float v = acc[mi][ni][r];
        if (n < 32) {
          leftT[((size_t)l * 32 + n) * 128 + sIdx] = f2bf(v + bl[n]);
        } else {
          rightT[((size_t)l * 32 + (n - 32)) * 128 + sIdx] =
              f2bf((v + br[n - 32]) * (1.f / NS));
        }
      }
    }
  }
}

// ---------------------------------------------------------------------------
// K3: fragpack -> leftF / rightF fragment tiles. grid 256.
// ---------------------------------------------------------------------------
__global__ __launch_bounds__(256) void k_fragpack(const u16* __restrict__ leftT,
                                                  const u16* __restrict__ rightT,
                                                  u16* __restrict__ leftF,
                                                  u16* __restrict__ rightF)
{
  __shared__ alignas(16) u16 lds[64 * 136];
  int t = threadIdx.x, bx = blockIdx.x;
  bool isR = bx >= 128;
  int blk = isR ? (bx - 128) : bx;
  #pragma unroll
  for (int it = 0; it < 4; ++it) {
    int u = it * 256 + t;
    int row = u >> 4, sc = u & 15;
    const u16* src;
    if (!isR) {
      src = leftT + ((size_t)(blk * 64 + row)) * 128 + sc * 8;
    } else {
      int gcol = blk * 64 + row;
      int mg = gcol >> 10, rem = gcol & 1023;
      int jc = rem >> 8, nc = rem & 255;
      int m = mg * 32 + (nc >> 3), j = jc * 8 + (nc & 7);
      src = rightT + ((size_t)(m * 32 + j)) * 128 + sc * 8;
    }
    *(s8v*)(lds + row * 136 + sc * 8) = *(const s8v*)src;
  }
  __syncthreads();
  u16* dst = (isR ? rightF : leftF) + (size_t)blk * 8192;
  #pragma unroll
  for (int it = 0; it < 4; ++it) {
    int o = it * 256 + t;
    int tloc = o >> 6, u = o & 63;
    int rb = tloc >> 2, sc2 = tloc & 3;
    int kslot = u >> 4, rr = u & 15;
    int row = rb * 16 + rr, s0 = sc2 * 32 + kslot * 8;
    *(s8v*)(dst + (size_t)o * 8) = *(const s8v*)(lds + row * 136 + s0);
  }
}

// ---------------------------------------------------------------------------
// K4: fused outer-product + Wo-proj + proj_down (unchanged from R9).
// ---------------------------------------------------------------------------
__global__ __launch_bounds__(512, 4) void k_fused(
    const u16* __restrict__ leftF, const u16* __restrict__ rightF,
    const u16* __restrict__ WoF, const u16* __restrict__ pairF,
    const u16* __restrict__ WdF, const float* __restrict__ bo,
    const float* __restrict__ bd, u16* __restrict__ pN)
{
  __shared__ alignas(16) u16 Als[8192];    // 16 KB
  __shared__ alignas(16) u16 opL[16384];   // 32 KB
  __shared__ alignas(16) u16 obL[8192];    // 16 KB
  int t = threadIdx.x, lane = t & 63, w = t >> 6;
  int rlo = lane & 15, slot = lane >> 4;
  int mg = blockIdx.x >> 7, lp = blockIdx.x & 127;
  int l0 = lp * 2, m0 = mg * 32;

  #pragma unroll
  for (int i = 0; i < 2; ++i) {
    int u = t + 512 * i;
    *(s8v*)(Als + (size_t)u * 8) = *(const s8v*)(leftF + (size_t)lp * 8192 + (size_t)u * 8);
  }

  f4v acc2[4] = {};
  s8v bb[8];
  #pragma unroll
  for (int ks = 0; ks < 4; ++ks)
    #pragma unroll
    for (int ni = 0; ni < 2; ++ni)
      bb[ks * 2 + ni] = *(const s8v*)(rightF +
          ((size_t)((mg * 64 + 0 * 16 + w * 2 + ni) * 4 + ks)) * 512 + lane * 8);
  __syncthreads();

  #pragma unroll
  for (int jc = 0; jc < 4; ++jc) {
    // ---- phase 1: op chunk ----
    f4v acc1[4][2] = {};
    __builtin_amdgcn_s_setprio(1);
    #pragma unroll
    for (int ks = 0; ks < 4; ++ks) {
      s8v a[4];
      #pragma unroll
      for (int mi = 0; mi < 4; ++mi)
        a[mi] = *(const s8v*)(Als + (size_t)(mi * 4 + ks) * 512 + lane * 8);
      #pragma unroll
      for (int mi = 0; mi < 4; ++mi)
        #pragma unroll
        for (int ni = 0; ni < 2; ++ni)
          acc1[mi][ni] = MFMA(a[mi], bb[ks * 2 + ni], acc1[mi][ni]);
    }
    __builtin_amdgcn_s_setprio(0);
    #pragma unroll
    for (int mi = 0; mi < 4; ++mi) {
      int i0 = (mi & 1) * 16 + slot * 4;
      int lLoc = mi >> 1;
      int kslot = (i0 >> 3) & 3;
      #pragma unroll
      for (int ni = 0; ni < 2; ++ni) {
        int n = w * 32 + ni * 16 + rlo;
        int pix = lLoc * 32 + (n >> 3);
        int jj = n & 7;
        uint2 o2;
        o2.x = cvtpk2(acc1[mi][ni][0], acc1[mi][ni][1]);
        o2.y = cvtpk2(acc1[mi][ni][2], acc1[mi][ni][3]);
        int byte = ((pix >> 4) * 8 + jj) * 1024 +
                   (kslot * 16 + ((pix & 15) ^ jj)) * 16 + (i0 & 7) * 2;
        *(uint2*)((char*)opL + byte) = o2;
      }
    }
    // hoist phase-2 B loads before the barrier (drain => arrived after it)
    s8v wb[8];
    #pragma unroll
    for (int ks = 0; ks < 8; ++ks)
      wb[ks] = *(const s8v*)(WoF + ((size_t)(w * 32 + jc * 8 + ks)) * 512 + lane * 8);
    __syncthreads();
    // ---- phase 2: acc2 += op_chunk @ WoF_chunk ----
    __builtin_amdgcn_s_setprio(1);
    #pragma unroll
    for (int ks = 0; ks < 8; ++ks) {
      s8v a[4];
      #pragma unroll
      for (int mi = 0; mi < 4; ++mi) {
        int byte = (mi * 8 + ks) * 1024 + (slot * 16 + (rlo ^ ks)) * 16;
        a[mi] = *(const s8v*)((const char*)opL + byte);
      }
      #pragma unroll
      for (int mi = 0; mi < 4; ++mi)
        acc2[mi] = MFMA(a[mi], wb[ks], acc2[mi]);
    }
    __builtin_amdgcn_s_setprio(0);
    // prefetch next-jc B fragments before the barrier
    if (jc < 3) {
      #pragma unroll
      for (int ks = 0; ks < 4; ++ks)
        #pragma unroll
        for (int ni = 0; ni < 2; ++ni)
          bb[ks * 2 + ni] = *(const s8v*)(rightF +
              ((size_t)((mg * 64 + (jc + 1) * 16 + w * 2 + ni) * 4 + ks)) * 512 + lane * 8);
    }
    __syncthreads();
  }

  // ob -> obL (+bo)
  {
    int c = w * 16 + rlo;
    float bias = bo[c];
    #pragma unroll
    for (int mi = 0; mi < 4; ++mi)
      #pragma unroll
      for (int r = 0; r < 4; ++r) {
        int pix = mi * 16 + slot * 4 + r;
        int byte = (pix * 256 + c * 2) ^ ((pix & 7) << 4);
        *(u16*)((char*)obL + byte) = f2bf(acc2[mi][r] + bias);
      }
  }
  __syncthreads();

  // ---- phase 3: p = [pairF | ob] @ WdF + bd ----
  int wr = w >> 2, wcq = w & 3;
  int pix0 = wr * 32, c0 = wcq * 32;
  {
    f4v acc[2][2] = {};
    #pragma unroll
    for (int ks = 0; ks < 4; ++ks) {        // K 0..127 from pairF
      s8v a[2], b[2];
      #pragma unroll
      for (int mi = 0; mi < 2; ++mi) {
        int pb = (l0 + wr) * 16 + (m0 >> 4) + mi;
        a[mi] = *(const s8v*)(pairF + ((size_t)(pb * 4 + ks)) * 512 + lane * 8);
      }
      #pragma unroll
      for (int ni = 0; ni < 2; ++ni) {
        int cblk = wcq * 2 + ni;
        b[ni] = *(const s8v*)(WdF + ((size_t)(cblk * 8 + ks)) * 512 + lane * 8);
      }
      #pragma unroll
      for (int mi = 0; mi < 2; ++mi)
        #pragma unroll
        for (int ni = 0; ni < 2; ++ni)
          acc[mi][ni] = MFMA(a[mi], b[ni], acc[mi][ni]);
    }
    #pragma unroll
    for (int ks = 0; ks < 4; ++ks) {        // K 128..255 from obL
      s8v a[2], b[2];
      #pragma unroll
      for (int mi = 0; mi < 2; ++mi) {
        int pix = pix0 + mi * 16 + rlo;
        int k = ks * 32 + slot * 8;
        int byte = (pix * 256 + k * 2) ^ ((pix & 7) << 4);
        a[mi] = *(const s8v*)((const char*)obL + byte);
      }
      #pragma unroll
      for (int ni = 0; ni < 2; ++ni) {
        int cblk = wcq * 2 + ni;
        b[ni] = *(const s8v*)(WdF + ((size_t)(cblk * 8 + 4 + ks)) * 512 + lane * 8);
      }
      #pragma unroll
      for (int mi = 0; mi < 2; ++mi)
        #pragma unroll
        for (int ni = 0; ni < 2; ++ni)
          acc[mi][ni] = MFMA(a[mi], b[ni], acc[mi][ni]);
    }
    #pragma unroll
    for (int mi = 0; mi < 2; ++mi)
      #pragma unroll
      for (int ni = 0; ni < 2; ++ni) {
        int c = c0 + ni * 16 + rlo;
        float bias = bd[c];
        #pragma unroll
        for (int r = 0; r < 4; ++r) {
          int pix = pix0 + mi * 16 + slot * 4 + r;
          int byte = (pix * 256 + c * 2) ^ ((pix & 7) << 4);
          *(u16*)((char*)opL + byte) = f2bf(acc[mi][ni][r] + bias);
        }
      }
  }
  __syncthreads();

  // write pN coalesced
  #pragma unroll
  for (int q = 0; q < 2; ++q) {
    int u = q * 512 + t;
    int pix = u >> 4, off = u & 15;
    int byte = (pix * 256 + off * 16) ^ ((pix & 7) << 4);
    uint4 v = *(const uint4*)((const char*)opL + byte);
    int pixG = (l0 + (pix >> 5)) * 256 + m0 + (pix & 31);
    *(uint4*)(pN + (size_t)pixG * 128 + off * 8) = v;
  }
}

// ---------------------------------------------------------------------------
// K5: conv3x3 implicit-GEMM MFMA, SOFTWARE-PIPELINED main loop (2-deep,
// named double buffers, setprio around MFMA clusters). NHWC bf16 in ->
// NHWC bf16 out + IN partials. grid (4, 128).
// ---------------------------------------------------------------------------
#define CONV_LOADA(it, dst) {                                                  \
    const int tap_ = (it) >> 2, kk_ = (it) & 3;                                \
    const int dy_ = tap_ / 3, dx_ = tap_ % 3;                                  \
    _Pragma("unroll")                                                          \
    for (int mi = 0; mi < 4; ++mi) {                                           \
      int p_ = mi * 16 + rlo + dx_;                                            \
      int lb_ = (((wpy + dy_) * 66 + p_) * 256 + kk_ * 64 + slot * 16) ^       \
                ((p_ & 7) << 4);                                               \
      dst[mi] = *(const s8v*)((const char*)Ast + lb_);                         \
    } }
#define CONV_LOADB(it, dst) {                                                  \
    const int tap_ = (it) >> 2, kk_ = (it) & 3;                                \
    _Pragma("unroll")                                                          \
    for (int ni = 0; ni < 4; ++ni) {                                           \
      int co_ = co0 + ni * 16 + rlo;                                           \
      dst[ni] = *(const s8v*)(wP +                                             \
          ((size_t)((tap_ * 4 + kk_) * 128 + co_) * 4 + slot) * 8);            \
    } }
#define CONV_STEP(aa, bbv) {                                                   \
    __builtin_amdgcn_s_setprio(1);                                             \
    _Pragma("unroll")                                                          \
    for (int mi = 0; mi < 4; ++mi)                                             \
      _Pragma("unroll")                                                        \
      for (int ni = 0; ni < 4; ++ni)                                           \
        acc[mi][ni] = MFMA(aa[mi], bbv[ni], acc[mi][ni]);                      \
    __builtin_amdgcn_s_setprio(0); }

__global__ __launch_bounds__(256, 2) void k_conv(const u16* __restrict__ inN,
                                                 const u16* __restrict__ wP,
                                                 u16* __restrict__ outB,
                                                 float* __restrict__ gS,
                                                 float* __restrict__ gQ)
{
  __shared__ alignas(16) u16 Ast[4 * 66 * 128];   // 67584 B (reused as f32 out)
  __shared__ float partS[4][64], partQ[4][64];
  int t = threadIdx.x, lane = t & 63, w = t >> 6;
  int rlo = lane & 15, slot = lane >> 4;
  int x0 = blockIdx.x * 64, y0 = blockIdx.y * 2;
  for (int u = t; u < 4224; u += 256) {
    int r = u / 1056;
    int rem = u - r * 1056;
    int p = rem >> 4, ku = rem & 15;
    int gy = y0 + r - 1, gx = x0 - 1 + p;
    s8v v = zero8();
    if ((unsigned)gy < 256u && (unsigned)gx < 256u)
      v = *(const s8v*)(inN + ((size_t)gy * LL + gx) * 128 + ku * 8);
    int lb = (u * 16) ^ ((p & 7) << 4);
    *(s8v*)((char*)Ast + lb) = v;
  }
  __syncthreads();
  int wpy = w >> 1, co0 = (w & 1) * 64;
  f4v acc[4][4] = {};
  // 2-deep software pipeline over the 36 k-steps (9 taps x 4 kk).
  s8v a0[4], b0[4], a1[4], b1[4];
  CONV_LOADA(0, a0) CONV_LOADB(0, b0)
  #pragma unroll
  for (int it = 0; it < 36; it += 2) {
    CONV_LOADA(it + 1, a1) CONV_LOADB(it + 1, b1)
    CONV_STEP(a0, b0)
    if (it + 2 < 36) { CONV_LOADA(it + 2, a0) CONV_LOADB(it + 2, b0) }
    CONV_STEP(a1, b1)
  }
  // IN partial stats from registers
  #pragma unroll
  for (int ni = 0; ni < 4; ++ni) {
    float s = 0.f, q = 0.f;
    #pragma unroll
    for (int mi = 0; mi < 4; ++mi)
      #pragma unroll
      for (int r = 0; r < 4; ++r) {
        float v = acc[mi][ni][r];
        s += v; q += v * v;
      }
    s += __shfl_xor(s, 16); s += __shfl_xor(s, 32);
    q += __shfl_xor(q, 16); q += __shfl_xor(q, 32);
    if (slot == 0) { partS[w][ni * 16 + rlo] = s; partQ[w][ni * 16 + rlo] = q; }
  }
  __syncthreads();           // all Ast reads done; safe to reuse
  float* AstF = (float*)Ast; // [wpy][64 px][128 co] f32, XOR (pix&7)<<4
  #pragma unroll
  for (int mi = 0; mi < 4; ++mi)
    #pragma unroll
    for (int ni = 0; ni < 4; ++ni) {
      int co = co0 + ni * 16 + rlo;
      #pragma unroll
      for (int r = 0; r < 4; ++r) {
        int pix = mi * 16 + slot * 4 + r;
        int byte = wpy * 32768 + ((pix * 512 + co * 4) ^ ((pix & 7) << 4));
        *(float*)((char*)AstF + byte) = acc[mi][ni][r];
      }
    }
  if (t < 128) {
    int half = t >> 6, cl = t & 63;
    int bid = blockIdx.y * 4 + blockIdx.x;
    gS[bid * 128 + t] = partS[half][cl] + partS[2 + half][cl];
    gQ[bid * 128 + t] = partQ[half][cl] + partQ[2 + half][cl];
  }
  __syncthreads();
  #pragma unroll
  for (int it = 0; it < 8; ++it) {
    int u = it * 256 + t;                   // 2048 units of 8 channels
    int wpy2 = u >> 10, rem = u & 1023;
    int pix = rem >> 4, cv8 = rem & 15;
    int base = wpy2 * 32768;
    int b0b = base + ((pix * 512 + cv8 * 32) ^ ((pix & 7) << 4));
    int b1b = base + ((pix * 512 + cv8 * 32 + 16) ^ ((pix & 7) << 4));
    float4 a = *(const float4*)((const char*)AstF + b0b);
    float4 b = *(const float4*)((const char*)AstF + b1b);
    uint4 o;
    o.x = cvtpk2(a.x, a.y); o.y = cvtpk2(a.z, a.w);
    o.z = cvtpk2(b.x, b.y); o.w = cvtpk2(b.z, b.w);
    *(uint4*)(outB + ((size_t)(y0 + wpy2) * LL + x0 + pix) * 128 + cv8 * 8) = o;
  }
}

// ---------------------------------------------------------------------------
// K6: reduce 512 partials -> folded stats (sc = rstd*g, b2 = b - m*sc).
// grid 1, block 512.
// ---------------------------------------------------------------------------
__global__ __launch_bounds__(512) void k_instat2(const float* __restrict__ gS,
                                                 const float* __restrict__ gQ,
                                                 const float* __restrict__ g,
                                                 const float* __restrict__ b,
                                                 float* __restrict__ st)
{
  __shared__ float redS[512], redQ[512];
  int t = threadIdx.x, c = t & 127, q = t >> 7;
  float s = 0.f, s2 = 0.f;
  for (int i = q * 128; i < q * 128 + 128; ++i) {
    s  += gS[i * 128 + c];
    s2 += gQ[i * 128 + c];
  }
  redS[t] = s; redQ[t] = s2;
  __syncthreads();
  if (t < 128) {
    s  = redS[t] + redS[t + 128] + redS[t + 256] + redS[t + 384];
    s2 = redQ[t] + redQ[t + 128] + redQ[t + 256] + redQ[t + 384];
    float m = s * (1.f / HW);
    float var = s2 * (1.f / HW) - m * m;
    float rstd = rsqrtf(var + 1e-6f);
    float sc = rstd * g[t];
    st[t] = sc;
    st[128 + t] = b[t] - m * sc;
  }
}

// ---------------------------------------------------------------------------
// K7: h1N = bf16 of elu(IN(h1raw)); 8-ch units. grid 4096.
// ---------------------------------------------------------------------------
__global__ __launch_bounds__(256) void k_in_elu(const u16* __restrict__ h,
                                                const float* __restrict__ st,
                                                u16* __restrict__ hN)
{
  int i = blockIdx.x * 256 + threadIdx.x;   // 1,048,576 uint4 units
  int c8 = i & 15;
  uint4 hv = ((const uint4*)h)[i];
  float4 s0 = ((const float4*)st)[c8 * 2], s1 = ((const float4*)st)[c8 * 2 + 1];
  float4 q0 = ((const float4*)(st + 128))[c8 * 2], q1 = ((const float4*)(st + 128))[c8 * 2 + 1];
  float v0 = elu1(bf2f((u16)(hv.x & 0xffff)) * s0.x + q0.x);
  float v1 = elu1(bf2f((u16)(hv.x >> 16))    * s0.y + q0.y);
  float v2 = elu1(bf2f((u16)(hv.y & 0xffff)) * s0.z + q0.z);
  float v3 = elu1(bf2f((u16)(hv.y >> 16))    * s0.w + q0.w);
  float v4 = elu1(bf2f((u16)(hv.z & 0xffff)) * s1.x + q1.x);
  float v5 = elu1(bf2f((u16)(hv.z >> 16))    * s1.y + q1.y);
  float v6 = elu1(bf2f((u16)(hv.w & 0xffff)) * s1.z + q1.z);
  float v7 = elu1(bf2f((u16)(hv.w >> 16))    * s1.w + q1.w);
  uint4 o;
  o.x = cvtpk2(v0, v1); o.y = cvtpk2(v2, v3);
  o.z = cvtpk2(v4, v5); o.w = cvtpk2(v6, v7);
  ((uint4*)hN)[i] = o;
}

// ---------------------------------------------------------------------------
// K8: out = elu(pN + IN2(h2raw)); 8-ch units. grid 4096.
// ---------------------------------------------------------------------------
__global__ __launch_bounds__(256) void k_final(const u16* __restrict__ pN,
                                               const u16* __restrict__ h2,
                                               const float* __restrict__ st,
                                               float* __restrict__ out)
{
  int i = blockIdx.x * 256 + threadIdx.x;   // 1,048,576 uint4 units
  int c8 = i & 15;
  uint4 hv = ((const uint4*)h2)[i];
  uint4 pv = ((const uint4*)pN)[i];
  float4 s0 = ((const float4*)st)[c8 * 2], s1 = ((const float4*)st)[c8 * 2 + 1];
  float4 q0 = ((const float4*)(st + 128))[c8 * 2], q1 = ((const float4*)(st + 128))[c8 * 2 + 1];
  float4 f0, f1;
  f0.x = bf2f((u16)(hv.x & 0xffff)) * s0.x + q0.x + bf2f((u16)(pv.x & 0xffff));
  f0.y = bf2f((u16)(hv.x >> 16))    * s0.y + q0.y + bf2f((u16)(pv.x >> 16));
  f0.z = bf2f((u16)(hv.y & 0xffff)) * s0.z + q0.z + bf2f((u16)(pv.y & 0xffff));
  f0.w = bf2f((u16)(hv.y >> 16))    * s0.w + q0.w + bf2f((u16)(pv.y >> 16));
  f1.x = bf2f((u16)(hv.z & 0xffff)) * s1.x + q1.x + bf2f((u16)(pv.z & 0xffff));
  f1.y = bf2f((u16)(hv.z >> 16))    * s1.y + q1.y + bf2f((u16)(pv.z >> 16));
  f1.z = bf2f((u16)(hv.w & 0xffff)) * s1.z + q1.z + bf2f((u16)(pv.w & 0xffff));
  f1.w = bf2f((u16)(hv.w >> 16))    * s1.w + q1.w + bf2f((u16)(pv.w >> 16));
  f0.x = elu1(f0.x); f0.y = elu1(f0.y); f0.z = elu1(f0.z); f0.w = elu1(f0.w);
  f1.x = elu1(f1.x); f1.y = elu1(f1.y); f1.z = elu1(f1.z); f1.w = elu1(f1.w);
  ((float4*)out)[(size_t)i * 2]     = f0;
  ((float4*)out)[(size_t)i * 2 + 1] = f1;
}

// ---------------------------------------------------------------------------
extern "C" void kernel_launch(void* const* d_in, const int* in_sizes, int n_in,
                              void* d_out, int out_size, void* d_ws, size_t ws_size,
                              hipStream_t stream)
{
  const float* msa   = (const float*)d_in[0];
  const float* pair  = (const float*)d_in[1];
  const float* ln_g  = (const float*)d_in[2];
  const float* ln_b  = (const float*)d_in[3];
  const float* Wl    = (const float*)d_in[4];
  const float* bl    = (const float*)d_in[5];
  const float* Wr    = (const float*)d_in[6];
  const float* br    = (const float*)d_in[7];
  const float* Wo    = (const float*)d_in[8];
  const float* bo    = (const float*)d_in[9];
  const float* Wd    = (const float*)d_in[10];
  const float* bd    = (const float*)d_in[11];
  const float* conv1 = (const float*)d_in[12];
  const float* in1_g = (const float*)d_in[13];
  const float* in1_b = (const float*)d_in[14];
  const float* conv2 = (const float*)d_in[15];
  const float* in2_g = (const float*)d_in[16];
  const float* in2_b = (const float*)d_in[17];
  float* out = (float*)d_out;

  // Workspace (F = 1Mi floats = 4 MB), peak ~89 MB:
  //  [0,4F)    msaF (dead after gemm_lr) -> h1N (bf16)
  //  [4F,5F)   leftT+rightT (dead after fragpack)
  //  [5F,5.5F) leftF ; [5.5F,6F) rightF
  //  [6F,10F)  pN (NHWC bf16, live to end)
  //  [10F,14F) h1raw (NHWC bf16)
  //  [14F,18F) h2raw (NHWC bf16)
  //  [18F,22F) pairF (dead after k_fused)
  //  [22F,..)  gS/gQ + stats + fragment weights
  float* ws = (float*)d_ws;
  const size_t F = 1048576;
  u16* msaF   = (u16*)ws;
  u16* h1N    = (u16*)ws;
  u16* leftT  = (u16*)(ws + 4 * F);
  u16* rightT = (u16*)(ws + 4 * F + F / 2);
  u16* leftF  = (u16*)(ws + 5 * F);
  u16* rightF = (u16*)(ws + 5 * F + F / 2);
  u16* pN     = (u16*)(ws + 6 * F);
  u16* h1raw  = (u16*)(ws + 10 * F);
  u16* h2raw  = (u16*)(ws + 14 * F);
  u16* pairF  = (u16*)(ws + 18 * F);
  float* gS   = ws + 22 * F;                 // 65536
  float* gQ   = ws + 22 * F + 65536;         // 65536
  float* stats = ws + 22 * F + 131072;       // 512
  u16* aux    = (u16*)(ws + 22 * F + 131584);
  u16* wP1    = aux;                         // 147456
  u16* wP2    = aux + 147456;                // 147456
  u16* WoF    = aux + 294912;                // 131072
  u16* WdF    = aux + 425984;                // 32768
  u16* WlrF   = aux + 458752;                // 16384

  k_prep_ln<<<dim3(6376), dim3(256), 0, stream>>>(Wl, Wr, Wo, Wd, conv1, conv2,
                                                  pair, msa, ln_g, ln_b,
                                                  WlrF, WoF, WdF, wP1, wP2, pairF, msaF);
  k_gemm_lr<<<dim3(128), dim3(256), 0, stream>>>(msaF, WlrF, bl, br, leftT, rightT);
  k_fragpack<<<dim3(256), dim3(256), 0, stream>>>(leftT, rightT, leftF, rightF);

  k_fused<<<dim3(1024), dim3(512), 0, stream>>>(leftF, rightF, WoF, pairF, WdF,
                                                bo, bd, pN);

  k_conv<<<dim3(4, 128), dim3(256), 0, stream>>>(pN, wP1, h1raw, gS, gQ);
  k_instat2<<<dim3(1), dim3(512), 0, stream>>>(gS, gQ, in1_g, in1_b, stats);
  k_in_elu<<<dim3(4096), dim3(256), 0, stream>>>(h1raw, stats, h1N);

  k_conv<<<dim3(4, 128), dim3(256), 0, stream>>>(h1N, wP2, h2raw, gS, gQ);
  k_instat2<<<dim3(1), dim3(512), 0, stream>>>(gS, gQ, in2_g, in2_b, stats + 256);

  k_final<<<dim3(4096), dim3(256), 0, stream>>>(pN, h2raw, stats + 256, out);
}